// Round 9
// baseline (410.981 us; speedup 1.0000x reference)
//
#include <hip/hip_runtime.h>

// BasicTransformerBlock on gfx950, bf16 MFMA implementation.
// R9: (1) FF2 -> gemm_n64 tile (640 blocks, kills 320-block makespan waste);
//     (2) attn_sa T14 async-STAGE split: K/V reg-prefetch issued before
//         compute of previous tile, ds_write after barrier. Same LDS/barriers.

using u16 = unsigned short;
typedef __attribute__((ext_vector_type(8))) short bfrag;   // 8 bf16 (4 VGPR)
typedef __attribute__((ext_vector_type(4))) float f4;
typedef __attribute__((ext_vector_type(4))) unsigned short us4;

#define MFMA(a, b, c) __builtin_amdgcn_mfma_f32_16x16x32_bf16((a), (b), (c), 0, 0, 0)

__device__ __forceinline__ void gload16(const void* g, void* l) {
    // async global->LDS, 16B per lane; LDS dest = uniform base + lane*16
    __builtin_amdgcn_global_load_lds(
        (const __attribute__((address_space(1))) void*)g,
        (__attribute__((address_space(3))) void*)l, 16, 0, 0);
}

__device__ __forceinline__ u16 f2b(float f) {   // f32 -> bf16 RNE
    unsigned u = __float_as_uint(f);
    unsigned r = u + 0x7FFFu + ((u >> 16) & 1u);
    return (u16)(r >> 16);
}
__device__ __forceinline__ float b2f(u16 u) {
    return __uint_as_float(((unsigned)u) << 16);
}
__device__ __forceinline__ unsigned pack2(float a, float b) {
    return (unsigned)f2b(a) | ((unsigned)f2b(b) << 16);
}
__device__ __forceinline__ bfrag bzero() {
    bfrag z = {0,0,0,0,0,0,0,0};
    return z;
}
// gelu: 0.5x(1+tanh(0.79788456(x+0.044715x^3))), tanh via e^{2y}
__device__ __forceinline__ float gelu_f(float x) {
    float y = 0.7978845608028654f * (x + 0.044715f * x * x * x);
    float e = exp2f(y * 2.8853900817779268f);          // e^{2y}
    float t = 1.0f - 2.0f * __builtin_amdgcn_rcpf(e + 1.0f);
    return 0.5f * x * (1.0f + t);
}

// ---------------------------------------------------------------------------
// prep mega-kernel: all weight transposes + input conversions in ONE dispatch.
__device__ __forceinline__ void transp_tile(const float* __restrict__ in,
                                            u16* __restrict__ out,
                                            int K, int N, int ldo,
                                            int tile, bool perm,
                                            float (*t)[33])
{
    int nw = N >> 5;
    int n0 = (tile % nw) * 32, k0 = (tile / nw) * 32;
    int tx = threadIdx.x & 31, ty = threadIdx.x >> 5;
    #pragma unroll
    for (int i = 0; i < 32; i += 8)
        t[ty + i][tx] = in[(size_t)(k0 + ty + i) * N + n0 + tx];
    __syncthreads();
    #pragma unroll
    for (int i = 0; i < 32; i += 8) {
        int n = n0 + ty + i;
        int dst;
        if (perm) {
            dst = (n < 2560) ? ((n >> 5) * 64 + (n & 31))
                             : (((n - 2560) >> 5) * 64 + 32 + ((n - 2560) & 31));
        } else {
            dst = n;
        }
        out[(size_t)dst * ldo + k0 + tx] = f2b(t[tx][ty + i]);
    }
}

__global__ __launch_bounds__(256) void prep_k(
    const float* __restrict__ x, const float* __restrict__ ctx,
    const float* __restrict__ sa_wq, const float* __restrict__ sa_wk,
    const float* __restrict__ sa_wv, const float* __restrict__ sa_wo,
    const float* __restrict__ ca_wq, const float* __restrict__ ca_wk,
    const float* __restrict__ ca_wv, const float* __restrict__ ca_wo,
    const float* __restrict__ ff_w1, const float* __restrict__ ff_w2,
    u16* saqkvt, u16* sawot, u16* cawqt, u16* cawot, u16* cakvt,
    u16* ffw1t, u16* ffw2t, u16* xb, u16* ctxb)
{
    __shared__ float t[32][33];
    int b = blockIdx.x;
    if (b < 2400) {
        int task = b / 400, tile = b - task * 400;
        const float* src;
        u16* dst;
        if      (task == 0) { src = sa_wq; dst = saqkvt; }
        else if (task == 1) { src = sa_wk; dst = saqkvt + 409600; }
        else if (task == 2) { src = sa_wv; dst = saqkvt + 819200; }
        else if (task == 3) { src = sa_wo; dst = sawot; }
        else if (task == 4) { src = ca_wq; dst = cawqt; }
        else                { src = ca_wo; dst = cawot; }
        transp_tile(src, dst, 640, 640, 640, tile, false, t);
    } else if (b < 3360) {
        int tt = b - 2400;
        int task = tt / 480, tile = tt - task * 480;
        transp_tile(task ? ca_wv : ca_wk, cakvt + task * 491520, 768, 640, 768,
                    tile, false, t);
    } else if (b < 6560) {
        transp_tile(ff_w1, ffw1t, 640, 5120, 640, b - 3360, true, t);
    } else if (b < 8160) {
        transp_tile(ff_w2, ffw2t, 2560, 640, 2560, b - 6560, false, t);
    } else if (b < 10720) {
        int i = (b - 8160) * 256 + threadIdx.x;     // < 655360
        const float4* p = (const float4*)x + (size_t)i * 2;
        float4 a = p[0], bb = p[1];
        uint4 w = { pack2(a.x, a.y), pack2(a.z, a.w),
                    pack2(bb.x, bb.y), pack2(bb.z, bb.w) };
        ((uint4*)xb)[i] = w;
    } else {
        int i = (b - 10720) * 256 + threadIdx.x;    // < 61440
        int rowOut = i / 96, c8 = (i - rowOut * 96) * 8;
        int bb = rowOut / 80, r = rowOut - bb * 80;
        uint4 w = {0, 0, 0, 0};
        if (r < 77) {
            const float4* p = (const float4*)(ctx + ((size_t)(bb * 77 + r)) * 768 + c8);
            float4 a = p[0], b2 = p[1];
            w = (uint4){ pack2(a.x, a.y), pack2(a.z, a.w),
                         pack2(b2.x, b2.y), pack2(b2.z, b2.w) };
        }
        ((uint4*)ctxb)[i] = w;
    }
}

// ---------------------------------------------------------------------------
// GEMM core: C[M][N] = A[M][K](bf16) @ Bt[N][K](bf16)^T, 128x128 tile, BK=64.
// ld = row stride of A and Bt in elements.
// MODE 0: outf = acc + bias[col] + b2f(resb[row*N+col])      (f32)
// MODE 1: outb = acc                                          (bf16, stride N)
// MODE 2: QKV: outb=qkvb[row*1920+col] (Q cols pre-scaled); V also -> out2=vt
// MODE 3: CA KV: rows b*80+r (r<77): col<640 -> kc; else -> vct[b,h,d,key]
// MODE 4: FF1+GEGLU: block-interleaved cols; a/gate in-thread
template<int MODE>
__device__ __forceinline__ void gemm_core(const u16* __restrict__ A,
                                          const u16* __restrict__ Bt,
                                          int N, int K, int ld,
                                          const float* __restrict__ bias,
                                          const u16* __restrict__ resb,
                                          float* __restrict__ outf,
                                          u16* __restrict__ outb,
                                          u16* __restrict__ out2,
                                          int bx, int by,
                                          u16* As, u16* Bs)
{
    const int lane = threadIdx.x & 63;
    const int wid  = threadIdx.x >> 6;
    const int q    = lane >> 4;
    const int lc   = lane & 15;
    const int wm = wid >> 1, wn = wid & 1;
    const int m0 = by * 128;
    const int n0 = bx * 128;
    const int ldb = ld * 2;               // bytes per row

    f4 acc[4][4];
    #pragma unroll
    for (int i = 0; i < 4; ++i)
        #pragma unroll
        for (int j = 0; j < 4; ++j) acc[i][j] = (f4){0.f, 0.f, 0.f, 0.f};

    const char* Abase = (const char*)A + (size_t)m0 * ldb;
    const char* Bbase = (const char*)Bt + (size_t)n0 * ldb;

    for (int kt = 0; kt < K; kt += 64) {
        #pragma unroll
        for (int c = 0; c < 4; ++c) {
            int cid = wid * 4 + c;
            int o = cid * 1024 + lane * 16;
            int row = o >> 7;
            int pc  = o & 127;
            int src = pc ^ ((row & 7) << 4);   // pre-swizzled source, linear dest
            gload16(Abase + (size_t)row * ldb + kt * 2 + src, (char*)As + cid * 1024);
            gload16(Bbase + (size_t)row * ldb + kt * 2 + src, (char*)Bs + cid * 1024);
        }
        __syncthreads();
        #pragma unroll
        for (int ks = 0; ks < 2; ++ks) {
            bfrag a[4], b[4];
            #pragma unroll
            for (int mi = 0; mi < 4; ++mi) {
                int row = wm * 64 + mi * 16 + lc;
                int off = row * 128 + ((ks * 64 + q * 16) ^ ((row & 7) << 4));
                a[mi] = *(const bfrag*)((const char*)As + off);
            }
            #pragma unroll
            for (int ni = 0; ni < 4; ++ni) {
                int row = wn * 64 + ni * 16 + lc;
                int off = row * 128 + ((ks * 64 + q * 16) ^ ((row & 7) << 4));
                b[ni] = *(const bfrag*)((const char*)Bs + off);
            }
            #pragma unroll
            for (int mi = 0; mi < 4; ++mi)
                #pragma unroll
                for (int ni = 0; ni < 4; ++ni)
                    acc[mi][ni] = MFMA(a[mi], b[ni], acc[mi][ni]);
        }
        __syncthreads();
    }

    const int baseRow = m0 + wm * 64;
    const int baseCol = n0 + wn * 64;

    if (MODE == 4) {
        const int blk = baseCol >> 6;
        #pragma unroll
        for (int mi = 0; mi < 4; ++mi)
            #pragma unroll
            for (int ni = 0; ni < 2; ++ni) {
                int j = blk * 32 + ni * 16 + lc;
                float ba = bias[j];
                float bg = bias[2560 + j];
                #pragma unroll
                for (int r = 0; r < 4; ++r) {
                    int row = baseRow + mi * 16 + q * 4 + r;
                    float aa = acc[mi][ni][r] + ba;
                    float gg = acc[mi][ni + 2][r] + bg;
                    outb[(size_t)row * 2560 + j] = f2b(aa * gelu_f(gg));
                }
            }
        return;
    }

    #pragma unroll
    for (int mi = 0; mi < 4; ++mi)
        #pragma unroll
        for (int ni = 0; ni < 4; ++ni) {
            int col = baseCol + ni * 16 + lc;
            if (MODE == 2) {
                const float qs = (col < 640) ? 0.11180339887498949f : 1.0f;
                us4 vv = {0, 0, 0, 0};
                #pragma unroll
                for (int r = 0; r < 4; ++r) {
                    int row = baseRow + mi * 16 + q * 4 + r;
                    u16 u = f2b(acc[mi][ni][r] * qs);
                    outb[(size_t)row * 1920 + col] = u;
                    vv[r] = u;
                }
                if (col >= 1280) {
                    int cd = col - 1280;
                    int hh = cd / 80, dd = cd - hh * 80;
                    int row0 = baseRow + mi * 16 + q * 4;
                    int bb = row0 >> 10, tok = row0 & 1023;
                    *(us4*)&out2[(size_t)((bb * 8 + hh) * 80 + dd) * 1024 + tok] = vv;
                }
            } else {
                #pragma unroll
                for (int r = 0; r < 4; ++r) {
                    int row = baseRow + mi * 16 + q * 4 + r;
                    float v = acc[mi][ni][r];
                    if (MODE == 0) {
                        v += bias[col] + b2f(resb[(size_t)row * N + col]);
                        outf[(size_t)row * N + col] = v;
                    } else if (MODE == 1) {
                        outb[(size_t)row * N + col] = f2b(v);
                    } else if (MODE == 3) {
                        int bb = row / 80, rr = row - bb * 80;
                        if (rr < 77) {
                            u16 u = f2b(v);
                            if (col < 640) {
                                outb[(size_t)row * 640 + col] = u;
                            } else {
                                int cd = col - 640;
                                int hh = cd / 80, dd = cd - hh * 80;
                                out2[((bb * 8 + hh) * 80 + dd) * 80 + rr] = u;
                            }
                        }
                    }
                }
            }
        }
}

template<int MODE>
__global__ __launch_bounds__(256) void gemm_bt(const u16* __restrict__ A,
                                               const u16* __restrict__ Bt,
                                               int N, int K,
                                               const float* __restrict__ bias,
                                               const u16* __restrict__ resb,
                                               float* __restrict__ outf,
                                               u16* __restrict__ outb,
                                               u16* __restrict__ out2)
{
    __shared__ u16 As[128 * 64];
    __shared__ u16 Bs[128 * 64];
    gemm_core<MODE>(A, Bt, N, K, K, bias, resb, outf, outb, out2,
                    blockIdx.x, blockIdx.y, As, Bs);
}

// fused: blocks [0,960) = QKV GEMM (MODE 2), [960,1010) = CA-KV GEMM (MODE 3)
__global__ __launch_bounds__(256) void gemm_qkv_cakv(
    const u16* __restrict__ xb, const u16* __restrict__ saqkvt,
    const u16* __restrict__ ctxb, const u16* __restrict__ cakvt,
    u16* qkvb, u16* vt, u16* kc, u16* vct)
{
    __shared__ u16 As[128 * 64];
    __shared__ u16 Bs[128 * 64];
    int bid = blockIdx.x;
    if (bid < 960) {
        gemm_core<2>(xb, saqkvt, 1920, 640, 640, nullptr, nullptr, nullptr,
                     qkvb, vt, bid % 15, bid / 15, As, Bs);
    } else {
        int tt = bid - 960;
        gemm_core<3>(ctxb, cakvt, 1280, 768, 768, nullptr, nullptr, nullptr,
                     kc, vct, tt % 10, tt / 10, As, Bs);
    }
}

// ---------------------------------------------------------------------------
// 128x64-tile GEMM for N=640 occupancy-bound shapes (projections + FF2).
// Grid (N/64, M/128) = 640 blocks. 4 waves as 2Mx2N; per-wave 64x32 (acc[4][2]).
// LDS: A = 16 chunks; B = 8 chunks; 24 total, 6 per wave.
// MODE 0: outf = acc + bias[col] + b2f(resb[row*N+col]) (f32)
// MODE 1: outb = f2b(acc)
template<int MODE>
__global__ __launch_bounds__(256) void gemm_n64(const u16* __restrict__ A,
                                                const u16* __restrict__ Bt,
                                                int N, int K,
                                                const float* __restrict__ bias,
                                                const u16* __restrict__ resb,
                                                float* __restrict__ outf,
                                                u16* __restrict__ outb)
{
    __shared__ u16 As[128 * 64];
    __shared__ u16 Bs[64 * 64];
    const int lane = threadIdx.x & 63;
    const int wid  = threadIdx.x >> 6;
    const int hi   = lane >> 4;
    const int lc   = lane & 15;
    const int wm = wid >> 1, wn = wid & 1;
    const int m0 = blockIdx.y * 128;
    const int n0 = blockIdx.x * 64;
    const int ldb = K * 2;

    f4 acc[4][2];
    #pragma unroll
    for (int i = 0; i < 4; ++i)
        #pragma unroll
        for (int j = 0; j < 2; ++j) acc[i][j] = (f4){0.f, 0.f, 0.f, 0.f};

    const char* Abase = (const char*)A + (size_t)m0 * ldb;
    const char* Bbase = (const char*)Bt + (size_t)n0 * ldb;

    for (int kt = 0; kt < K; kt += 64) {
        #pragma unroll
        for (int c = 0; c < 6; ++c) {
            int cid = wid * 6 + c;              // 24 chunks: 16 A + 8 B
            if (cid < 16) {
                int o = cid * 1024 + lane * 16;
                int row = o >> 7;
                int src = (o & 127) ^ ((row & 7) << 4);
                gload16(Abase + (size_t)row * ldb + kt * 2 + src, (char*)As + cid * 1024);
            } else {
                int c2 = cid - 16;
                int o = c2 * 1024 + lane * 16;
                int row = o >> 7;
                int src = (o & 127) ^ ((row & 7) << 4);
                gload16(Bbase + (size_t)row * ldb + kt * 2 + src, (char*)Bs + c2 * 1024);
            }
        }
        __syncthreads();
        #pragma unroll
        for (int ks = 0; ks < 2; ++ks) {
            bfrag a[4], b[2];
            #pragma unroll
            for (int mi = 0; mi < 4; ++mi) {
                int row = wm * 64 + mi * 16 + lc;
                int off = row * 128 + ((ks * 64 + hi * 16) ^ ((row & 7) << 4));
                a[mi] = *(const bfrag*)((const char*)As + off);
            }
            #pragma unroll
            for (int ni = 0; ni < 2; ++ni) {
                int row = wn * 32 + ni * 16 + lc;
                int off = row * 128 + ((ks * 64 + hi * 16) ^ ((row & 7) << 4));
                b[ni] = *(const bfrag*)((const char*)Bs + off);
            }
            #pragma unroll
            for (int mi = 0; mi < 4; ++mi)
                #pragma unroll
                for (int ni = 0; ni < 2; ++ni)
                    acc[mi][ni] = MFMA(a[mi], b[ni], acc[mi][ni]);
        }
        __syncthreads();
    }

    const int baseRow = m0 + wm * 64;
    const int baseCol = n0 + wn * 32;
    #pragma unroll
    for (int mi = 0; mi < 4; ++mi)
        #pragma unroll
        for (int ni = 0; ni < 2; ++ni) {
            int col = baseCol + ni * 16 + lc;
            #pragma unroll
            for (int r = 0; r < 4; ++r) {
                int row = baseRow + mi * 16 + hi * 4 + r;
                float v = acc[mi][ni][r];
                if (MODE == 0) {
                    v += bias[col] + b2f(resb[(size_t)row * N + col]);
                    outf[(size_t)row * N + col] = v;
                } else {
                    outb[(size_t)row * N + col] = f2b(v);
                }
            }
        }
}

// ---------------------------------------------------------------------------
// Self-attention, swapped-QK^T layout. Block = (qt, b, head); 4 waves x 16 rows.
// T14 async-STAGE: K/V tile t+1 loaded to regs before compute of tile t,
// ds_write after the post-compute barrier.
__global__ __launch_bounds__(256) void attn_sa(const u16* __restrict__ qkv,
                                               const u16* __restrict__ vt,
                                               u16* __restrict__ out)
{
    __shared__ u16 Qs[64 * 80];
    __shared__ u16 Ks[64 * 80];
    __shared__ u16 Vs[80 * 64];
    __shared__ u16 Ps[4][16 * 64];

    const int lane = threadIdx.x & 63;
    const int wid  = threadIdx.x >> 6;
    const int hi   = lane >> 4;
    const int lc   = lane & 15;
    const int bid = blockIdx.x;
    const int qt = bid >> 6;
    const int bb = (bid >> 3) & 7;
    const int hh = bid & 7;
    const int tok0 = bb * 1024 + qt * 64;
    const char* qbase = (const char*)qkv;

    for (int c = wid; c < 10; c += 4) {       // stage Q [64][80] (gload_lds)
        int o = c * 1024 + lane * 16;
        int row = o / 160, col = o - row * 160;
        gload16(qbase + (size_t)(tok0 + row) * 3840 + hh * 160 + col, (char*)Qs + c * 1024);
    }

    // per-wave K/V prefetch: 5 chunks (c = wid, wid+4, ..., wid+16)
    uint4 pf[5];
    auto ldchunks = [&](int t) {
        #pragma unroll
        for (int i = 0; i < 5; ++i) {
            int c = wid + i * 4;
            if (c < 10) {                      // K chunk: [64][80], 160B rows
                int o = c * 1024 + lane * 16;
                int row = o / 160, col = o - row * 160;
                pf[i] = *(const uint4*)(qbase
                    + (size_t)(bb * 1024 + t * 64 + row) * 3840 + 1280 + hh * 160 + col);
            } else {                           // V chunk: [80][64], swizzled src
                int c2 = c - 10;
                int o = c2 * 1024 + lane * 16;
                int row = o >> 7;
                int src = (o & 127) ^ ((row & 7) << 4);
                pf[i] = *(const uint4*)((const char*)vt
                    + (size_t)((bb * 8 + hh) * 80 + row) * 2048 + t * 128 + src);
            }
        }
    };
    auto stchunks = [&]() {
        #pragma unroll
        for (int i = 0; i < 5; ++i) {
            int c = wid + i * 4;
            char* d = (c < 10) ? ((char*)Ks + c * 1024)
                               : ((char*)Vs + (c - 10) * 1024);
            *(uint4*)(d + lane * 16) = pf[i];
        }
    };

    // prologue: tile 0 regs -> LDS (also drains Q gload_lds, older in vmcnt)
    ldchunks(0);
    stchunks();
    __syncthreads();

    const int qrow = wid * 16 + lc;
    bfrag qf0 = *(const bfrag*)((const char*)Qs + qrow * 160 + hi * 16);
    bfrag qf1 = *(const bfrag*)((const char*)Qs + qrow * 160 + 64 + hi * 16);
    bfrag qf2 = bzero();
    if (hi < 2) qf2 = *(const bfrag*)((const char*)Qs + qrow * 160 + 128 + hi * 16);

    float m = -3e30f, l = 0.f;
    f4 accO[5];
    #pragma unroll
    for (int no = 0; no < 5; ++no) accO[no] = (f4){0.f, 0.f, 0.f, 0.f};

    const float L2E = 1.4426950408889634f;

    for (int t = 0; t < 16; ++t) {
        if (t < 15) ldchunks(t + 1);           // loads in flight under compute

        f4 sT[4];
        #pragma unroll
        for (int nb = 0; nb < 4; ++nb) {
            const char* kb = (const char*)Ks + (nb * 16 + lc) * 160;
            bfrag k0 = *(const bfrag*)(kb + hi * 16);
            bfrag k1 = *(const bfrag*)(kb + 64 + hi * 16);
            bfrag k2 = bzero();
            if (hi < 2) k2 = *(const bfrag*)(kb + 128 + hi * 16);
            f4 a = {0.f, 0.f, 0.f, 0.f};
            a = MFMA(k0, qf0, a);
            a = MFMA(k1, qf1, a);
            a = MFMA(k2, qf2, a);
            sT[nb] = a;
        }

        float pm = sT[0][0];
        #pragma unroll
        for (int nb = 0; nb < 4; ++nb)
            #pragma unroll
            for (int r = 0; r < 4; ++r) pm = fmaxf(pm, sT[nb][r]);
        pm = fmaxf(pm, __shfl_xor(pm, 16));
        pm = fmaxf(pm, __shfl_xor(pm, 32));

        if (__any(pm > m + 8.0f)) {
            float mn = fmaxf(m, pm);
            float al = exp2f((m - mn) * L2E);
            m = mn;
            l *= al;
            float af[4];
            #pragma unroll
            for (int r = 0; r < 4; ++r) af[r] = __shfl(al, hi * 4 + r);
            #pragma unroll
            for (int no = 0; no < 5; ++no)
                #pragma unroll
                for (int r = 0; r < 4; ++r) accO[no][r] *= af[r];
        }

        float sum = 0.f;
        #pragma unroll
        for (int nb = 0; nb < 4; ++nb)
            #pragma unroll
            for (int r = 0; r < 4; ++r) {
                float p = exp2f((sT[nb][r] - m) * L2E);
                sT[nb][r] = p;
                sum += p;
            }
        sum += __shfl_xor(sum, 16);
        sum += __shfl_xor(sum, 32);
        l += sum;

        char* Pw = (char*)&Ps[wid][0];
        #pragma unroll
        for (int nb = 0; nb < 4; ++nb) {
            us4 pk = { f2b(sT[nb][0]), f2b(sT[nb][1]), f2b(sT[nb][2]), f2b(sT[nb][3]) };
            int cb = (nb * 16 + hi * 4) * 2;
            *(us4*)(Pw + lc * 128 + (cb ^ ((lc & 7) << 4))) = pk;
        }

        bfrag pa0 = *(const bfrag*)(Pw + lc * 128 + ((hi * 16) ^ ((lc & 7) << 4)));
        bfrag pa1 = *(const bfrag*)(Pw + lc * 128 + ((64 + hi * 16) ^ ((lc & 7) << 4)));
        #pragma unroll
        for (int no = 0; no < 5; ++no) {
            int vr = no * 16 + lc;
            const char* vb = (const char*)Vs + vr * 128;
            bfrag v0 = *(const bfrag*)(vb + ((hi * 16) ^ ((vr & 7) << 4)));
            bfrag v1 = *(const bfrag*)(vb + ((64 + hi * 16) ^ ((vr & 7) << 4)));
            accO[no] = MFMA(pa0, v0, accO[no]);
            accO[no] = MFMA(pa1, v1, accO[no]);
        }

        __syncthreads();                       // all reads of tile t complete
        if (t < 15) {
            stchunks();                        // compiler waits vmcnt before use
            __syncthreads();                   // writes visible to all waves
        }
    }

    float rf[4];
    #pragma unroll
    for (int r = 0; r < 4; ++r) {
        float lf = __shfl(l, hi * 4 + r);
        rf[r] = __builtin_amdgcn_rcpf(lf);
    }
    #pragma unroll
    for (int no = 0; no < 5; ++no)
        #pragma unroll
        for (int r = 0; r < 4; ++r) {
            int row = tok0 + wid * 16 + hi * 4 + r;
            int col = hh * 80 + no * 16 + lc;
            out[(size_t)row * 640 + col] = f2b(accO[no][r] * rf[r]);
        }
}

// ---------------------------------------------------------------------------
// Cross-attention: single KV tile (77 keys padded to 80, masked).
__global__ __launch_bounds__(256) void attn_ca(const u16* __restrict__ qc,
                                               const u16* __restrict__ kc,
                                               const u16* __restrict__ vct,
                                               u16* __restrict__ out)
{
    __shared__ u16 Qs[64 * 80];
    __shared__ u16 Ks[84 * 80];
    __shared__ u16 Vs[84 * 80];
    __shared__ u16 Ps[4][16 * 80];

    const int lane = threadIdx.x & 63;
    const int wid  = threadIdx.x >> 6;
    const int q    = lane >> 4;
    const int lc   = lane & 15;
    const int bid = blockIdx.x;
    const int qt = bid & 15;
    const int hh = (bid >> 4) & 7;
    const int bb = bid >> 7;
    const int tok0 = bb * 1024 + qt * 64;

    for (int c = wid; c < 36; c += 4) {
        if (c < 10) {
            int o = c * 1024 + lane * 16;
            int row = o / 160, col = o - row * 160;
            gload16((const char*)qc + (size_t)(tok0 + row) * 1280 + hh * 160 + col,
                    (char*)Qs + c * 1024);
        } else if (c < 23) {
            int c2 = c - 10;
            int o = c2 * 1024 + lane * 16;
            int row = o / 160, col = o - row * 160;
            gload16((const char*)kc + (size_t)(bb * 80 + row) * 1280 + hh * 160 + col,
                    (char*)Ks + c2 * 1024);
        } else {
            int c2 = c - 23;
            int o = c2 * 1024 + lane * 16;
            int row = o / 160, col = o - row * 160;
            gload16((const char*)vct + (size_t)((bb * 8 + hh) * 80 + row) * 160 + col,
                    (char*)Vs + c2 * 1024);
        }
    }
    __syncthreads();

    const int qrow = wid * 16 + lc;
    bfrag qf0 = *(const bfrag*)((const char*)Qs + qrow * 160 + q * 16);
    bfrag qf1 = *(const bfrag*)((const char*)Qs + qrow * 160 + 64 + q * 16);
    bfrag qf2 = bzero();
    if (q < 2) qf2 = *(const bfrag*)((const char*)Qs + qrow * 160 + 128 + q * 16);

    const float SC = 0.11180339887498949f;
    const float L2E = 1.4426950408889634f;

    f4 s[5];
    #pragma unroll
    for (int nb = 0; nb < 5; ++nb) {
        const char* kb = (const char*)Ks + (nb * 16 + lc) * 160;
        bfrag k0 = *(const bfrag*)(kb + q * 16);
        bfrag k1 = *(const bfrag*)(kb + 64 + q * 16);
        bfrag k2 = bzero();
        if (q < 2) k2 = *(const bfrag*)(kb + 128 + q * 16);
        f4 a = {0.f, 0.f, 0.f, 0.f};
        a = MFMA(qf0, k0, a);
        a = MFMA(qf1, k1, a);
        a = MFMA(qf2, k2, a);
        s[nb] = a;
    }
    #pragma unroll
    for (int nb = 0; nb < 5; ++nb) {
        int key = nb * 16 + lc;
        #pragma unroll
        for (int r = 0; r < 4; ++r) {
            s[nb][r] *= SC;
            if (key >= 77) s[nb][r] = -1e30f;
        }
    }
    float mrow[4], lrow[4];
    #pragma unroll
    for (int r = 0; r < 4; ++r) {
        float v = fmaxf(fmaxf(fmaxf(s[0][r], s[1][r]), fmaxf(s[2][r], s[3][r])), s[4][r]);
        v = fmaxf(v, __shfl_xor(v, 1));
        v = fmaxf(v, __shfl_xor(v, 2));
        v = fmaxf(v, __shfl_xor(v, 4));
        v = fmaxf(v, __shfl_xor(v, 8));
        mrow[r] = v;
    }
    float rsum[4] = {0.f, 0.f, 0.f, 0.f};
    #pragma unroll
    for (int nb = 0; nb < 5; ++nb)
        #pragma unroll
        for (int r = 0; r < 4; ++r) {
            float p = exp2f((s[nb][r] - mrow[r]) * L2E);
            s[nb][r] = p;
            rsum[r] += p;
        }
    #pragma unroll
    for (int r = 0; r < 4; ++r) {
        float v = rsum[r];
        v += __shfl_xor(v, 1);
        v += __shfl_xor(v, 2);
        v += __shfl_xor(v, 4);
        v += __shfl_xor(v, 8);
        lrow[r] = v;
    }

    char* Pw = (char*)&Ps[wid][0];
    #pragma unroll
    for (int nb = 0; nb < 5; ++nb)
        #pragma unroll
        for (int r = 0; r < 4; ++r) {
            int prow = q * 4 + r;
            *(u16*)(Pw + prow * 160 + (nb * 16 + lc) * 2) = f2b(s[nb][r]);
        }
    bfrag pa0 = *(const bfrag*)(Pw + lc * 160 + q * 16);
    bfrag pa1 = *(const bfrag*)(Pw + lc * 160 + 64 + q * 16);
    bfrag pa2 = bzero();
    if (q < 2) pa2 = *(const bfrag*)(Pw + lc * 160 + 128 + q * 16);

    f4 accO[5];
    #pragma unroll
    for (int no = 0; no < 5; ++no) {
        const char* vb = (const char*)Vs + (no * 16 + lc) * 160;
        bfrag v0 = *(const bfrag*)(vb + q * 16);
        bfrag v1 = *(const bfrag*)(vb + 64 + q * 16);
        bfrag v2 = bzero();
        if (q < 2) v2 = *(const bfrag*)(vb + 128 + q * 16);
        f4 a = {0.f, 0.f, 0.f, 0.f};
        a = MFMA(pa0, v0, a);
        a = MFMA(pa1, v1, a);
        a = MFMA(pa2, v2, a);
        accO[no] = a;
    }
    #pragma unroll
    for (int no = 0; no < 5; ++no)
        #pragma unroll
        for (int r = 0; r < 4; ++r) {
            int row = tok0 + wid * 16 + q * 4 + r;
            int col = hh * 80 + no * 16 + lc;
            out[(size_t)row * 640 + col] = f2b(accO[no][r] / lrow[r]);
        }
}

// ---------------------------------------------------------------------------
// LayerNorm over 640 cols; 1 wave per row, 4 rows per block.
__global__ __launch_bounds__(256) void ln_k(const float* __restrict__ pre,
                                            const float* __restrict__ g,
                                            const float* __restrict__ b,
                                            float* __restrict__ xo,
                                            u16* __restrict__ xb)
{
    const int lane = threadIdx.x & 63;
    const int wid  = threadIdx.x >> 6;
    const int row = blockIdx.x * 4 + wid;
    const float* p = pre + (size_t)row * 640;
    float v[10];
    #pragma unroll
    for (int i = 0; i < 10; ++i) v[i] = p[lane + i * 64];
    float s = 0.f;
    #pragma unroll
    for (int i = 0; i < 10; ++i) s += v[i];
    #pragma unroll
    for (int m = 1; m < 64; m <<= 1) s += __shfl_xor(s, m);
    float mu = s * (1.0f / 640.0f);
    float d2 = 0.f;
    #pragma unroll
    for (int i = 0; i < 10; ++i) { float d = v[i] - mu; d2 += d * d; }
    #pragma unroll
    for (int m = 1; m < 64; m <<= 1) d2 += __shfl_xor(d2, m);
    float rs = rsqrtf(d2 * (1.0f / 640.0f) + 1e-5f);
    #pragma unroll
    for (int i = 0; i < 10; ++i) {
        int col = lane + i * 64;
        float y = (v[i] - mu) * rs * g[col] + b[col];
        if (xo) xo[(size_t)row * 640 + col] = y;
        if (xb) xb[(size_t)row * 640 + col] = f2b(y);
    }
}

// ---------------------------------------------------------------------------
extern "C" void kernel_launch(void* const* d_in, const int* in_sizes, int n_in,
                              void* d_out, int out_size, void* d_ws, size_t ws_size,
                              hipStream_t stream)
{
    const float* x       = (const float*)d_in[0];
    const float* context = (const float*)d_in[1];
    const float* sa_wq = (const float*)d_in[2];
    const float* sa_wk = (const float*)d_in[3];
    const float* sa_wv = (const float*)d_in[4];
    const float* sa_wo = (const float*)d_in[5];
    const float* sa_bo = (const float*)d_in[6];
    const float* ca_wq = (const float*)d_in[7];
    const float* ca_wk = (const float*)d_in[8];
    const float* ca_wv = (const float*)d_in[9];
    const float* ca_wo = (const float*)d_in[10];
    const float* ca_bo = (const float*)d_in[11];
    const float* ff_w1 = (const float*)d_in[12];
    const float* ff_b1 = (const float*)d_in[13];
    const float* ff_w2 = (const float*)d_in[14];
    const float* ff_b2 = (const float*)d_in[15];
    const float* ln1_g = (const float*)d_in[16];
    const float* ln1_b = (const float*)d_in[17];
    const float* ln2_g = (const float*)d_in[18];
    const float* ln2_b = (const float*)d_in[19];
    const float* ln3_g = (const float*)d_in[20];
    const float* ln3_b = (const float*)d_in[21];

    char* ws = (char*)d_ws;
    const size_t OFF_XB     = 0;
    const size_t OFF_QKVB   = 10485760;
    const size_t OFF_VT     = 41943040;
    const size_t OFF_AB     = 52428800;
    const size_t OFF_ATTN   = 62914560;
    const size_t OFF_QC     = 73400320;
    const size_t OFF_KC     = 83886080;
    const size_t OFF_VCT    = 84705280;
    const size_t OFF_SAQKVT = 85524480;
    const size_t OFF_SAWOT  = 87982080;
    const size_t OFF_CAWQT  = 88801280;
    const size_t OFF_CAKVT  = 89620480;
    const size_t OFF_CAWOT  = 91586560;
    const size_t OFF_FFW1T  = 92405760;
    const size_t OFF_FFW2T  = 98959360;
    const size_t OFF_CTXB   = 102236160;
    const size_t OFF_PRE    = 103219200;    // f32, 20971520 B

    u16* xb      = (u16*)(ws + OFF_XB);
    u16* qkvb    = (u16*)(ws + OFF_QKVB);
    u16* vt      = (u16*)(ws + OFF_VT);
    u16* ab      = (u16*)(ws + OFF_AB);
    u16* attnb   = (u16*)(ws + OFF_ATTN);
    u16* qc      = (u16*)(ws + OFF_QC);
    u16* kc      = (u16*)(ws + OFF_KC);
    u16* vct     = (u16*)(ws + OFF_VCT);
    u16* saqkvt  = (u16*)(ws + OFF_SAQKVT);
    u16* sawot   = (u16*)(ws + OFF_SAWOT);
    u16* cawqt   = (u16*)(ws + OFF_CAWQT);
    u16* cakvt   = (u16*)(ws + OFF_CAKVT);
    u16* cawot   = (u16*)(ws + OFF_CAWOT);
    u16* ffw1t   = (u16*)(ws + OFF_FFW1T);
    u16* ffw2t   = (u16*)(ws + OFF_FFW2T);
    u16* ctxb    = (u16*)(ws + OFF_CTXB);
    float* pre   = (float*)(ws + OFF_PRE);
    u16* ffh     = (u16*)(ws + OFF_XB);          // aliases xb+qkvb

    // --- prep: all transposes + conversions, one dispatch ---
    hipLaunchKernelGGL(prep_k, dim3(10960), dim3(256), 0, stream,
                       x, context, sa_wq, sa_wk, sa_wv, sa_wo, ca_wq, ca_wk,
                       ca_wv, ca_wo, ff_w1, ff_w2,
                       saqkvt, sawot, cawqt, cawot, cakvt, ffw1t, ffw2t, xb, ctxb);

    // --- self-attention (QKV fused with CA-KV) ---
    hipLaunchKernelGGL(gemm_qkv_cakv, dim3(1010), dim3(256), 0, stream,
                       xb, saqkvt, ctxb, cakvt, qkvb, vt, kc, vct);
    hipLaunchKernelGGL(attn_sa, dim3(1024), dim3(256), 0, stream, qkvb, vt, attnb);
    hipLaunchKernelGGL(gemm_n64<0>, dim3(10, 64), dim3(256), 0, stream,
                       attnb, sawot, 640, 640, sa_bo, xb, pre, (u16*)nullptr);
    hipLaunchKernelGGL(ln_k, dim3(2048), dim3(256), 0, stream, pre, ln1_g, ln1_b,
                       (float*)nullptr, ab);

    // --- cross-attention ---
    hipLaunchKernelGGL(gemm_n64<1>, dim3(10, 64), dim3(256), 0, stream,
                       ab, cawqt, 640, 640, (const float*)nullptr, (const u16*)nullptr,
                       (float*)nullptr, qc);
    hipLaunchKernelGGL(attn_ca, dim3(1024), dim3(256), 0, stream, qc, kc, vct, attnb);
    hipLaunchKernelGGL(gemm_n64<0>, dim3(10, 64), dim3(256), 0, stream,
                       attnb, cawot, 640, 640, ca_bo, ab, pre, (u16*)nullptr);
    hipLaunchKernelGGL(ln_k, dim3(2048), dim3(256), 0, stream, pre, ln2_g, ln2_b,
                       (float*)nullptr, ab);

    // --- GEGLU FFN ---
    hipLaunchKernelGGL(gemm_bt<4>, dim3(40, 64), dim3(256), 0, stream,
                       ab, ffw1t, 5120, 640, ff_b1, (const u16*)nullptr,
                       (float*)nullptr, ffh, (u16*)nullptr);
    hipLaunchKernelGGL(gemm_n64<0>, dim3(10, 64), dim3(256), 0, stream,
                       ffh, ffw2t, 640, 2560, ff_b2, ab, pre, (u16*)nullptr);
    hipLaunchKernelGGL(ln_k, dim3(2048), dim3(256), 0, stream, pre, ln3_g, ln3_b,
                       (float*)d_out, (u16*)nullptr);
}

// Round 10
// 348.699 us; speedup vs baseline: 1.1786x; 1.1786x over previous
//
#include <hip/hip_runtime.h>

// BasicTransformerBlock on gfx950, bf16 MFMA implementation.
// R10: revert attn_sa to R8 (T14 reg-prefetch spilled pf[] to scratch:
//      WRITE_SIZE 155MB + 1M LDS write conflicts -> 135us). Keep FF2 on
//      gemm_n64 to isolate its effect (R9 arithmetic suggests ~-15us).

using u16 = unsigned short;
typedef __attribute__((ext_vector_type(8))) short bfrag;   // 8 bf16 (4 VGPR)
typedef __attribute__((ext_vector_type(4))) float f4;
typedef __attribute__((ext_vector_type(4))) unsigned short us4;

#define MFMA(a, b, c) __builtin_amdgcn_mfma_f32_16x16x32_bf16((a), (b), (c), 0, 0, 0)

__device__ __forceinline__ void gload16(const void* g, void* l) {
    // async global->LDS, 16B per lane; LDS dest = uniform base + lane*16
    __builtin_amdgcn_global_load_lds(
        (const __attribute__((address_space(1))) void*)g,
        (__attribute__((address_space(3))) void*)l, 16, 0, 0);
}

__device__ __forceinline__ u16 f2b(float f) {   // f32 -> bf16 RNE
    unsigned u = __float_as_uint(f);
    unsigned r = u + 0x7FFFu + ((u >> 16) & 1u);
    return (u16)(r >> 16);
}
__device__ __forceinline__ float b2f(u16 u) {
    return __uint_as_float(((unsigned)u) << 16);
}
__device__ __forceinline__ unsigned pack2(float a, float b) {
    return (unsigned)f2b(a) | ((unsigned)f2b(b) << 16);
}
__device__ __forceinline__ bfrag bzero() {
    bfrag z = {0,0,0,0,0,0,0,0};
    return z;
}
// gelu: 0.5x(1+tanh(0.79788456(x+0.044715x^3))), tanh via e^{2y}
__device__ __forceinline__ float gelu_f(float x) {
    float y = 0.7978845608028654f * (x + 0.044715f * x * x * x);
    float e = exp2f(y * 2.8853900817779268f);          // e^{2y}
    float t = 1.0f - 2.0f * __builtin_amdgcn_rcpf(e + 1.0f);
    return 0.5f * x * (1.0f + t);
}

// ---------------------------------------------------------------------------
// prep mega-kernel: all weight transposes + input conversions in ONE dispatch.
__device__ __forceinline__ void transp_tile(const float* __restrict__ in,
                                            u16* __restrict__ out,
                                            int K, int N, int ldo,
                                            int tile, bool perm,
                                            float (*t)[33])
{
    int nw = N >> 5;
    int n0 = (tile % nw) * 32, k0 = (tile / nw) * 32;
    int tx = threadIdx.x & 31, ty = threadIdx.x >> 5;
    #pragma unroll
    for (int i = 0; i < 32; i += 8)
        t[ty + i][tx] = in[(size_t)(k0 + ty + i) * N + n0 + tx];
    __syncthreads();
    #pragma unroll
    for (int i = 0; i < 32; i += 8) {
        int n = n0 + ty + i;
        int dst;
        if (perm) {
            dst = (n < 2560) ? ((n >> 5) * 64 + (n & 31))
                             : (((n - 2560) >> 5) * 64 + 32 + ((n - 2560) & 31));
        } else {
            dst = n;
        }
        out[(size_t)dst * ldo + k0 + tx] = f2b(t[tx][ty + i]);
    }
}

__global__ __launch_bounds__(256) void prep_k(
    const float* __restrict__ x, const float* __restrict__ ctx,
    const float* __restrict__ sa_wq, const float* __restrict__ sa_wk,
    const float* __restrict__ sa_wv, const float* __restrict__ sa_wo,
    const float* __restrict__ ca_wq, const float* __restrict__ ca_wk,
    const float* __restrict__ ca_wv, const float* __restrict__ ca_wo,
    const float* __restrict__ ff_w1, const float* __restrict__ ff_w2,
    u16* saqkvt, u16* sawot, u16* cawqt, u16* cawot, u16* cakvt,
    u16* ffw1t, u16* ffw2t, u16* xb, u16* ctxb)
{
    __shared__ float t[32][33];
    int b = blockIdx.x;
    if (b < 2400) {
        int task = b / 400, tile = b - task * 400;
        const float* src;
        u16* dst;
        if      (task == 0) { src = sa_wq; dst = saqkvt; }
        else if (task == 1) { src = sa_wk; dst = saqkvt + 409600; }
        else if (task == 2) { src = sa_wv; dst = saqkvt + 819200; }
        else if (task == 3) { src = sa_wo; dst = sawot; }
        else if (task == 4) { src = ca_wq; dst = cawqt; }
        else                { src = ca_wo; dst = cawot; }
        transp_tile(src, dst, 640, 640, 640, tile, false, t);
    } else if (b < 3360) {
        int tt = b - 2400;
        int task = tt / 480, tile = tt - task * 480;
        transp_tile(task ? ca_wv : ca_wk, cakvt + task * 491520, 768, 640, 768,
                    tile, false, t);
    } else if (b < 6560) {
        transp_tile(ff_w1, ffw1t, 640, 5120, 640, b - 3360, true, t);
    } else if (b < 8160) {
        transp_tile(ff_w2, ffw2t, 2560, 640, 2560, b - 6560, false, t);
    } else if (b < 10720) {
        int i = (b - 8160) * 256 + threadIdx.x;     // < 655360
        const float4* p = (const float4*)x + (size_t)i * 2;
        float4 a = p[0], bb = p[1];
        uint4 w = { pack2(a.x, a.y), pack2(a.z, a.w),
                    pack2(bb.x, bb.y), pack2(bb.z, bb.w) };
        ((uint4*)xb)[i] = w;
    } else {
        int i = (b - 10720) * 256 + threadIdx.x;    // < 61440
        int rowOut = i / 96, c8 = (i - rowOut * 96) * 8;
        int bb = rowOut / 80, r = rowOut - bb * 80;
        uint4 w = {0, 0, 0, 0};
        if (r < 77) {
            const float4* p = (const float4*)(ctx + ((size_t)(bb * 77 + r)) * 768 + c8);
            float4 a = p[0], b2 = p[1];
            w = (uint4){ pack2(a.x, a.y), pack2(a.z, a.w),
                         pack2(b2.x, b2.y), pack2(b2.z, b2.w) };
        }
        ((uint4*)ctxb)[i] = w;
    }
}

// ---------------------------------------------------------------------------
// GEMM core: C[M][N] = A[M][K](bf16) @ Bt[N][K](bf16)^T, 128x128 tile, BK=64.
// ld = row stride of A and Bt in elements.
// MODE 0: outf = acc + bias[col] + b2f(resb[row*N+col])      (f32)
// MODE 1: outb = acc                                          (bf16, stride N)
// MODE 2: QKV: outb=qkvb[row*1920+col] (Q cols pre-scaled); V also -> out2=vt
// MODE 3: CA KV: rows b*80+r (r<77): col<640 -> kc; else -> vct[b,h,d,key]
// MODE 4: FF1+GEGLU: block-interleaved cols; a/gate in-thread
template<int MODE>
__device__ __forceinline__ void gemm_core(const u16* __restrict__ A,
                                          const u16* __restrict__ Bt,
                                          int N, int K, int ld,
                                          const float* __restrict__ bias,
                                          const u16* __restrict__ resb,
                                          float* __restrict__ outf,
                                          u16* __restrict__ outb,
                                          u16* __restrict__ out2,
                                          int bx, int by,
                                          u16* As, u16* Bs)
{
    const int lane = threadIdx.x & 63;
    const int wid  = threadIdx.x >> 6;
    const int q    = lane >> 4;
    const int lc   = lane & 15;
    const int wm = wid >> 1, wn = wid & 1;
    const int m0 = by * 128;
    const int n0 = bx * 128;
    const int ldb = ld * 2;               // bytes per row

    f4 acc[4][4];
    #pragma unroll
    for (int i = 0; i < 4; ++i)
        #pragma unroll
        for (int j = 0; j < 4; ++j) acc[i][j] = (f4){0.f, 0.f, 0.f, 0.f};

    const char* Abase = (const char*)A + (size_t)m0 * ldb;
    const char* Bbase = (const char*)Bt + (size_t)n0 * ldb;

    for (int kt = 0; kt < K; kt += 64) {
        #pragma unroll
        for (int c = 0; c < 4; ++c) {
            int cid = wid * 4 + c;
            int o = cid * 1024 + lane * 16;
            int row = o >> 7;
            int pc  = o & 127;
            int src = pc ^ ((row & 7) << 4);   // pre-swizzled source, linear dest
            gload16(Abase + (size_t)row * ldb + kt * 2 + src, (char*)As + cid * 1024);
            gload16(Bbase + (size_t)row * ldb + kt * 2 + src, (char*)Bs + cid * 1024);
        }
        __syncthreads();
        #pragma unroll
        for (int ks = 0; ks < 2; ++ks) {
            bfrag a[4], b[4];
            #pragma unroll
            for (int mi = 0; mi < 4; ++mi) {
                int row = wm * 64 + mi * 16 + lc;
                int off = row * 128 + ((ks * 64 + q * 16) ^ ((row & 7) << 4));
                a[mi] = *(const bfrag*)((const char*)As + off);
            }
            #pragma unroll
            for (int ni = 0; ni < 4; ++ni) {
                int row = wn * 64 + ni * 16 + lc;
                int off = row * 128 + ((ks * 64 + q * 16) ^ ((row & 7) << 4));
                b[ni] = *(const bfrag*)((const char*)Bs + off);
            }
            #pragma unroll
            for (int mi = 0; mi < 4; ++mi)
                #pragma unroll
                for (int ni = 0; ni < 4; ++ni)
                    acc[mi][ni] = MFMA(a[mi], b[ni], acc[mi][ni]);
        }
        __syncthreads();
    }

    const int baseRow = m0 + wm * 64;
    const int baseCol = n0 + wn * 64;

    if (MODE == 4) {
        const int blk = baseCol >> 6;
        #pragma unroll
        for (int mi = 0; mi < 4; ++mi)
            #pragma unroll
            for (int ni = 0; ni < 2; ++ni) {
                int j = blk * 32 + ni * 16 + lc;
                float ba = bias[j];
                float bg = bias[2560 + j];
                #pragma unroll
                for (int r = 0; r < 4; ++r) {
                    int row = baseRow + mi * 16 + q * 4 + r;
                    float aa = acc[mi][ni][r] + ba;
                    float gg = acc[mi][ni + 2][r] + bg;
                    outb[(size_t)row * 2560 + j] = f2b(aa * gelu_f(gg));
                }
            }
        return;
    }

    #pragma unroll
    for (int mi = 0; mi < 4; ++mi)
        #pragma unroll
        for (int ni = 0; ni < 4; ++ni) {
            int col = baseCol + ni * 16 + lc;
            if (MODE == 2) {
                const float qs = (col < 640) ? 0.11180339887498949f : 1.0f;
                us4 vv = {0, 0, 0, 0};
                #pragma unroll
                for (int r = 0; r < 4; ++r) {
                    int row = baseRow + mi * 16 + q * 4 + r;
                    u16 u = f2b(acc[mi][ni][r] * qs);
                    outb[(size_t)row * 1920 + col] = u;
                    vv[r] = u;
                }
                if (col >= 1280) {
                    int cd = col - 1280;
                    int hh = cd / 80, dd = cd - hh * 80;
                    int row0 = baseRow + mi * 16 + q * 4;
                    int bb = row0 >> 10, tok = row0 & 1023;
                    *(us4*)&out2[(size_t)((bb * 8 + hh) * 80 + dd) * 1024 + tok] = vv;
                }
            } else {
                #pragma unroll
                for (int r = 0; r < 4; ++r) {
                    int row = baseRow + mi * 16 + q * 4 + r;
                    float v = acc[mi][ni][r];
                    if (MODE == 0) {
                        v += bias[col] + b2f(resb[(size_t)row * N + col]);
                        outf[(size_t)row * N + col] = v;
                    } else if (MODE == 1) {
                        outb[(size_t)row * N + col] = f2b(v);
                    } else if (MODE == 3) {
                        int bb = row / 80, rr = row - bb * 80;
                        if (rr < 77) {
                            u16 u = f2b(v);
                            if (col < 640) {
                                outb[(size_t)row * 640 + col] = u;
                            } else {
                                int cd = col - 640;
                                int hh = cd / 80, dd = cd - hh * 80;
                                out2[((bb * 8 + hh) * 80 + dd) * 80 + rr] = u;
                            }
                        }
                    }
                }
            }
        }
}

template<int MODE>
__global__ __launch_bounds__(256) void gemm_bt(const u16* __restrict__ A,
                                               const u16* __restrict__ Bt,
                                               int N, int K,
                                               const float* __restrict__ bias,
                                               const u16* __restrict__ resb,
                                               float* __restrict__ outf,
                                               u16* __restrict__ outb,
                                               u16* __restrict__ out2)
{
    __shared__ u16 As[128 * 64];
    __shared__ u16 Bs[128 * 64];
    gemm_core<MODE>(A, Bt, N, K, K, bias, resb, outf, outb, out2,
                    blockIdx.x, blockIdx.y, As, Bs);
}

// fused: blocks [0,960) = QKV GEMM (MODE 2), [960,1010) = CA-KV GEMM (MODE 3)
__global__ __launch_bounds__(256) void gemm_qkv_cakv(
    const u16* __restrict__ xb, const u16* __restrict__ saqkvt,
    const u16* __restrict__ ctxb, const u16* __restrict__ cakvt,
    u16* qkvb, u16* vt, u16* kc, u16* vct)
{
    __shared__ u16 As[128 * 64];
    __shared__ u16 Bs[128 * 64];
    int bid = blockIdx.x;
    if (bid < 960) {
        gemm_core<2>(xb, saqkvt, 1920, 640, 640, nullptr, nullptr, nullptr,
                     qkvb, vt, bid % 15, bid / 15, As, Bs);
    } else {
        int tt = bid - 960;
        gemm_core<3>(ctxb, cakvt, 1280, 768, 768, nullptr, nullptr, nullptr,
                     kc, vct, tt % 10, tt / 10, As, Bs);
    }
}

// ---------------------------------------------------------------------------
// 128x64-tile GEMM for N=640 occupancy-bound shapes (projections + FF2).
// Grid (N/64, M/128) = 640 blocks. 4 waves as 2Mx2N; per-wave 64x32 (acc[4][2]).
// LDS: A = 16 chunks; B = 8 chunks; 24 total, 6 per wave.
// MODE 0: outf = acc + bias[col] + b2f(resb[row*N+col]) (f32)
// MODE 1: outb = f2b(acc)
template<int MODE>
__global__ __launch_bounds__(256) void gemm_n64(const u16* __restrict__ A,
                                                const u16* __restrict__ Bt,
                                                int N, int K,
                                                const float* __restrict__ bias,
                                                const u16* __restrict__ resb,
                                                float* __restrict__ outf,
                                                u16* __restrict__ outb)
{
    __shared__ u16 As[128 * 64];
    __shared__ u16 Bs[64 * 64];
    const int lane = threadIdx.x & 63;
    const int wid  = threadIdx.x >> 6;
    const int hi   = lane >> 4;
    const int lc   = lane & 15;
    const int wm = wid >> 1, wn = wid & 1;
    const int m0 = blockIdx.y * 128;
    const int n0 = blockIdx.x * 64;
    const int ldb = K * 2;

    f4 acc[4][2];
    #pragma unroll
    for (int i = 0; i < 4; ++i)
        #pragma unroll
        for (int j = 0; j < 2; ++j) acc[i][j] = (f4){0.f, 0.f, 0.f, 0.f};

    const char* Abase = (const char*)A + (size_t)m0 * ldb;
    const char* Bbase = (const char*)Bt + (size_t)n0 * ldb;

    for (int kt = 0; kt < K; kt += 64) {
        #pragma unroll
        for (int c = 0; c < 6; ++c) {
            int cid = wid * 6 + c;              // 24 chunks: 16 A + 8 B
            if (cid < 16) {
                int o = cid * 1024 + lane * 16;
                int row = o >> 7;
                int src = (o & 127) ^ ((row & 7) << 4);
                gload16(Abase + (size_t)row * ldb + kt * 2 + src, (char*)As + cid * 1024);
            } else {
                int c2 = cid - 16;
                int o = c2 * 1024 + lane * 16;
                int row = o >> 7;
                int src = (o & 127) ^ ((row & 7) << 4);
                gload16(Bbase + (size_t)row * ldb + kt * 2 + src, (char*)Bs + c2 * 1024);
            }
        }
        __syncthreads();
        #pragma unroll
        for (int ks = 0; ks < 2; ++ks) {
            bfrag a[4], b[2];
            #pragma unroll
            for (int mi = 0; mi < 4; ++mi) {
                int row = wm * 64 + mi * 16 + lc;
                int off = row * 128 + ((ks * 64 + hi * 16) ^ ((row & 7) << 4));
                a[mi] = *(const bfrag*)((const char*)As + off);
            }
            #pragma unroll
            for (int ni = 0; ni < 2; ++ni) {
                int row = wn * 32 + ni * 16 + lc;
                int off = row * 128 + ((ks * 64 + hi * 16) ^ ((row & 7) << 4));
                b[ni] = *(const bfrag*)((const char*)Bs + off);
            }
            #pragma unroll
            for (int mi = 0; mi < 4; ++mi)
                #pragma unroll
                for (int ni = 0; ni < 2; ++ni)
                    acc[mi][ni] = MFMA(a[mi], b[ni], acc[mi][ni]);
        }
        __syncthreads();
    }

    const int baseRow = m0 + wm * 64;
    const int baseCol = n0 + wn * 32;
    #pragma unroll
    for (int mi = 0; mi < 4; ++mi)
        #pragma unroll
        for (int ni = 0; ni < 2; ++ni) {
            int col = baseCol + ni * 16 + lc;
            #pragma unroll
            for (int r = 0; r < 4; ++r) {
                int row = baseRow + mi * 16 + hi * 4 + r;
                float v = acc[mi][ni][r];
                if (MODE == 0) {
                    v += bias[col] + b2f(resb[(size_t)row * N + col]);
                    outf[(size_t)row * N + col] = v;
                } else {
                    outb[(size_t)row * N + col] = f2b(v);
                }
            }
        }
}

// ---------------------------------------------------------------------------
// Self-attention, swapped-QK^T layout (R8 version: gload_lds staging).
__global__ __launch_bounds__(256) void attn_sa(const u16* __restrict__ qkv,
                                               const u16* __restrict__ vt,
                                               u16* __restrict__ out)
{
    __shared__ u16 Qs[64 * 80];
    __shared__ u16 Ks[64 * 80];
    __shared__ u16 Vs[80 * 64];
    __shared__ u16 Ps[4][16 * 64];

    const int lane = threadIdx.x & 63;
    const int wid  = threadIdx.x >> 6;
    const int hi   = lane >> 4;
    const int lc   = lane & 15;
    const int bid = blockIdx.x;
    const int qt = bid >> 6;
    const int bb = (bid >> 3) & 7;
    const int hh = bid & 7;
    const int tok0 = bb * 1024 + qt * 64;
    const char* qbase = (const char*)qkv;

    for (int c = wid; c < 10; c += 4) {       // stage Q [64][80]
        int o = c * 1024 + lane * 16;
        int row = o / 160, col = o - row * 160;
        gload16(qbase + (size_t)(tok0 + row) * 3840 + hh * 160 + col, (char*)Qs + c * 1024);
    }
    __syncthreads();

    const int qrow = wid * 16 + lc;
    bfrag qf0 = *(const bfrag*)((const char*)Qs + qrow * 160 + hi * 16);
    bfrag qf1 = *(const bfrag*)((const char*)Qs + qrow * 160 + 64 + hi * 16);
    bfrag qf2 = bzero();
    if (hi < 2) qf2 = *(const bfrag*)((const char*)Qs + qrow * 160 + 128 + hi * 16);

    float m = -3e30f, l = 0.f;
    f4 accO[5];
    #pragma unroll
    for (int no = 0; no < 5; ++no) accO[no] = (f4){0.f, 0.f, 0.f, 0.f};

    const float L2E = 1.4426950408889634f;

    for (int t = 0; t < 16; ++t) {
        __syncthreads();
        for (int c = wid; c < 20; c += 4) {   // stage K [64][80] + Vt [80][64]
            if (c < 10) {
                int o = c * 1024 + lane * 16;
                int row = o / 160, col = o - row * 160;
                gload16(qbase + (size_t)(bb * 1024 + t * 64 + row) * 3840 + 1280 + hh * 160 + col,
                        (char*)Ks + c * 1024);
            } else {
                int c2 = c - 10;
                int o = c2 * 1024 + lane * 16;
                int row = o >> 7;
                int pc  = o & 127;
                int src = pc ^ ((row & 7) << 4);
                gload16((const char*)vt + (size_t)((bb * 8 + hh) * 80 + row) * 2048 + t * 128 + src,
                        (char*)Vs + c2 * 1024);
            }
        }
        __syncthreads();

        f4 sT[4];
        #pragma unroll
        for (int nb = 0; nb < 4; ++nb) {
            const char* kb = (const char*)Ks + (nb * 16 + lc) * 160;
            bfrag k0 = *(const bfrag*)(kb + hi * 16);
            bfrag k1 = *(const bfrag*)(kb + 64 + hi * 16);
            bfrag k2 = bzero();
            if (hi < 2) k2 = *(const bfrag*)(kb + 128 + hi * 16);
            f4 a = {0.f, 0.f, 0.f, 0.f};
            a = MFMA(k0, qf0, a);
            a = MFMA(k1, qf1, a);
            a = MFMA(k2, qf2, a);
            sT[nb] = a;
        }

        float pm = sT[0][0];
        #pragma unroll
        for (int nb = 0; nb < 4; ++nb)
            #pragma unroll
            for (int r = 0; r < 4; ++r) pm = fmaxf(pm, sT[nb][r]);
        pm = fmaxf(pm, __shfl_xor(pm, 16));
        pm = fmaxf(pm, __shfl_xor(pm, 32));

        if (__any(pm > m + 8.0f)) {
            float mn = fmaxf(m, pm);
            float al = exp2f((m - mn) * L2E);
            m = mn;
            l *= al;
            float af[4];
            #pragma unroll
            for (int r = 0; r < 4; ++r) af[r] = __shfl(al, hi * 4 + r);
            #pragma unroll
            for (int no = 0; no < 5; ++no)
                #pragma unroll
                for (int r = 0; r < 4; ++r) accO[no][r] *= af[r];
        }

        float sum = 0.f;
        #pragma unroll
        for (int nb = 0; nb < 4; ++nb)
            #pragma unroll
            for (int r = 0; r < 4; ++r) {
                float p = exp2f((sT[nb][r] - m) * L2E);
                sT[nb][r] = p;
                sum += p;
            }
        sum += __shfl_xor(sum, 16);
        sum += __shfl_xor(sum, 32);
        l += sum;

        char* Pw = (char*)&Ps[wid][0];
        #pragma unroll
        for (int nb = 0; nb < 4; ++nb) {
            us4 pk = { f2b(sT[nb][0]), f2b(sT[nb][1]), f2b(sT[nb][2]), f2b(sT[nb][3]) };
            int cb = (nb * 16 + hi * 4) * 2;
            *(us4*)(Pw + lc * 128 + (cb ^ ((lc & 7) << 4))) = pk;
        }

        bfrag pa0 = *(const bfrag*)(Pw + lc * 128 + ((hi * 16) ^ ((lc & 7) << 4)));
        bfrag pa1 = *(const bfrag*)(Pw + lc * 128 + ((64 + hi * 16) ^ ((lc & 7) << 4)));
        #pragma unroll
        for (int no = 0; no < 5; ++no) {
            int vr = no * 16 + lc;
            const char* vb = (const char*)Vs + vr * 128;
            bfrag v0 = *(const bfrag*)(vb + ((hi * 16) ^ ((vr & 7) << 4)));
            bfrag v1 = *(const bfrag*)(vb + ((64 + hi * 16) ^ ((vr & 7) << 4)));
            accO[no] = MFMA(pa0, v0, accO[no]);
            accO[no] = MFMA(pa1, v1, accO[no]);
        }
    }

    float rf[4];
    #pragma unroll
    for (int r = 0; r < 4; ++r) {
        float lf = __shfl(l, hi * 4 + r);
        rf[r] = __builtin_amdgcn_rcpf(lf);
    }
    #pragma unroll
    for (int no = 0; no < 5; ++no)
        #pragma unroll
        for (int r = 0; r < 4; ++r) {
            int row = tok0 + wid * 16 + hi * 4 + r;
            int col = hh * 80 + no * 16 + lc;
            out[(size_t)row * 640 + col] = f2b(accO[no][r] * rf[r]);
        }
}

// ---------------------------------------------------------------------------
// Cross-attention: single KV tile (77 keys padded to 80, masked).
__global__ __launch_bounds__(256) void attn_ca(const u16* __restrict__ qc,
                                               const u16* __restrict__ kc,
                                               const u16* __restrict__ vct,
                                               u16* __restrict__ out)
{
    __shared__ u16 Qs[64 * 80];
    __shared__ u16 Ks[84 * 80];
    __shared__ u16 Vs[84 * 80];
    __shared__ u16 Ps[4][16 * 80];

    const int lane = threadIdx.x & 63;
    const int wid  = threadIdx.x >> 6;
    const int q    = lane >> 4;
    const int lc   = lane & 15;
    const int bid = blockIdx.x;
    const int qt = bid & 15;
    const int hh = (bid >> 4) & 7;
    const int bb = bid >> 7;
    const int tok0 = bb * 1024 + qt * 64;

    for (int c = wid; c < 36; c += 4) {
        if (c < 10) {
            int o = c * 1024 + lane * 16;
            int row = o / 160, col = o - row * 160;
            gload16((const char*)qc + (size_t)(tok0 + row) * 1280 + hh * 160 + col,
                    (char*)Qs + c * 1024);
        } else if (c < 23) {
            int c2 = c - 10;
            int o = c2 * 1024 + lane * 16;
            int row = o / 160, col = o - row * 160;
            gload16((const char*)kc + (size_t)(bb * 80 + row) * 1280 + hh * 160 + col,
                    (char*)Ks + c2 * 1024);
        } else {
            int c2 = c - 23;
            int o = c2 * 1024 + lane * 16;
            int row = o / 160, col = o - row * 160;
            gload16((const char*)vct + (size_t)((bb * 8 + hh) * 80 + row) * 160 + col,
                    (char*)Vs + c2 * 1024);
        }
    }
    __syncthreads();

    const int qrow = wid * 16 + lc;
    bfrag qf0 = *(const bfrag*)((const char*)Qs + qrow * 160 + q * 16);
    bfrag qf1 = *(const bfrag*)((const char*)Qs + qrow * 160 + 64 + q * 16);
    bfrag qf2 = bzero();
    if (q < 2) qf2 = *(const bfrag*)((const char*)Qs + qrow * 160 + 128 + q * 16);

    const float SC = 0.11180339887498949f;
    const float L2E = 1.4426950408889634f;

    f4 s[5];
    #pragma unroll
    for (int nb = 0; nb < 5; ++nb) {
        const char* kb = (const char*)Ks + (nb * 16 + lc) * 160;
        bfrag k0 = *(const bfrag*)(kb + q * 16);
        bfrag k1 = *(const bfrag*)(kb + 64 + q * 16);
        bfrag k2 = bzero();
        if (q < 2) k2 = *(const bfrag*)(kb + 128 + q * 16);
        f4 a = {0.f, 0.f, 0.f, 0.f};
        a = MFMA(qf0, k0, a);
        a = MFMA(qf1, k1, a);
        a = MFMA(qf2, k2, a);
        s[nb] = a;
    }
    #pragma unroll
    for (int nb = 0; nb < 5; ++nb) {
        int key = nb * 16 + lc;
        #pragma unroll
        for (int r = 0; r < 4; ++r) {
            s[nb][r] *= SC;
            if (key >= 77) s[nb][r] = -1e30f;
        }
    }
    float mrow[4], lrow[4];
    #pragma unroll
    for (int r = 0; r < 4; ++r) {
        float v = fmaxf(fmaxf(fmaxf(s[0][r], s[1][r]), fmaxf(s[2][r], s[3][r])), s[4][r]);
        v = fmaxf(v, __shfl_xor(v, 1));
        v = fmaxf(v, __shfl_xor(v, 2));
        v = fmaxf(v, __shfl_xor(v, 4));
        v = fmaxf(v, __shfl_xor(v, 8));
        mrow[r] = v;
    }
    float rsum[4] = {0.f, 0.f, 0.f, 0.f};
    #pragma unroll
    for (int nb = 0; nb < 5; ++nb)
        #pragma unroll
        for (int r = 0; r < 4; ++r) {
            float p = exp2f((s[nb][r] - mrow[r]) * L2E);
            s[nb][r] = p;
            rsum[r] += p;
        }
    #pragma unroll
    for (int r = 0; r < 4; ++r) {
        float v = rsum[r];
        v += __shfl_xor(v, 1);
        v += __shfl_xor(v, 2);
        v += __shfl_xor(v, 4);
        v += __shfl_xor(v, 8);
        lrow[r] = v;
    }

    char* Pw = (char*)&Ps[wid][0];
    #pragma unroll
    for (int nb = 0; nb < 5; ++nb)
        #pragma unroll
        for (int r = 0; r < 4; ++r) {
            int prow = q * 4 + r;
            *(u16*)(Pw + prow * 160 + (nb * 16 + lc) * 2) = f2b(s[nb][r]);
        }
    bfrag pa0 = *(const bfrag*)(Pw + lc * 160 + q * 16);
    bfrag pa1 = *(const bfrag*)(Pw + lc * 160 + 64 + q * 16);
    bfrag pa2 = bzero();
    if (q < 2) pa2 = *(const bfrag*)(Pw + lc * 160 + 128 + q * 16);

    f4 accO[5];
    #pragma unroll
    for (int no = 0; no < 5; ++no) {
        const char* vb = (const char*)Vs + (no * 16 + lc) * 160;
        bfrag v0 = *(const bfrag*)(vb + q * 16);
        bfrag v1 = *(const bfrag*)(vb + 64 + q * 16);
        bfrag v2 = bzero();
        if (q < 2) v2 = *(const bfrag*)(vb + 128 + q * 16);
        f4 a = {0.f, 0.f, 0.f, 0.f};
        a = MFMA(pa0, v0, a);
        a = MFMA(pa1, v1, a);
        a = MFMA(pa2, v2, a);
        accO[no] = a;
    }
    #pragma unroll
    for (int no = 0; no < 5; ++no)
        #pragma unroll
        for (int r = 0; r < 4; ++r) {
            int row = tok0 + wid * 16 + q * 4 + r;
            int col = hh * 80 + no * 16 + lc;
            out[(size_t)row * 640 + col] = f2b(accO[no][r] / lrow[r]);
        }
}

// ---------------------------------------------------------------------------
// LayerNorm over 640 cols; 1 wave per row, 4 rows per block.
__global__ __launch_bounds__(256) void ln_k(const float* __restrict__ pre,
                                            const float* __restrict__ g,
                                            const float* __restrict__ b,
                                            float* __restrict__ xo,
                                            u16* __restrict__ xb)
{
    const int lane = threadIdx.x & 63;
    const int wid  = threadIdx.x >> 6;
    const int row = blockIdx.x * 4 + wid;
    const float* p = pre + (size_t)row * 640;
    float v[10];
    #pragma unroll
    for (int i = 0; i < 10; ++i) v[i] = p[lane + i * 64];
    float s = 0.f;
    #pragma unroll
    for (int i = 0; i < 10; ++i) s += v[i];
    #pragma unroll
    for (int m = 1; m < 64; m <<= 1) s += __shfl_xor(s, m);
    float mu = s * (1.0f / 640.0f);
    float d2 = 0.f;
    #pragma unroll
    for (int i = 0; i < 10; ++i) { float d = v[i] - mu; d2 += d * d; }
    #pragma unroll
    for (int m = 1; m < 64; m <<= 1) d2 += __shfl_xor(d2, m);
    float rs = rsqrtf(d2 * (1.0f / 640.0f) + 1e-5f);
    #pragma unroll
    for (int i = 0; i < 10; ++i) {
        int col = lane + i * 64;
        float y = (v[i] - mu) * rs * g[col] + b[col];
        if (xo) xo[(size_t)row * 640 + col] = y;
        if (xb) xb[(size_t)row * 640 + col] = f2b(y);
    }
}

// ---------------------------------------------------------------------------
extern "C" void kernel_launch(void* const* d_in, const int* in_sizes, int n_in,
                              void* d_out, int out_size, void* d_ws, size_t ws_size,
                              hipStream_t stream)
{
    const float* x       = (const float*)d_in[0];
    const float* context = (const float*)d_in[1];
    const float* sa_wq = (const float*)d_in[2];
    const float* sa_wk = (const float*)d_in[3];
    const float* sa_wv = (const float*)d_in[4];
    const float* sa_wo = (const float*)d_in[5];
    const float* sa_bo = (const float*)d_in[6];
    const float* ca_wq = (const float*)d_in[7];
    const float* ca_wk = (const float*)d_in[8];
    const float* ca_wv = (const float*)d_in[9];
    const float* ca_wo = (const float*)d_in[10];
    const float* ca_bo = (const float*)d_in[11];
    const float* ff_w1 = (const float*)d_in[12];
    const float* ff_b1 = (const float*)d_in[13];
    const float* ff_w2 = (const float*)d_in[14];
    const float* ff_b2 = (const float*)d_in[15];
    const float* ln1_g = (const float*)d_in[16];
    const float* ln1_b = (const float*)d_in[17];
    const float* ln2_g = (const float*)d_in[18];
    const float* ln2_b = (const float*)d_in[19];
    const float* ln3_g = (const float*)d_in[20];
    const float* ln3_b = (const float*)d_in[21];

    char* ws = (char*)d_ws;
    const size_t OFF_XB     = 0;
    const size_t OFF_QKVB   = 10485760;
    const size_t OFF_VT     = 41943040;
    const size_t OFF_AB     = 52428800;
    const size_t OFF_ATTN   = 62914560;
    const size_t OFF_QC     = 73400320;
    const size_t OFF_KC     = 83886080;
    const size_t OFF_VCT    = 84705280;
    const size_t OFF_SAQKVT = 85524480;
    const size_t OFF_SAWOT  = 87982080;
    const size_t OFF_CAWQT  = 88801280;
    const size_t OFF_CAKVT  = 89620480;
    const size_t OFF_CAWOT  = 91586560;
    const size_t OFF_FFW1T  = 92405760;
    const size_t OFF_FFW2T  = 98959360;
    const size_t OFF_CTXB   = 102236160;
    const size_t OFF_PRE    = 103219200;    // f32, 20971520 B

    u16* xb      = (u16*)(ws + OFF_XB);
    u16* qkvb    = (u16*)(ws + OFF_QKVB);
    u16* vt      = (u16*)(ws + OFF_VT);
    u16* ab      = (u16*)(ws + OFF_AB);
    u16* attnb   = (u16*)(ws + OFF_ATTN);
    u16* qc      = (u16*)(ws + OFF_QC);
    u16* kc      = (u16*)(ws + OFF_KC);
    u16* vct     = (u16*)(ws + OFF_VCT);
    u16* saqkvt  = (u16*)(ws + OFF_SAQKVT);
    u16* sawot   = (u16*)(ws + OFF_SAWOT);
    u16* cawqt   = (u16*)(ws + OFF_CAWQT);
    u16* cakvt   = (u16*)(ws + OFF_CAKVT);
    u16* cawot   = (u16*)(ws + OFF_CAWOT);
    u16* ffw1t   = (u16*)(ws + OFF_FFW1T);
    u16* ffw2t   = (u16*)(ws + OFF_FFW2T);
    u16* ctxb    = (u16*)(ws + OFF_CTXB);
    float* pre   = (float*)(ws + OFF_PRE);
    u16* ffh     = (u16*)(ws + OFF_XB);          // aliases xb+qkvb

    // --- prep: all transposes + conversions, one dispatch ---
    hipLaunchKernelGGL(prep_k, dim3(10960), dim3(256), 0, stream,
                       x, context, sa_wq, sa_wk, sa_wv, sa_wo, ca_wq, ca_wk,
                       ca_wv, ca_wo, ff_w1, ff_w2,
                       saqkvt, sawot, cawqt, cawot, cakvt, ffw1t, ffw2t, xb, ctxb);

    // --- self-attention (QKV fused with CA-KV) ---
    hipLaunchKernelGGL(gemm_qkv_cakv, dim3(1010), dim3(256), 0, stream,
                       xb, saqkvt, ctxb, cakvt, qkvb, vt, kc, vct);
    hipLaunchKernelGGL(attn_sa, dim3(1024), dim3(256), 0, stream, qkvb, vt, attnb);
    hipLaunchKernelGGL(gemm_n64<0>, dim3(10, 64), dim3(256), 0, stream,
                       attnb, sawot, 640, 640, sa_bo, xb, pre, (u16*)nullptr);
    hipLaunchKernelGGL(ln_k, dim3(2048), dim3(256), 0, stream, pre, ln1_g, ln1_b,
                       (float*)nullptr, ab);

    // --- cross-attention ---
    hipLaunchKernelGGL(gemm_n64<1>, dim3(10, 64), dim3(256), 0, stream,
                       ab, cawqt, 640, 640, (const float*)nullptr, (const u16*)nullptr,
                       (float*)nullptr, qc);
    hipLaunchKernelGGL(attn_ca, dim3(1024), dim3(256), 0, stream, qc, kc, vct, attnb);
    hipLaunchKernelGGL(gemm_n64<0>, dim3(10, 64), dim3(256), 0, stream,
                       attnb, cawot, 640, 640, ca_bo, ab, pre, (u16*)nullptr);
    hipLaunchKernelGGL(ln_k, dim3(2048), dim3(256), 0, stream, pre, ln2_g, ln2_b,
                       (float*)nullptr, ab);

    // --- GEGLU FFN ---
    hipLaunchKernelGGL(gemm_bt<4>, dim3(40, 64), dim3(256), 0, stream,
                       ab, ffw1t, 5120, 640, ff_b1, (const u16*)nullptr,
                       (float*)nullptr, ffh, (u16*)nullptr);
    hipLaunchKernelGGL(gemm_n64<0>, dim3(10, 64), dim3(256), 0, stream,
                       ffh, ffw2t, 640, 2560, ff_b2, ab, pre, (u16*)nullptr);
    hipLaunchKernelGGL(ln_k, dim3(2048), dim3(256), 0, stream, pre, ln3_g, ln3_b,
                       (float*)d_out, (u16*)nullptr);
}

// Round 11
// 342.368 us; speedup vs baseline: 1.2004x; 1.0185x over previous
//
#include <hip/hip_runtime.h>

// BasicTransformerBlock on gfx950, bf16 MFMA implementation.
// R11: bf16 psum for all residual+LN stages (gemm epilogue stores f2b(sum);
//      ln_kb reads bf16 psum with vectorized loads). Saves ~60MB f32 traffic.
//      Everything else identical to R10 (best: 348.7us).

using u16 = unsigned short;
typedef __attribute__((ext_vector_type(8))) short bfrag;   // 8 bf16 (4 VGPR)
typedef __attribute__((ext_vector_type(4))) float f4;
typedef __attribute__((ext_vector_type(4))) unsigned short us4;

#define MFMA(a, b, c) __builtin_amdgcn_mfma_f32_16x16x32_bf16((a), (b), (c), 0, 0, 0)

__device__ __forceinline__ void gload16(const void* g, void* l) {
    // async global->LDS, 16B per lane; LDS dest = uniform base + lane*16
    __builtin_amdgcn_global_load_lds(
        (const __attribute__((address_space(1))) void*)g,
        (__attribute__((address_space(3))) void*)l, 16, 0, 0);
}

__device__ __forceinline__ u16 f2b(float f) {   // f32 -> bf16 RNE
    unsigned u = __float_as_uint(f);
    unsigned r = u + 0x7FFFu + ((u >> 16) & 1u);
    return (u16)(r >> 16);
}
__device__ __forceinline__ float b2f(u16 u) {
    return __uint_as_float(((unsigned)u) << 16);
}
__device__ __forceinline__ unsigned pack2(float a, float b) {
    return (unsigned)f2b(a) | ((unsigned)f2b(b) << 16);
}
__device__ __forceinline__ bfrag bzero() {
    bfrag z = {0,0,0,0,0,0,0,0};
    return z;
}
// gelu: 0.5x(1+tanh(0.79788456(x+0.044715x^3))), tanh via e^{2y}
__device__ __forceinline__ float gelu_f(float x) {
    float y = 0.7978845608028654f * (x + 0.044715f * x * x * x);
    float e = exp2f(y * 2.8853900817779268f);          // e^{2y}
    float t = 1.0f - 2.0f * __builtin_amdgcn_rcpf(e + 1.0f);
    return 0.5f * x * (1.0f + t);
}

// ---------------------------------------------------------------------------
// prep mega-kernel: all weight transposes + input conversions in ONE dispatch.
__device__ __forceinline__ void transp_tile(const float* __restrict__ in,
                                            u16* __restrict__ out,
                                            int K, int N, int ldo,
                                            int tile, bool perm,
                                            float (*t)[33])
{
    int nw = N >> 5;
    int n0 = (tile % nw) * 32, k0 = (tile / nw) * 32;
    int tx = threadIdx.x & 31, ty = threadIdx.x >> 5;
    #pragma unroll
    for (int i = 0; i < 32; i += 8)
        t[ty + i][tx] = in[(size_t)(k0 + ty + i) * N + n0 + tx];
    __syncthreads();
    #pragma unroll
    for (int i = 0; i < 32; i += 8) {
        int n = n0 + ty + i;
        int dst;
        if (perm) {
            dst = (n < 2560) ? ((n >> 5) * 64 + (n & 31))
                             : (((n - 2560) >> 5) * 64 + 32 + ((n - 2560) & 31));
        } else {
            dst = n;
        }
        out[(size_t)dst * ldo + k0 + tx] = f2b(t[tx][ty + i]);
    }
}

__global__ __launch_bounds__(256) void prep_k(
    const float* __restrict__ x, const float* __restrict__ ctx,
    const float* __restrict__ sa_wq, const float* __restrict__ sa_wk,
    const float* __restrict__ sa_wv, const float* __restrict__ sa_wo,
    const float* __restrict__ ca_wq, const float* __restrict__ ca_wk,
    const float* __restrict__ ca_wv, const float* __restrict__ ca_wo,
    const float* __restrict__ ff_w1, const float* __restrict__ ff_w2,
    u16* saqkvt, u16* sawot, u16* cawqt, u16* cawot, u16* cakvt,
    u16* ffw1t, u16* ffw2t, u16* xb, u16* ctxb)
{
    __shared__ float t[32][33];
    int b = blockIdx.x;
    if (b < 2400) {
        int task = b / 400, tile = b - task * 400;
        const float* src;
        u16* dst;
        if      (task == 0) { src = sa_wq; dst = saqkvt; }
        else if (task == 1) { src = sa_wk; dst = saqkvt + 409600; }
        else if (task == 2) { src = sa_wv; dst = saqkvt + 819200; }
        else if (task == 3) { src = sa_wo; dst = sawot; }
        else if (task == 4) { src = ca_wq; dst = cawqt; }
        else                { src = ca_wo; dst = cawot; }
        transp_tile(src, dst, 640, 640, 640, tile, false, t);
    } else if (b < 3360) {
        int tt = b - 2400;
        int task = tt / 480, tile = tt - task * 480;
        transp_tile(task ? ca_wv : ca_wk, cakvt + task * 491520, 768, 640, 768,
                    tile, false, t);
    } else if (b < 6560) {
        transp_tile(ff_w1, ffw1t, 640, 5120, 640, b - 3360, true, t);
    } else if (b < 8160) {
        transp_tile(ff_w2, ffw2t, 2560, 640, 2560, b - 6560, false, t);
    } else if (b < 10720) {
        int i = (b - 8160) * 256 + threadIdx.x;     // < 655360
        const float4* p = (const float4*)x + (size_t)i * 2;
        float4 a = p[0], bb = p[1];
        uint4 w = { pack2(a.x, a.y), pack2(a.z, a.w),
                    pack2(bb.x, bb.y), pack2(bb.z, bb.w) };
        ((uint4*)xb)[i] = w;
    } else {
        int i = (b - 10720) * 256 + threadIdx.x;    // < 61440
        int rowOut = i / 96, c8 = (i - rowOut * 96) * 8;
        int bb = rowOut / 80, r = rowOut - bb * 80;
        uint4 w = {0, 0, 0, 0};
        if (r < 77) {
            const float4* p = (const float4*)(ctx + ((size_t)(bb * 77 + r)) * 768 + c8);
            float4 a = p[0], b2 = p[1];
            w = (uint4){ pack2(a.x, a.y), pack2(a.z, a.w),
                         pack2(b2.x, b2.y), pack2(b2.z, b2.w) };
        }
        ((uint4*)ctxb)[i] = w;
    }
}

// ---------------------------------------------------------------------------
// GEMM core: C[M][N] = A[M][K](bf16) @ Bt[N][K](bf16)^T, 128x128 tile, BK=64.
// MODE 1: outb = acc (bf16)
// MODE 2: QKV; MODE 3: CA KV; MODE 4: FF1+GEGLU
template<int MODE>
__device__ __forceinline__ void gemm_core(const u16* __restrict__ A,
                                          const u16* __restrict__ Bt,
                                          int N, int K, int ld,
                                          const float* __restrict__ bias,
                                          const u16* __restrict__ resb,
                                          float* __restrict__ outf,
                                          u16* __restrict__ outb,
                                          u16* __restrict__ out2,
                                          int bx, int by,
                                          u16* As, u16* Bs)
{
    const int lane = threadIdx.x & 63;
    const int wid  = threadIdx.x >> 6;
    const int q    = lane >> 4;
    const int lc   = lane & 15;
    const int wm = wid >> 1, wn = wid & 1;
    const int m0 = by * 128;
    const int n0 = bx * 128;
    const int ldb = ld * 2;               // bytes per row

    f4 acc[4][4];
    #pragma unroll
    for (int i = 0; i < 4; ++i)
        #pragma unroll
        for (int j = 0; j < 4; ++j) acc[i][j] = (f4){0.f, 0.f, 0.f, 0.f};

    const char* Abase = (const char*)A + (size_t)m0 * ldb;
    const char* Bbase = (const char*)Bt + (size_t)n0 * ldb;

    for (int kt = 0; kt < K; kt += 64) {
        #pragma unroll
        for (int c = 0; c < 4; ++c) {
            int cid = wid * 4 + c;
            int o = cid * 1024 + lane * 16;
            int row = o >> 7;
            int pc  = o & 127;
            int src = pc ^ ((row & 7) << 4);   // pre-swizzled source, linear dest
            gload16(Abase + (size_t)row * ldb + kt * 2 + src, (char*)As + cid * 1024);
            gload16(Bbase + (size_t)row * ldb + kt * 2 + src, (char*)Bs + cid * 1024);
        }
        __syncthreads();
        #pragma unroll
        for (int ks = 0; ks < 2; ++ks) {
            bfrag a[4], b[4];
            #pragma unroll
            for (int mi = 0; mi < 4; ++mi) {
                int row = wm * 64 + mi * 16 + lc;
                int off = row * 128 + ((ks * 64 + q * 16) ^ ((row & 7) << 4));
                a[mi] = *(const bfrag*)((const char*)As + off);
            }
            #pragma unroll
            for (int ni = 0; ni < 4; ++ni) {
                int row = wn * 64 + ni * 16 + lc;
                int off = row * 128 + ((ks * 64 + q * 16) ^ ((row & 7) << 4));
                b[ni] = *(const bfrag*)((const char*)Bs + off);
            }
            #pragma unroll
            for (int mi = 0; mi < 4; ++mi)
                #pragma unroll
                for (int ni = 0; ni < 4; ++ni)
                    acc[mi][ni] = MFMA(a[mi], b[ni], acc[mi][ni]);
        }
        __syncthreads();
    }

    const int baseRow = m0 + wm * 64;
    const int baseCol = n0 + wn * 64;

    if (MODE == 4) {
        const int blk = baseCol >> 6;
        #pragma unroll
        for (int mi = 0; mi < 4; ++mi)
            #pragma unroll
            for (int ni = 0; ni < 2; ++ni) {
                int j = blk * 32 + ni * 16 + lc;
                float ba = bias[j];
                float bg = bias[2560 + j];
                #pragma unroll
                for (int r = 0; r < 4; ++r) {
                    int row = baseRow + mi * 16 + q * 4 + r;
                    float aa = acc[mi][ni][r] + ba;
                    float gg = acc[mi][ni + 2][r] + bg;
                    outb[(size_t)row * 2560 + j] = f2b(aa * gelu_f(gg));
                }
            }
        return;
    }

    #pragma unroll
    for (int mi = 0; mi < 4; ++mi)
        #pragma unroll
        for (int ni = 0; ni < 4; ++ni) {
            int col = baseCol + ni * 16 + lc;
            if (MODE == 2) {
                const float qs = (col < 640) ? 0.11180339887498949f : 1.0f;
                us4 vv = {0, 0, 0, 0};
                #pragma unroll
                for (int r = 0; r < 4; ++r) {
                    int row = baseRow + mi * 16 + q * 4 + r;
                    u16 u = f2b(acc[mi][ni][r] * qs);
                    outb[(size_t)row * 1920 + col] = u;
                    vv[r] = u;
                }
                if (col >= 1280) {
                    int cd = col - 1280;
                    int hh = cd / 80, dd = cd - hh * 80;
                    int row0 = baseRow + mi * 16 + q * 4;
                    int bb = row0 >> 10, tok = row0 & 1023;
                    *(us4*)&out2[(size_t)((bb * 8 + hh) * 80 + dd) * 1024 + tok] = vv;
                }
            } else {
                #pragma unroll
                for (int r = 0; r < 4; ++r) {
                    int row = baseRow + mi * 16 + q * 4 + r;
                    float v = acc[mi][ni][r];
                    if (MODE == 1) {
                        outb[(size_t)row * N + col] = f2b(v);
                    } else if (MODE == 3) {
                        int bb = row / 80, rr = row - bb * 80;
                        if (rr < 77) {
                            u16 u = f2b(v);
                            if (col < 640) {
                                outb[(size_t)row * 640 + col] = u;
                            } else {
                                int cd = col - 640;
                                int hh = cd / 80, dd = cd - hh * 80;
                                out2[((bb * 8 + hh) * 80 + dd) * 80 + rr] = u;
                            }
                        }
                    }
                }
            }
        }
}

template<int MODE>
__global__ __launch_bounds__(256) void gemm_bt(const u16* __restrict__ A,
                                               const u16* __restrict__ Bt,
                                               int N, int K,
                                               const float* __restrict__ bias,
                                               const u16* __restrict__ resb,
                                               float* __restrict__ outf,
                                               u16* __restrict__ outb,
                                               u16* __restrict__ out2)
{
    __shared__ u16 As[128 * 64];
    __shared__ u16 Bs[128 * 64];
    gemm_core<MODE>(A, Bt, N, K, K, bias, resb, outf, outb, out2,
                    blockIdx.x, blockIdx.y, As, Bs);
}

// fused: blocks [0,960) = QKV GEMM (MODE 2), [960,1010) = CA-KV GEMM (MODE 3)
__global__ __launch_bounds__(256) void gemm_qkv_cakv(
    const u16* __restrict__ xb, const u16* __restrict__ saqkvt,
    const u16* __restrict__ ctxb, const u16* __restrict__ cakvt,
    u16* qkvb, u16* vt, u16* kc, u16* vct)
{
    __shared__ u16 As[128 * 64];
    __shared__ u16 Bs[128 * 64];
    int bid = blockIdx.x;
    if (bid < 960) {
        gemm_core<2>(xb, saqkvt, 1920, 640, 640, nullptr, nullptr, nullptr,
                     qkvb, vt, bid % 15, bid / 15, As, Bs);
    } else {
        int tt = bid - 960;
        gemm_core<3>(ctxb, cakvt, 1280, 768, 768, nullptr, nullptr, nullptr,
                     kc, vct, tt % 10, tt / 10, As, Bs);
    }
}

// ---------------------------------------------------------------------------
// 128x64-tile GEMM for N=640 occupancy-bound shapes (projections + FF2).
// Grid (N/64, M/128) = 640 blocks. 4 waves as 2Mx2N; per-wave 64x32 (acc[4][2]).
// MODE 0: outb = f2b(acc + bias[col] + b2f(resb[row*N+col]))  (bf16 psum)
// MODE 1: outb = f2b(acc)
template<int MODE>
__global__ __launch_bounds__(256) void gemm_n64(const u16* __restrict__ A,
                                                const u16* __restrict__ Bt,
                                                int N, int K,
                                                const float* __restrict__ bias,
                                                const u16* __restrict__ resb,
                                                u16* __restrict__ outb)
{
    __shared__ u16 As[128 * 64];
    __shared__ u16 Bs[64 * 64];
    const int lane = threadIdx.x & 63;
    const int wid  = threadIdx.x >> 6;
    const int hi   = lane >> 4;
    const int lc   = lane & 15;
    const int wm = wid >> 1, wn = wid & 1;
    const int m0 = blockIdx.y * 128;
    const int n0 = blockIdx.x * 64;
    const int ldb = K * 2;

    f4 acc[4][2];
    #pragma unroll
    for (int i = 0; i < 4; ++i)
        #pragma unroll
        for (int j = 0; j < 2; ++j) acc[i][j] = (f4){0.f, 0.f, 0.f, 0.f};

    const char* Abase = (const char*)A + (size_t)m0 * ldb;
    const char* Bbase = (const char*)Bt + (size_t)n0 * ldb;

    for (int kt = 0; kt < K; kt += 64) {
        #pragma unroll
        for (int c = 0; c < 6; ++c) {
            int cid = wid * 6 + c;              // 24 chunks: 16 A + 8 B
            if (cid < 16) {
                int o = cid * 1024 + lane * 16;
                int row = o >> 7;
                int src = (o & 127) ^ ((row & 7) << 4);
                gload16(Abase + (size_t)row * ldb + kt * 2 + src, (char*)As + cid * 1024);
            } else {
                int c2 = cid - 16;
                int o = c2 * 1024 + lane * 16;
                int row = o >> 7;
                int src = (o & 127) ^ ((row & 7) << 4);
                gload16(Bbase + (size_t)row * ldb + kt * 2 + src, (char*)Bs + c2 * 1024);
            }
        }
        __syncthreads();
        #pragma unroll
        for (int ks = 0; ks < 2; ++ks) {
            bfrag a[4], b[2];
            #pragma unroll
            for (int mi = 0; mi < 4; ++mi) {
                int row = wm * 64 + mi * 16 + lc;
                int off = row * 128 + ((ks * 64 + hi * 16) ^ ((row & 7) << 4));
                a[mi] = *(const bfrag*)((const char*)As + off);
            }
            #pragma unroll
            for (int ni = 0; ni < 2; ++ni) {
                int row = wn * 32 + ni * 16 + lc;
                int off = row * 128 + ((ks * 64 + hi * 16) ^ ((row & 7) << 4));
                b[ni] = *(const bfrag*)((const char*)Bs + off);
            }
            #pragma unroll
            for (int mi = 0; mi < 4; ++mi)
                #pragma unroll
                for (int ni = 0; ni < 2; ++ni)
                    acc[mi][ni] = MFMA(a[mi], b[ni], acc[mi][ni]);
        }
        __syncthreads();
    }

    const int baseRow = m0 + wm * 64;
    const int baseCol = n0 + wn * 32;
    #pragma unroll
    for (int mi = 0; mi < 4; ++mi)
        #pragma unroll
        for (int ni = 0; ni < 2; ++ni) {
            int col = baseCol + ni * 16 + lc;
            #pragma unroll
            for (int r = 0; r < 4; ++r) {
                int row = baseRow + mi * 16 + hi * 4 + r;
                float v = acc[mi][ni][r];
                if (MODE == 0)
                    v += bias[col] + b2f(resb[(size_t)row * N + col]);
                outb[(size_t)row * N + col] = f2b(v);
            }
        }
}

// ---------------------------------------------------------------------------
// Self-attention, swapped-QK^T layout (R8 version: gload_lds staging).
__global__ __launch_bounds__(256) void attn_sa(const u16* __restrict__ qkv,
                                               const u16* __restrict__ vt,
                                               u16* __restrict__ out)
{
    __shared__ u16 Qs[64 * 80];
    __shared__ u16 Ks[64 * 80];
    __shared__ u16 Vs[80 * 64];
    __shared__ u16 Ps[4][16 * 64];

    const int lane = threadIdx.x & 63;
    const int wid  = threadIdx.x >> 6;
    const int hi   = lane >> 4;
    const int lc   = lane & 15;
    const int bid = blockIdx.x;
    const int qt = bid >> 6;
    const int bb = (bid >> 3) & 7;
    const int hh = bid & 7;
    const int tok0 = bb * 1024 + qt * 64;
    const char* qbase = (const char*)qkv;

    for (int c = wid; c < 10; c += 4) {       // stage Q [64][80]
        int o = c * 1024 + lane * 16;
        int row = o / 160, col = o - row * 160;
        gload16(qbase + (size_t)(tok0 + row) * 3840 + hh * 160 + col, (char*)Qs + c * 1024);
    }
    __syncthreads();

    const int qrow = wid * 16 + lc;
    bfrag qf0 = *(const bfrag*)((const char*)Qs + qrow * 160 + hi * 16);
    bfrag qf1 = *(const bfrag*)((const char*)Qs + qrow * 160 + 64 + hi * 16);
    bfrag qf2 = bzero();
    if (hi < 2) qf2 = *(const bfrag*)((const char*)Qs + qrow * 160 + 128 + hi * 16);

    float m = -3e30f, l = 0.f;
    f4 accO[5];
    #pragma unroll
    for (int no = 0; no < 5; ++no) accO[no] = (f4){0.f, 0.f, 0.f, 0.f};

    const float L2E = 1.4426950408889634f;

    for (int t = 0; t < 16; ++t) {
        __syncthreads();
        for (int c = wid; c < 20; c += 4) {   // stage K [64][80] + Vt [80][64]
            if (c < 10) {
                int o = c * 1024 + lane * 16;
                int row = o / 160, col = o - row * 160;
                gload16(qbase + (size_t)(bb * 1024 + t * 64 + row) * 3840 + 1280 + hh * 160 + col,
                        (char*)Ks + c * 1024);
            } else {
                int c2 = c - 10;
                int o = c2 * 1024 + lane * 16;
                int row = o >> 7;
                int pc  = o & 127;
                int src = pc ^ ((row & 7) << 4);
                gload16((const char*)vt + (size_t)((bb * 8 + hh) * 80 + row) * 2048 + t * 128 + src,
                        (char*)Vs + c2 * 1024);
            }
        }
        __syncthreads();

        f4 sT[4];
        #pragma unroll
        for (int nb = 0; nb < 4; ++nb) {
            const char* kb = (const char*)Ks + (nb * 16 + lc) * 160;
            bfrag k0 = *(const bfrag*)(kb + hi * 16);
            bfrag k1 = *(const bfrag*)(kb + 64 + hi * 16);
            bfrag k2 = bzero();
            if (hi < 2) k2 = *(const bfrag*)(kb + 128 + hi * 16);
            f4 a = {0.f, 0.f, 0.f, 0.f};
            a = MFMA(k0, qf0, a);
            a = MFMA(k1, qf1, a);
            a = MFMA(k2, qf2, a);
            sT[nb] = a;
        }

        float pm = sT[0][0];
        #pragma unroll
        for (int nb = 0; nb < 4; ++nb)
            #pragma unroll
            for (int r = 0; r < 4; ++r) pm = fmaxf(pm, sT[nb][r]);
        pm = fmaxf(pm, __shfl_xor(pm, 16));
        pm = fmaxf(pm, __shfl_xor(pm, 32));

        if (__any(pm > m + 8.0f)) {
            float mn = fmaxf(m, pm);
            float al = exp2f((m - mn) * L2E);
            m = mn;
            l *= al;
            float af[4];
            #pragma unroll
            for (int r = 0; r < 4; ++r) af[r] = __shfl(al, hi * 4 + r);
            #pragma unroll
            for (int no = 0; no < 5; ++no)
                #pragma unroll
                for (int r = 0; r < 4; ++r) accO[no][r] *= af[r];
        }

        float sum = 0.f;
        #pragma unroll
        for (int nb = 0; nb < 4; ++nb)
            #pragma unroll
            for (int r = 0; r < 4; ++r) {
                float p = exp2f((sT[nb][r] - m) * L2E);
                sT[nb][r] = p;
                sum += p;
            }
        sum += __shfl_xor(sum, 16);
        sum += __shfl_xor(sum, 32);
        l += sum;

        char* Pw = (char*)&Ps[wid][0];
        #pragma unroll
        for (int nb = 0; nb < 4; ++nb) {
            us4 pk = { f2b(sT[nb][0]), f2b(sT[nb][1]), f2b(sT[nb][2]), f2b(sT[nb][3]) };
            int cb = (nb * 16 + hi * 4) * 2;
            *(us4*)(Pw + lc * 128 + (cb ^ ((lc & 7) << 4))) = pk;
        }

        bfrag pa0 = *(const bfrag*)(Pw + lc * 128 + ((hi * 16) ^ ((lc & 7) << 4)));
        bfrag pa1 = *(const bfrag*)(Pw + lc * 128 + ((64 + hi * 16) ^ ((lc & 7) << 4)));
        #pragma unroll
        for (int no = 0; no < 5; ++no) {
            int vr = no * 16 + lc;
            const char* vb = (const char*)Vs + vr * 128;
            bfrag v0 = *(const bfrag*)(vb + ((hi * 16) ^ ((vr & 7) << 4)));
            bfrag v1 = *(const bfrag*)(vb + ((64 + hi * 16) ^ ((vr & 7) << 4)));
            accO[no] = MFMA(pa0, v0, accO[no]);
            accO[no] = MFMA(pa1, v1, accO[no]);
        }
    }

    float rf[4];
    #pragma unroll
    for (int r = 0; r < 4; ++r) {
        float lf = __shfl(l, hi * 4 + r);
        rf[r] = __builtin_amdgcn_rcpf(lf);
    }
    #pragma unroll
    for (int no = 0; no < 5; ++no)
        #pragma unroll
        for (int r = 0; r < 4; ++r) {
            int row = tok0 + wid * 16 + hi * 4 + r;
            int col = hh * 80 + no * 16 + lc;
            out[(size_t)row * 640 + col] = f2b(accO[no][r] * rf[r]);
        }
}

// ---------------------------------------------------------------------------
// Cross-attention: single KV tile (77 keys padded to 80, masked).
__global__ __launch_bounds__(256) void attn_ca(const u16* __restrict__ qc,
                                               const u16* __restrict__ kc,
                                               const u16* __restrict__ vct,
                                               u16* __restrict__ out)
{
    __shared__ u16 Qs[64 * 80];
    __shared__ u16 Ks[84 * 80];
    __shared__ u16 Vs[84 * 80];
    __shared__ u16 Ps[4][16 * 80];

    const int lane = threadIdx.x & 63;
    const int wid  = threadIdx.x >> 6;
    const int q    = lane >> 4;
    const int lc   = lane & 15;
    const int bid = blockIdx.x;
    const int qt = bid & 15;
    const int hh = (bid >> 4) & 7;
    const int bb = bid >> 7;
    const int tok0 = bb * 1024 + qt * 64;

    for (int c = wid; c < 36; c += 4) {
        if (c < 10) {
            int o = c * 1024 + lane * 16;
            int row = o / 160, col = o - row * 160;
            gload16((const char*)qc + (size_t)(tok0 + row) * 1280 + hh * 160 + col,
                    (char*)Qs + c * 1024);
        } else if (c < 23) {
            int c2 = c - 10;
            int o = c2 * 1024 + lane * 16;
            int row = o / 160, col = o - row * 160;
            gload16((const char*)kc + (size_t)(bb * 80 + row) * 1280 + hh * 160 + col,
                    (char*)Ks + c2 * 1024);
        } else {
            int c2 = c - 23;
            int o = c2 * 1024 + lane * 16;
            int row = o / 160, col = o - row * 160;
            gload16((const char*)vct + (size_t)((bb * 8 + hh) * 80 + row) * 160 + col,
                    (char*)Vs + c2 * 1024);
        }
    }
    __syncthreads();

    const int qrow = wid * 16 + lc;
    bfrag qf0 = *(const bfrag*)((const char*)Qs + qrow * 160 + q * 16);
    bfrag qf1 = *(const bfrag*)((const char*)Qs + qrow * 160 + 64 + q * 16);
    bfrag qf2 = bzero();
    if (q < 2) qf2 = *(const bfrag*)((const char*)Qs + qrow * 160 + 128 + q * 16);

    const float SC = 0.11180339887498949f;
    const float L2E = 1.4426950408889634f;

    f4 s[5];
    #pragma unroll
    for (int nb = 0; nb < 5; ++nb) {
        const char* kb = (const char*)Ks + (nb * 16 + lc) * 160;
        bfrag k0 = *(const bfrag*)(kb + q * 16);
        bfrag k1 = *(const bfrag*)(kb + 64 + q * 16);
        bfrag k2 = bzero();
        if (q < 2) k2 = *(const bfrag*)(kb + 128 + q * 16);
        f4 a = {0.f, 0.f, 0.f, 0.f};
        a = MFMA(qf0, k0, a);
        a = MFMA(qf1, k1, a);
        a = MFMA(qf2, k2, a);
        s[nb] = a;
    }
    #pragma unroll
    for (int nb = 0; nb < 5; ++nb) {
        int key = nb * 16 + lc;
        #pragma unroll
        for (int r = 0; r < 4; ++r) {
            s[nb][r] *= SC;
            if (key >= 77) s[nb][r] = -1e30f;
        }
    }
    float mrow[4], lrow[4];
    #pragma unroll
    for (int r = 0; r < 4; ++r) {
        float v = fmaxf(fmaxf(fmaxf(s[0][r], s[1][r]), fmaxf(s[2][r], s[3][r])), s[4][r]);
        v = fmaxf(v, __shfl_xor(v, 1));
        v = fmaxf(v, __shfl_xor(v, 2));
        v = fmaxf(v, __shfl_xor(v, 4));
        v = fmaxf(v, __shfl_xor(v, 8));
        mrow[r] = v;
    }
    float rsum[4] = {0.f, 0.f, 0.f, 0.f};
    #pragma unroll
    for (int nb = 0; nb < 5; ++nb)
        #pragma unroll
        for (int r = 0; r < 4; ++r) {
            float p = exp2f((s[nb][r] - mrow[r]) * L2E);
            s[nb][r] = p;
            rsum[r] += p;
        }
    #pragma unroll
    for (int r = 0; r < 4; ++r) {
        float v = rsum[r];
        v += __shfl_xor(v, 1);
        v += __shfl_xor(v, 2);
        v += __shfl_xor(v, 4);
        v += __shfl_xor(v, 8);
        lrow[r] = v;
    }

    char* Pw = (char*)&Ps[wid][0];
    #pragma unroll
    for (int nb = 0; nb < 5; ++nb)
        #pragma unroll
        for (int r = 0; r < 4; ++r) {
            int prow = q * 4 + r;
            *(u16*)(Pw + prow * 160 + (nb * 16 + lc) * 2) = f2b(s[nb][r]);
        }
    bfrag pa0 = *(const bfrag*)(Pw + lc * 160 + q * 16);
    bfrag pa1 = *(const bfrag*)(Pw + lc * 160 + 64 + q * 16);
    bfrag pa2 = bzero();
    if (q < 2) pa2 = *(const bfrag*)(Pw + lc * 160 + 128 + q * 16);

    f4 accO[5];
    #pragma unroll
    for (int no = 0; no < 5; ++no) {
        const char* vb = (const char*)Vs + (no * 16 + lc) * 160;
        bfrag v0 = *(const bfrag*)(vb + q * 16);
        bfrag v1 = *(const bfrag*)(vb + 64 + q * 16);
        bfrag v2 = bzero();
        if (q < 2) v2 = *(const bfrag*)(vb + 128 + q * 16);
        f4 a = {0.f, 0.f, 0.f, 0.f};
        a = MFMA(pa0, v0, a);
        a = MFMA(pa1, v1, a);
        a = MFMA(pa2, v2, a);
        accO[no] = a;
    }
    #pragma unroll
    for (int no = 0; no < 5; ++no)
        #pragma unroll
        for (int r = 0; r < 4; ++r) {
            int row = tok0 + wid * 16 + q * 4 + r;
            int col = hh * 80 + no * 16 + lc;
            out[(size_t)row * 640 + col] = f2b(accO[no][r] / lrow[r]);
        }
}

// ---------------------------------------------------------------------------
// LayerNorm over 640 cols from bf16 psum; 1 wave per row, 4 rows per block.
// Vectorized: 5 x uint (2 bf16) loads per lane; paired stores.
__global__ __launch_bounds__(256) void ln_kb(const u16* __restrict__ pre,
                                             const float* __restrict__ g,
                                             const float* __restrict__ b,
                                             float* __restrict__ xo,
                                             u16* __restrict__ xb)
{
    const int lane = threadIdx.x & 63;
    const int wid  = threadIdx.x >> 6;
    const int row = blockIdx.x * 4 + wid;
    const u16* p = pre + (size_t)row * 640;
    float v[10];
    #pragma unroll
    for (int i = 0; i < 5; ++i) {
        unsigned d = *(const unsigned*)(p + i * 128 + lane * 2);
        v[2 * i]     = b2f((u16)(d & 0xffffu));
        v[2 * i + 1] = b2f((u16)(d >> 16));
    }
    float s = 0.f;
    #pragma unroll
    for (int i = 0; i < 10; ++i) s += v[i];
    #pragma unroll
    for (int m = 1; m < 64; m <<= 1) s += __shfl_xor(s, m);
    float mu = s * (1.0f / 640.0f);
    float d2 = 0.f;
    #pragma unroll
    for (int i = 0; i < 10; ++i) { float d = v[i] - mu; d2 += d * d; }
    #pragma unroll
    for (int m = 1; m < 64; m <<= 1) d2 += __shfl_xor(d2, m);
    float rs = rsqrtf(d2 * (1.0f / 640.0f) + 1e-5f);
    #pragma unroll
    for (int i = 0; i < 5; ++i) {
        int col = i * 128 + lane * 2;
        float y0 = (v[2 * i]     - mu) * rs * g[col]     + b[col];
        float y1 = (v[2 * i + 1] - mu) * rs * g[col + 1] + b[col + 1];
        if (xo) {
            *(float2*)&xo[(size_t)row * 640 + col] = make_float2(y0, y1);
        }
        if (xb) {
            *(unsigned*)&xb[(size_t)row * 640 + col] = pack2(y0, y1);
        }
    }
}

// ---------------------------------------------------------------------------
extern "C" void kernel_launch(void* const* d_in, const int* in_sizes, int n_in,
                              void* d_out, int out_size, void* d_ws, size_t ws_size,
                              hipStream_t stream)
{
    const float* x       = (const float*)d_in[0];
    const float* context = (const float*)d_in[1];
    const float* sa_wq = (const float*)d_in[2];
    const float* sa_wk = (const float*)d_in[3];
    const float* sa_wv = (const float*)d_in[4];
    const float* sa_wo = (const float*)d_in[5];
    const float* sa_bo = (const float*)d_in[6];
    const float* ca_wq = (const float*)d_in[7];
    const float* ca_wk = (const float*)d_in[8];
    const float* ca_wv = (const float*)d_in[9];
    const float* ca_wo = (const float*)d_in[10];
    const float* ca_bo = (const float*)d_in[11];
    const float* ff_w1 = (const float*)d_in[12];
    const float* ff_b1 = (const float*)d_in[13];
    const float* ff_w2 = (const float*)d_in[14];
    const float* ff_b2 = (const float*)d_in[15];
    const float* ln1_g = (const float*)d_in[16];
    const float* ln1_b = (const float*)d_in[17];
    const float* ln2_g = (const float*)d_in[18];
    const float* ln2_b = (const float*)d_in[19];
    const float* ln3_g = (const float*)d_in[20];
    const float* ln3_b = (const float*)d_in[21];

    char* ws = (char*)d_ws;
    const size_t OFF_XB     = 0;
    const size_t OFF_QKVB   = 10485760;
    const size_t OFF_VT     = 41943040;
    const size_t OFF_AB     = 52428800;
    const size_t OFF_ATTN   = 62914560;
    const size_t OFF_QC     = 73400320;
    const size_t OFF_KC     = 83886080;
    const size_t OFF_VCT    = 84705280;
    const size_t OFF_SAQKVT = 85524480;
    const size_t OFF_SAWOT  = 87982080;
    const size_t OFF_CAWQT  = 88801280;
    const size_t OFF_CAKVT  = 89620480;
    const size_t OFF_CAWOT  = 91586560;
    const size_t OFF_FFW1T  = 92405760;
    const size_t OFF_FFW2T  = 98959360;
    const size_t OFF_CTXB   = 102236160;
    const size_t OFF_PRE    = 103219200;    // bf16 psum, 10485760 B used

    u16* xb      = (u16*)(ws + OFF_XB);
    u16* qkvb    = (u16*)(ws + OFF_QKVB);
    u16* vt      = (u16*)(ws + OFF_VT);
    u16* ab      = (u16*)(ws + OFF_AB);
    u16* attnb   = (u16*)(ws + OFF_ATTN);
    u16* qc      = (u16*)(ws + OFF_QC);
    u16* kc      = (u16*)(ws + OFF_KC);
    u16* vct     = (u16*)(ws + OFF_VCT);
    u16* saqkvt  = (u16*)(ws + OFF_SAQKVT);
    u16* sawot   = (u16*)(ws + OFF_SAWOT);
    u16* cawqt   = (u16*)(ws + OFF_CAWQT);
    u16* cakvt   = (u16*)(ws + OFF_CAKVT);
    u16* cawot   = (u16*)(ws + OFF_CAWOT);
    u16* ffw1t   = (u16*)(ws + OFF_FFW1T);
    u16* ffw2t   = (u16*)(ws + OFF_FFW2T);
    u16* ctxb    = (u16*)(ws + OFF_CTXB);
    u16* psum    = (u16*)(ws + OFF_PRE);
    u16* ffh     = (u16*)(ws + OFF_XB);          // aliases xb+qkvb

    // --- prep: all transposes + conversions, one dispatch ---
    hipLaunchKernelGGL(prep_k, dim3(10960), dim3(256), 0, stream,
                       x, context, sa_wq, sa_wk, sa_wv, sa_wo, ca_wq, ca_wk,
                       ca_wv, ca_wo, ff_w1, ff_w2,
                       saqkvt, sawot, cawqt, cawot, cakvt, ffw1t, ffw2t, xb, ctxb);

    // --- self-attention (QKV fused with CA-KV) ---
    hipLaunchKernelGGL(gemm_qkv_cakv, dim3(1010), dim3(256), 0, stream,
                       xb, saqkvt, ctxb, cakvt, qkvb, vt, kc, vct);
    hipLaunchKernelGGL(attn_sa, dim3(1024), dim3(256), 0, stream, qkvb, vt, attnb);
    hipLaunchKernelGGL(gemm_n64<0>, dim3(10, 64), dim3(256), 0, stream,
                       attnb, sawot, 640, 640, sa_bo, xb, psum);
    hipLaunchKernelGGL(ln_kb, dim3(2048), dim3(256), 0, stream, psum, ln1_g, ln1_b,
                       (float*)nullptr, ab);

    // --- cross-attention ---
    hipLaunchKernelGGL(gemm_n64<1>, dim3(10, 64), dim3(256), 0, stream,
                       ab, cawqt, 640, 640, (const float*)nullptr, (const u16*)nullptr,
                       qc);
    hipLaunchKernelGGL(attn_ca, dim3(1024), dim3(256), 0, stream, qc, kc, vct, attnb);
    hipLaunchKernelGGL(gemm_n64<0>, dim3(10, 64), dim3(256), 0, stream,
                       attnb, cawot, 640, 640, ca_bo, ab, psum);
    hipLaunchKernelGGL(ln_kb, dim3(2048), dim3(256), 0, stream, psum, ln2_g, ln2_b,
                       (float*)nullptr, ab);

    // --- GEGLU FFN ---
    hipLaunchKernelGGL(gemm_bt<4>, dim3(40, 64), dim3(256), 0, stream,
                       ab, ffw1t, 5120, 640, ff_b1, (const u16*)nullptr,
                       (float*)nullptr, ffh, (u16*)nullptr);
    hipLaunchKernelGGL(gemm_n64<0>, dim3(10, 64), dim3(256), 0, stream,
                       ffh, ffw2t, 640, 2560, ff_b2, ab, psum);
    hipLaunchKernelGGL(ln_kb, dim3(2048), dim3(256), 0, stream, psum, ln3_g, ln3_b,
                       (float*)d_out, (u16*)nullptr);
}

// Round 12
// 338.170 us; speedup vs baseline: 1.2153x; 1.0124x over previous
//
#include <hip/hip_runtime.h>

// BasicTransformerBlock on gfx950, bf16 MFMA implementation.
// R12: retry attn_sa T14 async-STAGE with NAMED uint4 prefetch registers
//      (pf0..pf4, straight-line; R9's pf[5]-in-lambda spilled to scratch).
//      Everything else identical to R11 (342.4us best).

using u16 = unsigned short;
typedef __attribute__((ext_vector_type(8))) short bfrag;   // 8 bf16 (4 VGPR)
typedef __attribute__((ext_vector_type(4))) float f4;
typedef __attribute__((ext_vector_type(4))) unsigned short us4;

#define MFMA(a, b, c) __builtin_amdgcn_mfma_f32_16x16x32_bf16((a), (b), (c), 0, 0, 0)

__device__ __forceinline__ void gload16(const void* g, void* l) {
    // async global->LDS, 16B per lane; LDS dest = uniform base + lane*16
    __builtin_amdgcn_global_load_lds(
        (const __attribute__((address_space(1))) void*)g,
        (__attribute__((address_space(3))) void*)l, 16, 0, 0);
}

__device__ __forceinline__ u16 f2b(float f) {   // f32 -> bf16 RNE
    unsigned u = __float_as_uint(f);
    unsigned r = u + 0x7FFFu + ((u >> 16) & 1u);
    return (u16)(r >> 16);
}
__device__ __forceinline__ float b2f(u16 u) {
    return __uint_as_float(((unsigned)u) << 16);
}
__device__ __forceinline__ unsigned pack2(float a, float b) {
    return (unsigned)f2b(a) | ((unsigned)f2b(b) << 16);
}
__device__ __forceinline__ bfrag bzero() {
    bfrag z = {0,0,0,0,0,0,0,0};
    return z;
}
// gelu: 0.5x(1+tanh(0.79788456(x+0.044715x^3))), tanh via e^{2y}
__device__ __forceinline__ float gelu_f(float x) {
    float y = 0.7978845608028654f * (x + 0.044715f * x * x * x);
    float e = exp2f(y * 2.8853900817779268f);          // e^{2y}
    float t = 1.0f - 2.0f * __builtin_amdgcn_rcpf(e + 1.0f);
    return 0.5f * x * (1.0f + t);
}

// ---------------------------------------------------------------------------
// prep mega-kernel: all weight transposes + input conversions in ONE dispatch.
__device__ __forceinline__ void transp_tile(const float* __restrict__ in,
                                            u16* __restrict__ out,
                                            int K, int N, int ldo,
                                            int tile, bool perm,
                                            float (*t)[33])
{
    int nw = N >> 5;
    int n0 = (tile % nw) * 32, k0 = (tile / nw) * 32;
    int tx = threadIdx.x & 31, ty = threadIdx.x >> 5;
    #pragma unroll
    for (int i = 0; i < 32; i += 8)
        t[ty + i][tx] = in[(size_t)(k0 + ty + i) * N + n0 + tx];
    __syncthreads();
    #pragma unroll
    for (int i = 0; i < 32; i += 8) {
        int n = n0 + ty + i;
        int dst;
        if (perm) {
            dst = (n < 2560) ? ((n >> 5) * 64 + (n & 31))
                             : (((n - 2560) >> 5) * 64 + 32 + ((n - 2560) & 31));
        } else {
            dst = n;
        }
        out[(size_t)dst * ldo + k0 + tx] = f2b(t[tx][ty + i]);
    }
}

__global__ __launch_bounds__(256) void prep_k(
    const float* __restrict__ x, const float* __restrict__ ctx,
    const float* __restrict__ sa_wq, const float* __restrict__ sa_wk,
    const float* __restrict__ sa_wv, const float* __restrict__ sa_wo,
    const float* __restrict__ ca_wq, const float* __restrict__ ca_wk,
    const float* __restrict__ ca_wv, const float* __restrict__ ca_wo,
    const float* __restrict__ ff_w1, const float* __restrict__ ff_w2,
    u16* saqkvt, u16* sawot, u16* cawqt, u16* cawot, u16* cakvt,
    u16* ffw1t, u16* ffw2t, u16* xb, u16* ctxb)
{
    __shared__ float t[32][33];
    int b = blockIdx.x;
    if (b < 2400) {
        int task = b / 400, tile = b - task * 400;
        const float* src;
        u16* dst;
        if      (task == 0) { src = sa_wq; dst = saqkvt; }
        else if (task == 1) { src = sa_wk; dst = saqkvt + 409600; }
        else if (task == 2) { src = sa_wv; dst = saqkvt + 819200; }
        else if (task == 3) { src = sa_wo; dst = sawot; }
        else if (task == 4) { src = ca_wq; dst = cawqt; }
        else                { src = ca_wo; dst = cawot; }
        transp_tile(src, dst, 640, 640, 640, tile, false, t);
    } else if (b < 3360) {
        int tt = b - 2400;
        int task = tt / 480, tile = tt - task * 480;
        transp_tile(task ? ca_wv : ca_wk, cakvt + task * 491520, 768, 640, 768,
                    tile, false, t);
    } else if (b < 6560) {
        transp_tile(ff_w1, ffw1t, 640, 5120, 640, b - 3360, true, t);
    } else if (b < 8160) {
        transp_tile(ff_w2, ffw2t, 2560, 640, 2560, b - 6560, false, t);
    } else if (b < 10720) {
        int i = (b - 8160) * 256 + threadIdx.x;     // < 655360
        const float4* p = (const float4*)x + (size_t)i * 2;
        float4 a = p[0], bb = p[1];
        uint4 w = { pack2(a.x, a.y), pack2(a.z, a.w),
                    pack2(bb.x, bb.y), pack2(bb.z, bb.w) };
        ((uint4*)xb)[i] = w;
    } else {
        int i = (b - 10720) * 256 + threadIdx.x;    // < 61440
        int rowOut = i / 96, c8 = (i - rowOut * 96) * 8;
        int bb = rowOut / 80, r = rowOut - bb * 80;
        uint4 w = {0, 0, 0, 0};
        if (r < 77) {
            const float4* p = (const float4*)(ctx + ((size_t)(bb * 77 + r)) * 768 + c8);
            float4 a = p[0], b2 = p[1];
            w = (uint4){ pack2(a.x, a.y), pack2(a.z, a.w),
                         pack2(b2.x, b2.y), pack2(b2.z, b2.w) };
        }
        ((uint4*)ctxb)[i] = w;
    }
}

// ---------------------------------------------------------------------------
// GEMM core: C[M][N] = A[M][K](bf16) @ Bt[N][K](bf16)^T, 128x128 tile, BK=64.
// MODE 1: outb = acc (bf16)
// MODE 2: QKV; MODE 3: CA KV; MODE 4: FF1+GEGLU
template<int MODE>
__device__ __forceinline__ void gemm_core(const u16* __restrict__ A,
                                          const u16* __restrict__ Bt,
                                          int N, int K, int ld,
                                          const float* __restrict__ bias,
                                          const u16* __restrict__ resb,
                                          float* __restrict__ outf,
                                          u16* __restrict__ outb,
                                          u16* __restrict__ out2,
                                          int bx, int by,
                                          u16* As, u16* Bs)
{
    const int lane = threadIdx.x & 63;
    const int wid  = threadIdx.x >> 6;
    const int q    = lane >> 4;
    const int lc   = lane & 15;
    const int wm = wid >> 1, wn = wid & 1;
    const int m0 = by * 128;
    const int n0 = bx * 128;
    const int ldb = ld * 2;               // bytes per row

    f4 acc[4][4];
    #pragma unroll
    for (int i = 0; i < 4; ++i)
        #pragma unroll
        for (int j = 0; j < 4; ++j) acc[i][j] = (f4){0.f, 0.f, 0.f, 0.f};

    const char* Abase = (const char*)A + (size_t)m0 * ldb;
    const char* Bbase = (const char*)Bt + (size_t)n0 * ldb;

    for (int kt = 0; kt < K; kt += 64) {
        #pragma unroll
        for (int c = 0; c < 4; ++c) {
            int cid = wid * 4 + c;
            int o = cid * 1024 + lane * 16;
            int row = o >> 7;
            int pc  = o & 127;
            int src = pc ^ ((row & 7) << 4);   // pre-swizzled source, linear dest
            gload16(Abase + (size_t)row * ldb + kt * 2 + src, (char*)As + cid * 1024);
            gload16(Bbase + (size_t)row * ldb + kt * 2 + src, (char*)Bs + cid * 1024);
        }
        __syncthreads();
        #pragma unroll
        for (int ks = 0; ks < 2; ++ks) {
            bfrag a[4], b[4];
            #pragma unroll
            for (int mi = 0; mi < 4; ++mi) {
                int row = wm * 64 + mi * 16 + lc;
                int off = row * 128 + ((ks * 64 + q * 16) ^ ((row & 7) << 4));
                a[mi] = *(const bfrag*)((const char*)As + off);
            }
            #pragma unroll
            for (int ni = 0; ni < 4; ++ni) {
                int row = wn * 64 + ni * 16 + lc;
                int off = row * 128 + ((ks * 64 + q * 16) ^ ((row & 7) << 4));
                b[ni] = *(const bfrag*)((const char*)Bs + off);
            }
            #pragma unroll
            for (int mi = 0; mi < 4; ++mi)
                #pragma unroll
                for (int ni = 0; ni < 4; ++ni)
                    acc[mi][ni] = MFMA(a[mi], b[ni], acc[mi][ni]);
        }
        __syncthreads();
    }

    const int baseRow = m0 + wm * 64;
    const int baseCol = n0 + wn * 64;

    if (MODE == 4) {
        const int blk = baseCol >> 6;
        #pragma unroll
        for (int mi = 0; mi < 4; ++mi)
            #pragma unroll
            for (int ni = 0; ni < 2; ++ni) {
                int j = blk * 32 + ni * 16 + lc;
                float ba = bias[j];
                float bg = bias[2560 + j];
                #pragma unroll
                for (int r = 0; r < 4; ++r) {
                    int row = baseRow + mi * 16 + q * 4 + r;
                    float aa = acc[mi][ni][r] + ba;
                    float gg = acc[mi][ni + 2][r] + bg;
                    outb[(size_t)row * 2560 + j] = f2b(aa * gelu_f(gg));
                }
            }
        return;
    }

    #pragma unroll
    for (int mi = 0; mi < 4; ++mi)
        #pragma unroll
        for (int ni = 0; ni < 4; ++ni) {
            int col = baseCol + ni * 16 + lc;
            if (MODE == 2) {
                const float qs = (col < 640) ? 0.11180339887498949f : 1.0f;
                us4 vv = {0, 0, 0, 0};
                #pragma unroll
                for (int r = 0; r < 4; ++r) {
                    int row = baseRow + mi * 16 + q * 4 + r;
                    u16 u = f2b(acc[mi][ni][r] * qs);
                    outb[(size_t)row * 1920 + col] = u;
                    vv[r] = u;
                }
                if (col >= 1280) {
                    int cd = col - 1280;
                    int hh = cd / 80, dd = cd - hh * 80;
                    int row0 = baseRow + mi * 16 + q * 4;
                    int bb = row0 >> 10, tok = row0 & 1023;
                    *(us4*)&out2[(size_t)((bb * 8 + hh) * 80 + dd) * 1024 + tok] = vv;
                }
            } else {
                #pragma unroll
                for (int r = 0; r < 4; ++r) {
                    int row = baseRow + mi * 16 + q * 4 + r;
                    float v = acc[mi][ni][r];
                    if (MODE == 1) {
                        outb[(size_t)row * N + col] = f2b(v);
                    } else if (MODE == 3) {
                        int bb = row / 80, rr = row - bb * 80;
                        if (rr < 77) {
                            u16 u = f2b(v);
                            if (col < 640) {
                                outb[(size_t)row * 640 + col] = u;
                            } else {
                                int cd = col - 640;
                                int hh = cd / 80, dd = cd - hh * 80;
                                out2[((bb * 8 + hh) * 80 + dd) * 80 + rr] = u;
                            }
                        }
                    }
                }
            }
        }
}

template<int MODE>
__global__ __launch_bounds__(256) void gemm_bt(const u16* __restrict__ A,
                                               const u16* __restrict__ Bt,
                                               int N, int K,
                                               const float* __restrict__ bias,
                                               const u16* __restrict__ resb,
                                               float* __restrict__ outf,
                                               u16* __restrict__ outb,
                                               u16* __restrict__ out2)
{
    __shared__ u16 As[128 * 64];
    __shared__ u16 Bs[128 * 64];
    gemm_core<MODE>(A, Bt, N, K, K, bias, resb, outf, outb, out2,
                    blockIdx.x, blockIdx.y, As, Bs);
}

// fused: blocks [0,960) = QKV GEMM (MODE 2), [960,1010) = CA-KV GEMM (MODE 3)
__global__ __launch_bounds__(256) void gemm_qkv_cakv(
    const u16* __restrict__ xb, const u16* __restrict__ saqkvt,
    const u16* __restrict__ ctxb, const u16* __restrict__ cakvt,
    u16* qkvb, u16* vt, u16* kc, u16* vct)
{
    __shared__ u16 As[128 * 64];
    __shared__ u16 Bs[128 * 64];
    int bid = blockIdx.x;
    if (bid < 960) {
        gemm_core<2>(xb, saqkvt, 1920, 640, 640, nullptr, nullptr, nullptr,
                     qkvb, vt, bid % 15, bid / 15, As, Bs);
    } else {
        int tt = bid - 960;
        gemm_core<3>(ctxb, cakvt, 1280, 768, 768, nullptr, nullptr, nullptr,
                     kc, vct, tt % 10, tt / 10, As, Bs);
    }
}

// ---------------------------------------------------------------------------
// 128x64-tile GEMM for N=640 occupancy-bound shapes (projections + FF2).
// MODE 0: outb = f2b(acc + bias[col] + b2f(resb[row*N+col]))  (bf16 psum)
// MODE 1: outb = f2b(acc)
template<int MODE>
__global__ __launch_bounds__(256) void gemm_n64(const u16* __restrict__ A,
                                                const u16* __restrict__ Bt,
                                                int N, int K,
                                                const float* __restrict__ bias,
                                                const u16* __restrict__ resb,
                                                u16* __restrict__ outb)
{
    __shared__ u16 As[128 * 64];
    __shared__ u16 Bs[64 * 64];
    const int lane = threadIdx.x & 63;
    const int wid  = threadIdx.x >> 6;
    const int hi   = lane >> 4;
    const int lc   = lane & 15;
    const int wm = wid >> 1, wn = wid & 1;
    const int m0 = blockIdx.y * 128;
    const int n0 = blockIdx.x * 64;
    const int ldb = K * 2;

    f4 acc[4][2];
    #pragma unroll
    for (int i = 0; i < 4; ++i)
        #pragma unroll
        for (int j = 0; j < 2; ++j) acc[i][j] = (f4){0.f, 0.f, 0.f, 0.f};

    const char* Abase = (const char*)A + (size_t)m0 * ldb;
    const char* Bbase = (const char*)Bt + (size_t)n0 * ldb;

    for (int kt = 0; kt < K; kt += 64) {
        #pragma unroll
        for (int c = 0; c < 6; ++c) {
            int cid = wid * 6 + c;              // 24 chunks: 16 A + 8 B
            if (cid < 16) {
                int o = cid * 1024 + lane * 16;
                int row = o >> 7;
                int src = (o & 127) ^ ((row & 7) << 4);
                gload16(Abase + (size_t)row * ldb + kt * 2 + src, (char*)As + cid * 1024);
            } else {
                int c2 = cid - 16;
                int o = c2 * 1024 + lane * 16;
                int row = o >> 7;
                int src = (o & 127) ^ ((row & 7) << 4);
                gload16(Bbase + (size_t)row * ldb + kt * 2 + src, (char*)Bs + c2 * 1024);
            }
        }
        __syncthreads();
        #pragma unroll
        for (int ks = 0; ks < 2; ++ks) {
            bfrag a[4], b[2];
            #pragma unroll
            for (int mi = 0; mi < 4; ++mi) {
                int row = wm * 64 + mi * 16 + lc;
                int off = row * 128 + ((ks * 64 + hi * 16) ^ ((row & 7) << 4));
                a[mi] = *(const bfrag*)((const char*)As + off);
            }
            #pragma unroll
            for (int ni = 0; ni < 2; ++ni) {
                int row = wn * 32 + ni * 16 + lc;
                int off = row * 128 + ((ks * 64 + hi * 16) ^ ((row & 7) << 4));
                b[ni] = *(const bfrag*)((const char*)Bs + off);
            }
            #pragma unroll
            for (int mi = 0; mi < 4; ++mi)
                #pragma unroll
                for (int ni = 0; ni < 2; ++ni)
                    acc[mi][ni] = MFMA(a[mi], b[ni], acc[mi][ni]);
        }
        __syncthreads();
    }

    const int baseRow = m0 + wm * 64;
    const int baseCol = n0 + wn * 32;
    #pragma unroll
    for (int mi = 0; mi < 4; ++mi)
        #pragma unroll
        for (int ni = 0; ni < 2; ++ni) {
            int col = baseCol + ni * 16 + lc;
            #pragma unroll
            for (int r = 0; r < 4; ++r) {
                int row = baseRow + mi * 16 + hi * 4 + r;
                float v = acc[mi][ni][r];
                if (MODE == 0)
                    v += bias[col] + b2f(resb[(size_t)row * N + col]);
                outb[(size_t)row * N + col] = f2b(v);
            }
        }
}

// ---------------------------------------------------------------------------
// Self-attention, swapped-QK^T layout. T14 async-STAGE with NAMED registers:
// K/V tile t+1 -> pf0..pf4 (uint4, straight-line) before compute of tile t;
// ds_write after the post-compute barrier.
__global__ __launch_bounds__(256) void attn_sa(const u16* __restrict__ qkv,
                                               const u16* __restrict__ vt,
                                               u16* __restrict__ out)
{
    __shared__ u16 Qs[64 * 80];
    __shared__ u16 Ks[64 * 80];
    __shared__ u16 Vs[80 * 64];
    __shared__ u16 Ps[4][16 * 64];

    const int lane = threadIdx.x & 63;
    const int wid  = threadIdx.x >> 6;
    const int hi   = lane >> 4;
    const int lc   = lane & 15;
    const int bid = blockIdx.x;
    const int qt = bid >> 6;
    const int bb = (bid >> 3) & 7;
    const int hh = bid & 7;
    const int tok0 = bb * 1024 + qt * 64;
    const char* qbase = (const char*)qkv;

    for (int c = wid; c < 10; c += 4) {       // stage Q [64][80] (gload_lds)
        int o = c * 1024 + lane * 16;
        int row = o / 160, col = o - row * 160;
        gload16(qbase + (size_t)(tok0 + row) * 3840 + hh * 160 + col, (char*)Qs + c * 1024);
    }

    // ---- T14 prefetch setup: chunk c_i = wid + 4*i, i = 0..4.
    // c<10 -> K chunk ([64][80], 160B rows); else V chunk ([80][64], swz src).
    // Per-chunk global base (without tile term) and LDS dest, all loop-invariant.
    const char* gsrc0; const char* gsrc1; const char* gsrc2;
    const char* gsrc3; const char* gsrc4;
    char* ldst0; char* ldst1; char* ldst2; char* ldst3; char* ldst4;
    size_t tstep0, tstep1, tstep2, tstep3, tstep4;
    {
        const char* kbase = qbase + (size_t)(bb * 1024) * 3840 + 1280 + hh * 160;
        const char* vbase = (const char*)vt + (size_t)((bb * 8 + hh) * 80) * 2048;
#define SETUP_CH(I)                                                            \
        {                                                                      \
            int c = wid + 4 * I;                                               \
            if (c < 10) {                                                      \
                int o = c * 1024 + lane * 16;                                  \
                int row = o / 160, col = o - row * 160;                        \
                gsrc##I = kbase + (size_t)row * 3840 + col;                    \
                tstep##I = (size_t)64 * 3840;                                  \
                ldst##I = (char*)Ks + c * 1024 + lane * 16;                    \
            } else {                                                           \
                int c2 = c - 10;                                               \
                int o = c2 * 1024 + lane * 16;                                 \
                int row = o >> 7;                                              \
                int src = (o & 127) ^ ((row & 7) << 4);                        \
                gsrc##I = vbase + (size_t)row * 2048 + src;                    \
                tstep##I = 128;                                                \
                ldst##I = (char*)Vs + c2 * 1024 + lane * 16;                   \
            }                                                                  \
        }
        SETUP_CH(0) SETUP_CH(1) SETUP_CH(2) SETUP_CH(3) SETUP_CH(4)
#undef SETUP_CH
    }

    uint4 pf0, pf1, pf2, pf3, pf4;
#define LD_TILE(T)                                                             \
    pf0 = *(const uint4*)(gsrc0 + (size_t)(T) * tstep0);                       \
    pf1 = *(const uint4*)(gsrc1 + (size_t)(T) * tstep1);                       \
    pf2 = *(const uint4*)(gsrc2 + (size_t)(T) * tstep2);                       \
    pf3 = *(const uint4*)(gsrc3 + (size_t)(T) * tstep3);                       \
    pf4 = *(const uint4*)(gsrc4 + (size_t)(T) * tstep4);
#define ST_TILE()                                                              \
    *(uint4*)ldst0 = pf0; *(uint4*)ldst1 = pf1; *(uint4*)ldst2 = pf2;          \
    *(uint4*)ldst3 = pf3; *(uint4*)ldst4 = pf4;

    // prologue: tile 0 regs -> LDS (Q gload_lds drained by barrier semantics)
    LD_TILE(0)
    ST_TILE()
    __syncthreads();

    const int qrow = wid * 16 + lc;
    bfrag qf0 = *(const bfrag*)((const char*)Qs + qrow * 160 + hi * 16);
    bfrag qf1 = *(const bfrag*)((const char*)Qs + qrow * 160 + 64 + hi * 16);
    bfrag qf2 = bzero();
    if (hi < 2) qf2 = *(const bfrag*)((const char*)Qs + qrow * 160 + 128 + hi * 16);

    float m = -3e30f, l = 0.f;
    f4 accO[5];
    #pragma unroll
    for (int no = 0; no < 5; ++no) accO[no] = (f4){0.f, 0.f, 0.f, 0.f};

    const float L2E = 1.4426950408889634f;

    for (int t = 0; t < 16; ++t) {
        if (t < 15) { LD_TILE(t + 1) }         // loads in flight under compute

        f4 sT[4];
        #pragma unroll
        for (int nb = 0; nb < 4; ++nb) {
            const char* kb = (const char*)Ks + (nb * 16 + lc) * 160;
            bfrag k0 = *(const bfrag*)(kb + hi * 16);
            bfrag k1 = *(const bfrag*)(kb + 64 + hi * 16);
            bfrag k2 = bzero();
            if (hi < 2) k2 = *(const bfrag*)(kb + 128 + hi * 16);
            f4 a = {0.f, 0.f, 0.f, 0.f};
            a = MFMA(k0, qf0, a);
            a = MFMA(k1, qf1, a);
            a = MFMA(k2, qf2, a);
            sT[nb] = a;
        }

        float pm = sT[0][0];
        #pragma unroll
        for (int nb = 0; nb < 4; ++nb)
            #pragma unroll
            for (int r = 0; r < 4; ++r) pm = fmaxf(pm, sT[nb][r]);
        pm = fmaxf(pm, __shfl_xor(pm, 16));
        pm = fmaxf(pm, __shfl_xor(pm, 32));

        if (__any(pm > m + 8.0f)) {
            float mn = fmaxf(m, pm);
            float al = exp2f((m - mn) * L2E);
            m = mn;
            l *= al;
            float af[4];
            #pragma unroll
            for (int r = 0; r < 4; ++r) af[r] = __shfl(al, hi * 4 + r);
            #pragma unroll
            for (int no = 0; no < 5; ++no)
                #pragma unroll
                for (int r = 0; r < 4; ++r) accO[no][r] *= af[r];
        }

        float sum = 0.f;
        #pragma unroll
        for (int nb = 0; nb < 4; ++nb)
            #pragma unroll
            for (int r = 0; r < 4; ++r) {
                float p = exp2f((sT[nb][r] - m) * L2E);
                sT[nb][r] = p;
                sum += p;
            }
        sum += __shfl_xor(sum, 16);
        sum += __shfl_xor(sum, 32);
        l += sum;

        char* Pw = (char*)&Ps[wid][0];
        #pragma unroll
        for (int nb = 0; nb < 4; ++nb) {
            us4 pk = { f2b(sT[nb][0]), f2b(sT[nb][1]), f2b(sT[nb][2]), f2b(sT[nb][3]) };
            int cb = (nb * 16 + hi * 4) * 2;
            *(us4*)(Pw + lc * 128 + (cb ^ ((lc & 7) << 4))) = pk;
        }

        bfrag pa0 = *(const bfrag*)(Pw + lc * 128 + ((hi * 16) ^ ((lc & 7) << 4)));
        bfrag pa1 = *(const bfrag*)(Pw + lc * 128 + ((64 + hi * 16) ^ ((lc & 7) << 4)));
        #pragma unroll
        for (int no = 0; no < 5; ++no) {
            int vr = no * 16 + lc;
            const char* vb = (const char*)Vs + vr * 128;
            bfrag v0 = *(const bfrag*)(vb + ((hi * 16) ^ ((vr & 7) << 4)));
            bfrag v1 = *(const bfrag*)(vb + ((64 + hi * 16) ^ ((vr & 7) << 4)));
            accO[no] = MFMA(pa0, v0, accO[no]);
            accO[no] = MFMA(pa1, v1, accO[no]);
        }

        __syncthreads();                       // all reads of tile t complete
        if (t < 15) {
            ST_TILE()                          // waits vmcnt on pf regs
            __syncthreads();                   // writes visible to all waves
        }
    }
#undef LD_TILE
#undef ST_TILE

    float rf[4];
    #pragma unroll
    for (int r = 0; r < 4; ++r) {
        float lf = __shfl(l, hi * 4 + r);
        rf[r] = __builtin_amdgcn_rcpf(lf);
    }
    #pragma unroll
    for (int no = 0; no < 5; ++no)
        #pragma unroll
        for (int r = 0; r < 4; ++r) {
            int row = tok0 + wid * 16 + hi * 4 + r;
            int col = hh * 80 + no * 16 + lc;
            out[(size_t)row * 640 + col] = f2b(accO[no][r] * rf[r]);
        }
}

// ---------------------------------------------------------------------------
// Cross-attention: single KV tile (77 keys padded to 80, masked).
__global__ __launch_bounds__(256) void attn_ca(const u16* __restrict__ qc,
                                               const u16* __restrict__ kc,
                                               const u16* __restrict__ vct,
                                               u16* __restrict__ out)
{
    __shared__ u16 Qs[64 * 80];
    __shared__ u16 Ks[84 * 80];
    __shared__ u16 Vs[84 * 80];
    __shared__ u16 Ps[4][16 * 80];

    const int lane = threadIdx.x & 63;
    const int wid  = threadIdx.x >> 6;
    const int q    = lane >> 4;
    const int lc   = lane & 15;
    const int bid = blockIdx.x;
    const int qt = bid & 15;
    const int hh = (bid >> 4) & 7;
    const int bb = bid >> 7;
    const int tok0 = bb * 1024 + qt * 64;

    for (int c = wid; c < 36; c += 4) {
        if (c < 10) {
            int o = c * 1024 + lane * 16;
            int row = o / 160, col = o - row * 160;
            gload16((const char*)qc + (size_t)(tok0 + row) * 1280 + hh * 160 + col,
                    (char*)Qs + c * 1024);
        } else if (c < 23) {
            int c2 = c - 10;
            int o = c2 * 1024 + lane * 16;
            int row = o / 160, col = o - row * 160;
            gload16((const char*)kc + (size_t)(bb * 80 + row) * 1280 + hh * 160 + col,
                    (char*)Ks + c2 * 1024);
        } else {
            int c2 = c - 23;
            int o = c2 * 1024 + lane * 16;
            int row = o / 160, col = o - row * 160;
            gload16((const char*)vct + (size_t)((bb * 8 + hh) * 80 + row) * 160 + col,
                    (char*)Vs + c2 * 1024);
        }
    }
    __syncthreads();

    const int qrow = wid * 16 + lc;
    bfrag qf0 = *(const bfrag*)((const char*)Qs + qrow * 160 + q * 16);
    bfrag qf1 = *(const bfrag*)((const char*)Qs + qrow * 160 + 64 + q * 16);
    bfrag qf2 = bzero();
    if (q < 2) qf2 = *(const bfrag*)((const char*)Qs + qrow * 160 + 128 + q * 16);

    const float SC = 0.11180339887498949f;
    const float L2E = 1.4426950408889634f;

    f4 s[5];
    #pragma unroll
    for (int nb = 0; nb < 5; ++nb) {
        const char* kb = (const char*)Ks + (nb * 16 + lc) * 160;
        bfrag k0 = *(const bfrag*)(kb + q * 16);
        bfrag k1 = *(const bfrag*)(kb + 64 + q * 16);
        bfrag k2 = bzero();
        if (q < 2) k2 = *(const bfrag*)(kb + 128 + q * 16);
        f4 a = {0.f, 0.f, 0.f, 0.f};
        a = MFMA(qf0, k0, a);
        a = MFMA(qf1, k1, a);
        a = MFMA(qf2, k2, a);
        s[nb] = a;
    }
    #pragma unroll
    for (int nb = 0; nb < 5; ++nb) {
        int key = nb * 16 + lc;
        #pragma unroll
        for (int r = 0; r < 4; ++r) {
            s[nb][r] *= SC;
            if (key >= 77) s[nb][r] = -1e30f;
        }
    }
    float mrow[4], lrow[4];
    #pragma unroll
    for (int r = 0; r < 4; ++r) {
        float v = fmaxf(fmaxf(fmaxf(s[0][r], s[1][r]), fmaxf(s[2][r], s[3][r])), s[4][r]);
        v = fmaxf(v, __shfl_xor(v, 1));
        v = fmaxf(v, __shfl_xor(v, 2));
        v = fmaxf(v, __shfl_xor(v, 4));
        v = fmaxf(v, __shfl_xor(v, 8));
        mrow[r] = v;
    }
    float rsum[4] = {0.f, 0.f, 0.f, 0.f};
    #pragma unroll
    for (int nb = 0; nb < 5; ++nb)
        #pragma unroll
        for (int r = 0; r < 4; ++r) {
            float p = exp2f((s[nb][r] - mrow[r]) * L2E);
            s[nb][r] = p;
            rsum[r] += p;
        }
    #pragma unroll
    for (int r = 0; r < 4; ++r) {
        float v = rsum[r];
        v += __shfl_xor(v, 1);
        v += __shfl_xor(v, 2);
        v += __shfl_xor(v, 4);
        v += __shfl_xor(v, 8);
        lrow[r] = v;
    }

    char* Pw = (char*)&Ps[wid][0];
    #pragma unroll
    for (int nb = 0; nb < 5; ++nb)
        #pragma unroll
        for (int r = 0; r < 4; ++r) {
            int prow = q * 4 + r;
            *(u16*)(Pw + prow * 160 + (nb * 16 + lc) * 2) = f2b(s[nb][r]);
        }
    bfrag pa0 = *(const bfrag*)(Pw + lc * 160 + q * 16);
    bfrag pa1 = *(const bfrag*)(Pw + lc * 160 + 64 + q * 16);
    bfrag pa2 = bzero();
    if (q < 2) pa2 = *(const bfrag*)(Pw + lc * 160 + 128 + q * 16);

    f4 accO[5];
    #pragma unroll
    for (int no = 0; no < 5; ++no) {
        const char* vb = (const char*)Vs + (no * 16 + lc) * 160;
        bfrag v0 = *(const bfrag*)(vb + q * 16);
        bfrag v1 = *(const bfrag*)(vb + 64 + q * 16);
        bfrag v2 = bzero();
        if (q < 2) v2 = *(const bfrag*)(vb + 128 + q * 16);
        f4 a = {0.f, 0.f, 0.f, 0.f};
        a = MFMA(pa0, v0, a);
        a = MFMA(pa1, v1, a);
        a = MFMA(pa2, v2, a);
        accO[no] = a;
    }
    #pragma unroll
    for (int no = 0; no < 5; ++no)
        #pragma unroll
        for (int r = 0; r < 4; ++r) {
            int row = tok0 + wid * 16 + q * 4 + r;
            int col = hh * 80 + no * 16 + lc;
            out[(size_t)row * 640 + col] = f2b(accO[no][r] / lrow[r]);
        }
}

// ---------------------------------------------------------------------------
// LayerNorm over 640 cols from bf16 psum; 1 wave per row, 4 rows per block.
__global__ __launch_bounds__(256) void ln_kb(const u16* __restrict__ pre,
                                             const float* __restrict__ g,
                                             const float* __restrict__ b,
                                             float* __restrict__ xo,
                                             u16* __restrict__ xb)
{
    const int lane = threadIdx.x & 63;
    const int wid  = threadIdx.x >> 6;
    const int row = blockIdx.x * 4 + wid;
    const u16* p = pre + (size_t)row * 640;
    float v[10];
    #pragma unroll
    for (int i = 0; i < 5; ++i) {
        unsigned d = *(const unsigned*)(p + i * 128 + lane * 2);
        v[2 * i]     = b2f((u16)(d & 0xffffu));
        v[2 * i + 1] = b2f((u16)(d >> 16));
    }
    float s = 0.f;
    #pragma unroll
    for (int i = 0; i < 10; ++i) s += v[i];
    #pragma unroll
    for (int m = 1; m < 64; m <<= 1) s += __shfl_xor(s, m);
    float mu = s * (1.0f / 640.0f);
    float d2 = 0.f;
    #pragma unroll
    for (int i = 0; i < 10; ++i) { float d = v[i] - mu; d2 += d * d; }
    #pragma unroll
    for (int m = 1; m < 64; m <<= 1) d2 += __shfl_xor(d2, m);
    float rs = rsqrtf(d2 * (1.0f / 640.0f) + 1e-5f);
    #pragma unroll
    for (int i = 0; i < 5; ++i) {
        int col = i * 128 + lane * 2;
        float y0 = (v[2 * i]     - mu) * rs * g[col]     + b[col];
        float y1 = (v[2 * i + 1] - mu) * rs * g[col + 1] + b[col + 1];
        if (xo) {
            *(float2*)&xo[(size_t)row * 640 + col] = make_float2(y0, y1);
        }
        if (xb) {
            *(unsigned*)&xb[(size_t)row * 640 + col] = pack2(y0, y1);
        }
    }
}

// ---------------------------------------------------------------------------
extern "C" void kernel_launch(void* const* d_in, const int* in_sizes, int n_in,
                              void* d_out, int out_size, void* d_ws, size_t ws_size,
                              hipStream_t stream)
{
    const float* x       = (const float*)d_in[0];
    const float* context = (const float*)d_in[1];
    const float* sa_wq = (const float*)d_in[2];
    const float* sa_wk = (const float*)d_in[3];
    const float* sa_wv = (const float*)d_in[4];
    const float* sa_wo = (const float*)d_in[5];
    const float* sa_bo = (const float*)d_in[6];
    const float* ca_wq = (const float*)d_in[7];
    const float* ca_wk = (const float*)d_in[8];
    const float* ca_wv = (const float*)d_in[9];
    const float* ca_wo = (const float*)d_in[10];
    const float* ca_bo = (const float*)d_in[11];
    const float* ff_w1 = (const float*)d_in[12];
    const float* ff_b1 = (const float*)d_in[13];
    const float* ff_w2 = (const float*)d_in[14];
    const float* ff_b2 = (const float*)d_in[15];
    const float* ln1_g = (const float*)d_in[16];
    const float* ln1_b = (const float*)d_in[17];
    const float* ln2_g = (const float*)d_in[18];
    const float* ln2_b = (const float*)d_in[19];
    const float* ln3_g = (const float*)d_in[20];
    const float* ln3_b = (const float*)d_in[21];

    char* ws = (char*)d_ws;
    const size_t OFF_XB     = 0;
    const size_t OFF_QKVB   = 10485760;
    const size_t OFF_VT     = 41943040;
    const size_t OFF_AB     = 52428800;
    const size_t OFF_ATTN   = 62914560;
    const size_t OFF_QC     = 73400320;
    const size_t OFF_KC     = 83886080;
    const size_t OFF_VCT    = 84705280;
    const size_t OFF_SAQKVT = 85524480;
    const size_t OFF_SAWOT  = 87982080;
    const size_t OFF_CAWQT  = 88801280;
    const size_t OFF_CAKVT  = 89620480;
    const size_t OFF_CAWOT  = 91586560;
    const size_t OFF_FFW1T  = 92405760;
    const size_t OFF_FFW2T  = 98959360;
    const size_t OFF_CTXB   = 102236160;
    const size_t OFF_PRE    = 103219200;    // bf16 psum

    u16* xb      = (u16*)(ws + OFF_XB);
    u16* qkvb    = (u16*)(ws + OFF_QKVB);
    u16* vt      = (u16*)(ws + OFF_VT);
    u16* ab      = (u16*)(ws + OFF_AB);
    u16* attnb   = (u16*)(ws + OFF_ATTN);
    u16* qc      = (u16*)(ws + OFF_QC);
    u16* kc      = (u16*)(ws + OFF_KC);
    u16* vct     = (u16*)(ws + OFF_VCT);
    u16* saqkvt  = (u16*)(ws + OFF_SAQKVT);
    u16* sawot   = (u16*)(ws + OFF_SAWOT);
    u16* cawqt   = (u16*)(ws + OFF_CAWQT);
    u16* cakvt   = (u16*)(ws + OFF_CAKVT);
    u16* cawot   = (u16*)(ws + OFF_CAWOT);
    u16* ffw1t   = (u16*)(ws + OFF_FFW1T);
    u16* ffw2t   = (u16*)(ws + OFF_FFW2T);
    u16* ctxb    = (u16*)(ws + OFF_CTXB);
    u16* psum    = (u16*)(ws + OFF_PRE);
    u16* ffh     = (u16*)(ws + OFF_XB);          // aliases xb+qkvb

    // --- prep: all transposes + conversions, one dispatch ---
    hipLaunchKernelGGL(prep_k, dim3(10960), dim3(256), 0, stream,
                       x, context, sa_wq, sa_wk, sa_wv, sa_wo, ca_wq, ca_wk,
                       ca_wv, ca_wo, ff_w1, ff_w2,
                       saqkvt, sawot, cawqt, cawot, cakvt, ffw1t, ffw2t, xb, ctxb);

    // --- self-attention (QKV fused with CA-KV) ---
    hipLaunchKernelGGL(gemm_qkv_cakv, dim3(1010), dim3(256), 0, stream,
                       xb, saqkvt, ctxb, cakvt, qkvb, vt, kc, vct);
    hipLaunchKernelGGL(attn_sa, dim3(1024), dim3(256), 0, stream, qkvb, vt, attnb);
    hipLaunchKernelGGL(gemm_n64<0>, dim3(10, 64), dim3(256), 0, stream,
                       attnb, sawot, 640, 640, sa_bo, xb, psum);
    hipLaunchKernelGGL(ln_kb, dim3(2048), dim3(256), 0, stream, psum, ln1_g, ln1_b,
                       (float*)nullptr, ab);

    // --- cross-attention ---
    hipLaunchKernelGGL(gemm_n64<1>, dim3(10, 64), dim3(256), 0, stream,
                       ab, cawqt, 640, 640, (const float*)nullptr, (const u16*)nullptr,
                       qc);
    hipLaunchKernelGGL(attn_ca, dim3(1024), dim3(256), 0, stream, qc, kc, vct, attnb);
    hipLaunchKernelGGL(gemm_n64<0>, dim3(10, 64), dim3(256), 0, stream,
                       attnb, cawot, 640, 640, ca_bo, ab, psum);
    hipLaunchKernelGGL(ln_kb, dim3(2048), dim3(256), 0, stream, psum, ln2_g, ln2_b,
                       (float*)nullptr, ab);

    // --- GEGLU FFN ---
    hipLaunchKernelGGL(gemm_bt<4>, dim3(40, 64), dim3(256), 0, stream,
                       ab, ffw1t, 5120, 640, ff_b1, (const u16*)nullptr,
                       (float*)nullptr, ffh, (u16*)nullptr);
    hipLaunchKernelGGL(gemm_n64<0>, dim3(10, 64), dim3(256), 0, stream,
                       ffh, ffw2t, 640, 2560, ff_b2, ab, psum);
    hipLaunchKernelGGL(ln_kb, dim3(2048), dim3(256), 0, stream, psum, ln3_g, ln3_b,
                       (float*)d_out, (u16*)nullptr);
}

// Round 13
// 335.048 us; speedup vs baseline: 1.2266x; 1.0093x over previous
//
#include <hip/hip_runtime.h>

// BasicTransformerBlock on gfx950, bf16 MFMA implementation.
// R13: T5 setprio around attn MFMA clusters (attn_sa QK/PV, attn_ca);
//      MODE 2 skips dead V-column store to qkvb (V read only via vt).
//      Everything else identical to R12 (338.2us best).

using u16 = unsigned short;
typedef __attribute__((ext_vector_type(8))) short bfrag;   // 8 bf16 (4 VGPR)
typedef __attribute__((ext_vector_type(4))) float f4;
typedef __attribute__((ext_vector_type(4))) unsigned short us4;

#define MFMA(a, b, c) __builtin_amdgcn_mfma_f32_16x16x32_bf16((a), (b), (c), 0, 0, 0)

__device__ __forceinline__ void gload16(const void* g, void* l) {
    // async global->LDS, 16B per lane; LDS dest = uniform base + lane*16
    __builtin_amdgcn_global_load_lds(
        (const __attribute__((address_space(1))) void*)g,
        (__attribute__((address_space(3))) void*)l, 16, 0, 0);
}

__device__ __forceinline__ u16 f2b(float f) {   // f32 -> bf16 RNE
    unsigned u = __float_as_uint(f);
    unsigned r = u + 0x7FFFu + ((u >> 16) & 1u);
    return (u16)(r >> 16);
}
__device__ __forceinline__ float b2f(u16 u) {
    return __uint_as_float(((unsigned)u) << 16);
}
__device__ __forceinline__ unsigned pack2(float a, float b) {
    return (unsigned)f2b(a) | ((unsigned)f2b(b) << 16);
}
__device__ __forceinline__ bfrag bzero() {
    bfrag z = {0,0,0,0,0,0,0,0};
    return z;
}
// gelu: 0.5x(1+tanh(0.79788456(x+0.044715x^3))), tanh via e^{2y}
__device__ __forceinline__ float gelu_f(float x) {
    float y = 0.7978845608028654f * (x + 0.044715f * x * x * x);
    float e = exp2f(y * 2.8853900817779268f);          // e^{2y}
    float t = 1.0f - 2.0f * __builtin_amdgcn_rcpf(e + 1.0f);
    return 0.5f * x * (1.0f + t);
}

// ---------------------------------------------------------------------------
// prep mega-kernel: all weight transposes + input conversions in ONE dispatch.
__device__ __forceinline__ void transp_tile(const float* __restrict__ in,
                                            u16* __restrict__ out,
                                            int K, int N, int ldo,
                                            int tile, bool perm,
                                            float (*t)[33])
{
    int nw = N >> 5;
    int n0 = (tile % nw) * 32, k0 = (tile / nw) * 32;
    int tx = threadIdx.x & 31, ty = threadIdx.x >> 5;
    #pragma unroll
    for (int i = 0; i < 32; i += 8)
        t[ty + i][tx] = in[(size_t)(k0 + ty + i) * N + n0 + tx];
    __syncthreads();
    #pragma unroll
    for (int i = 0; i < 32; i += 8) {
        int n = n0 + ty + i;
        int dst;
        if (perm) {
            dst = (n < 2560) ? ((n >> 5) * 64 + (n & 31))
                             : (((n - 2560) >> 5) * 64 + 32 + ((n - 2560) & 31));
        } else {
            dst = n;
        }
        out[(size_t)dst * ldo + k0 + tx] = f2b(t[tx][ty + i]);
    }
}

__global__ __launch_bounds__(256) void prep_k(
    const float* __restrict__ x, const float* __restrict__ ctx,
    const float* __restrict__ sa_wq, const float* __restrict__ sa_wk,
    const float* __restrict__ sa_wv, const float* __restrict__ sa_wo,
    const float* __restrict__ ca_wq, const float* __restrict__ ca_wk,
    const float* __restrict__ ca_wv, const float* __restrict__ ca_wo,
    const float* __restrict__ ff_w1, const float* __restrict__ ff_w2,
    u16* saqkvt, u16* sawot, u16* cawqt, u16* cawot, u16* cakvt,
    u16* ffw1t, u16* ffw2t, u16* xb, u16* ctxb)
{
    __shared__ float t[32][33];
    int b = blockIdx.x;
    if (b < 2400) {
        int task = b / 400, tile = b - task * 400;
        const float* src;
        u16* dst;
        if      (task == 0) { src = sa_wq; dst = saqkvt; }
        else if (task == 1) { src = sa_wk; dst = saqkvt + 409600; }
        else if (task == 2) { src = sa_wv; dst = saqkvt + 819200; }
        else if (task == 3) { src = sa_wo; dst = sawot; }
        else if (task == 4) { src = ca_wq; dst = cawqt; }
        else                { src = ca_wo; dst = cawot; }
        transp_tile(src, dst, 640, 640, 640, tile, false, t);
    } else if (b < 3360) {
        int tt = b - 2400;
        int task = tt / 480, tile = tt - task * 480;
        transp_tile(task ? ca_wv : ca_wk, cakvt + task * 491520, 768, 640, 768,
                    tile, false, t);
    } else if (b < 6560) {
        transp_tile(ff_w1, ffw1t, 640, 5120, 640, b - 3360, true, t);
    } else if (b < 8160) {
        transp_tile(ff_w2, ffw2t, 2560, 640, 2560, b - 6560, false, t);
    } else if (b < 10720) {
        int i = (b - 8160) * 256 + threadIdx.x;     // < 655360
        const float4* p = (const float4*)x + (size_t)i * 2;
        float4 a = p[0], bb = p[1];
        uint4 w = { pack2(a.x, a.y), pack2(a.z, a.w),
                    pack2(bb.x, bb.y), pack2(bb.z, bb.w) };
        ((uint4*)xb)[i] = w;
    } else {
        int i = (b - 10720) * 256 + threadIdx.x;    // < 61440
        int rowOut = i / 96, c8 = (i - rowOut * 96) * 8;
        int bb = rowOut / 80, r = rowOut - bb * 80;
        uint4 w = {0, 0, 0, 0};
        if (r < 77) {
            const float4* p = (const float4*)(ctx + ((size_t)(bb * 77 + r)) * 768 + c8);
            float4 a = p[0], b2 = p[1];
            w = (uint4){ pack2(a.x, a.y), pack2(a.z, a.w),
                         pack2(b2.x, b2.y), pack2(b2.z, b2.w) };
        }
        ((uint4*)ctxb)[i] = w;
    }
}

// ---------------------------------------------------------------------------
// GEMM core: C[M][N] = A[M][K](bf16) @ Bt[N][K](bf16)^T, 128x128 tile, BK=64.
// MODE 1: outb = acc (bf16)
// MODE 2: QKV (V cols only -> vt; qkvb store skipped for col>=1280)
// MODE 3: CA KV; MODE 4: FF1+GEGLU
template<int MODE>
__device__ __forceinline__ void gemm_core(const u16* __restrict__ A,
                                          const u16* __restrict__ Bt,
                                          int N, int K, int ld,
                                          const float* __restrict__ bias,
                                          const u16* __restrict__ resb,
                                          float* __restrict__ outf,
                                          u16* __restrict__ outb,
                                          u16* __restrict__ out2,
                                          int bx, int by,
                                          u16* As, u16* Bs)
{
    const int lane = threadIdx.x & 63;
    const int wid  = threadIdx.x >> 6;
    const int q    = lane >> 4;
    const int lc   = lane & 15;
    const int wm = wid >> 1, wn = wid & 1;
    const int m0 = by * 128;
    const int n0 = bx * 128;
    const int ldb = ld * 2;               // bytes per row

    f4 acc[4][4];
    #pragma unroll
    for (int i = 0; i < 4; ++i)
        #pragma unroll
        for (int j = 0; j < 4; ++j) acc[i][j] = (f4){0.f, 0.f, 0.f, 0.f};

    const char* Abase = (const char*)A + (size_t)m0 * ldb;
    const char* Bbase = (const char*)Bt + (size_t)n0 * ldb;

    for (int kt = 0; kt < K; kt += 64) {
        #pragma unroll
        for (int c = 0; c < 4; ++c) {
            int cid = wid * 4 + c;
            int o = cid * 1024 + lane * 16;
            int row = o >> 7;
            int pc  = o & 127;
            int src = pc ^ ((row & 7) << 4);   // pre-swizzled source, linear dest
            gload16(Abase + (size_t)row * ldb + kt * 2 + src, (char*)As + cid * 1024);
            gload16(Bbase + (size_t)row * ldb + kt * 2 + src, (char*)Bs + cid * 1024);
        }
        __syncthreads();
        #pragma unroll
        for (int ks = 0; ks < 2; ++ks) {
            bfrag a[4], b[4];
            #pragma unroll
            for (int mi = 0; mi < 4; ++mi) {
                int row = wm * 64 + mi * 16 + lc;
                int off = row * 128 + ((ks * 64 + q * 16) ^ ((row & 7) << 4));
                a[mi] = *(const bfrag*)((const char*)As + off);
            }
            #pragma unroll
            for (int ni = 0; ni < 4; ++ni) {
                int row = wn * 64 + ni * 16 + lc;
                int off = row * 128 + ((ks * 64 + q * 16) ^ ((row & 7) << 4));
                b[ni] = *(const bfrag*)((const char*)Bs + off);
            }
            #pragma unroll
            for (int mi = 0; mi < 4; ++mi)
                #pragma unroll
                for (int ni = 0; ni < 4; ++ni)
                    acc[mi][ni] = MFMA(a[mi], b[ni], acc[mi][ni]);
        }
        __syncthreads();
    }

    const int baseRow = m0 + wm * 64;
    const int baseCol = n0 + wn * 64;

    if (MODE == 4) {
        const int blk = baseCol >> 6;
        #pragma unroll
        for (int mi = 0; mi < 4; ++mi)
            #pragma unroll
            for (int ni = 0; ni < 2; ++ni) {
                int j = blk * 32 + ni * 16 + lc;
                float ba = bias[j];
                float bg = bias[2560 + j];
                #pragma unroll
                for (int r = 0; r < 4; ++r) {
                    int row = baseRow + mi * 16 + q * 4 + r;
                    float aa = acc[mi][ni][r] + ba;
                    float gg = acc[mi][ni + 2][r] + bg;
                    outb[(size_t)row * 2560 + j] = f2b(aa * gelu_f(gg));
                }
            }
        return;
    }

    #pragma unroll
    for (int mi = 0; mi < 4; ++mi)
        #pragma unroll
        for (int ni = 0; ni < 4; ++ni) {
            int col = baseCol + ni * 16 + lc;
            if (MODE == 2) {
                const float qs = (col < 640) ? 0.11180339887498949f : 1.0f;
                us4 vv = {0, 0, 0, 0};
                #pragma unroll
                for (int r = 0; r < 4; ++r) {
                    int row = baseRow + mi * 16 + q * 4 + r;
                    u16 u = f2b(acc[mi][ni][r] * qs);
                    if (col < 1280)            // V cols never read from qkvb
                        outb[(size_t)row * 1920 + col] = u;
                    vv[r] = u;
                }
                if (col >= 1280) {
                    int cd = col - 1280;
                    int hh = cd / 80, dd = cd - hh * 80;
                    int row0 = baseRow + mi * 16 + q * 4;
                    int bb = row0 >> 10, tok = row0 & 1023;
                    *(us4*)&out2[(size_t)((bb * 8 + hh) * 80 + dd) * 1024 + tok] = vv;
                }
            } else {
                #pragma unroll
                for (int r = 0; r < 4; ++r) {
                    int row = baseRow + mi * 16 + q * 4 + r;
                    float v = acc[mi][ni][r];
                    if (MODE == 1) {
                        outb[(size_t)row * N + col] = f2b(v);
                    } else if (MODE == 3) {
                        int bb = row / 80, rr = row - bb * 80;
                        if (rr < 77) {
                            u16 u = f2b(v);
                            if (col < 640) {
                                outb[(size_t)row * 640 + col] = u;
                            } else {
                                int cd = col - 640;
                                int hh = cd / 80, dd = cd - hh * 80;
                                out2[((bb * 8 + hh) * 80 + dd) * 80 + rr] = u;
                            }
                        }
                    }
                }
            }
        }
}

template<int MODE>
__global__ __launch_bounds__(256) void gemm_bt(const u16* __restrict__ A,
                                               const u16* __restrict__ Bt,
                                               int N, int K,
                                               const float* __restrict__ bias,
                                               const u16* __restrict__ resb,
                                               float* __restrict__ outf,
                                               u16* __restrict__ outb,
                                               u16* __restrict__ out2)
{
    __shared__ u16 As[128 * 64];
    __shared__ u16 Bs[128 * 64];
    gemm_core<MODE>(A, Bt, N, K, K, bias, resb, outf, outb, out2,
                    blockIdx.x, blockIdx.y, As, Bs);
}

// fused: blocks [0,960) = QKV GEMM (MODE 2), [960,1010) = CA-KV GEMM (MODE 3)
__global__ __launch_bounds__(256) void gemm_qkv_cakv(
    const u16* __restrict__ xb, const u16* __restrict__ saqkvt,
    const u16* __restrict__ ctxb, const u16* __restrict__ cakvt,
    u16* qkvb, u16* vt, u16* kc, u16* vct)
{
    __shared__ u16 As[128 * 64];
    __shared__ u16 Bs[128 * 64];
    int bid = blockIdx.x;
    if (bid < 960) {
        gemm_core<2>(xb, saqkvt, 1920, 640, 640, nullptr, nullptr, nullptr,
                     qkvb, vt, bid % 15, bid / 15, As, Bs);
    } else {
        int tt = bid - 960;
        gemm_core<3>(ctxb, cakvt, 1280, 768, 768, nullptr, nullptr, nullptr,
                     kc, vct, tt % 10, tt / 10, As, Bs);
    }
}

// ---------------------------------------------------------------------------
// 128x64-tile GEMM for N=640 occupancy-bound shapes (projections + FF2).
// MODE 0: outb = f2b(acc + bias[col] + b2f(resb[row*N+col]))  (bf16 psum)
// MODE 1: outb = f2b(acc)
template<int MODE>
__global__ __launch_bounds__(256) void gemm_n64(const u16* __restrict__ A,
                                                const u16* __restrict__ Bt,
                                                int N, int K,
                                                const float* __restrict__ bias,
                                                const u16* __restrict__ resb,
                                                u16* __restrict__ outb)
{
    __shared__ u16 As[128 * 64];
    __shared__ u16 Bs[64 * 64];
    const int lane = threadIdx.x & 63;
    const int wid  = threadIdx.x >> 6;
    const int hi   = lane >> 4;
    const int lc   = lane & 15;
    const int wm = wid >> 1, wn = wid & 1;
    const int m0 = blockIdx.y * 128;
    const int n0 = blockIdx.x * 64;
    const int ldb = K * 2;

    f4 acc[4][2];
    #pragma unroll
    for (int i = 0; i < 4; ++i)
        #pragma unroll
        for (int j = 0; j < 2; ++j) acc[i][j] = (f4){0.f, 0.f, 0.f, 0.f};

    const char* Abase = (const char*)A + (size_t)m0 * ldb;
    const char* Bbase = (const char*)Bt + (size_t)n0 * ldb;

    for (int kt = 0; kt < K; kt += 64) {
        #pragma unroll
        for (int c = 0; c < 6; ++c) {
            int cid = wid * 6 + c;              // 24 chunks: 16 A + 8 B
            if (cid < 16) {
                int o = cid * 1024 + lane * 16;
                int row = o >> 7;
                int src = (o & 127) ^ ((row & 7) << 4);
                gload16(Abase + (size_t)row * ldb + kt * 2 + src, (char*)As + cid * 1024);
            } else {
                int c2 = cid - 16;
                int o = c2 * 1024 + lane * 16;
                int row = o >> 7;
                int src = (o & 127) ^ ((row & 7) << 4);
                gload16(Bbase + (size_t)row * ldb + kt * 2 + src, (char*)Bs + c2 * 1024);
            }
        }
        __syncthreads();
        #pragma unroll
        for (int ks = 0; ks < 2; ++ks) {
            bfrag a[4], b[2];
            #pragma unroll
            for (int mi = 0; mi < 4; ++mi) {
                int row = wm * 64 + mi * 16 + lc;
                int off = row * 128 + ((ks * 64 + hi * 16) ^ ((row & 7) << 4));
                a[mi] = *(const bfrag*)((const char*)As + off);
            }
            #pragma unroll
            for (int ni = 0; ni < 2; ++ni) {
                int row = wn * 32 + ni * 16 + lc;
                int off = row * 128 + ((ks * 64 + hi * 16) ^ ((row & 7) << 4));
                b[ni] = *(const bfrag*)((const char*)Bs + off);
            }
            #pragma unroll
            for (int mi = 0; mi < 4; ++mi)
                #pragma unroll
                for (int ni = 0; ni < 2; ++ni)
                    acc[mi][ni] = MFMA(a[mi], b[ni], acc[mi][ni]);
        }
        __syncthreads();
    }

    const int baseRow = m0 + wm * 64;
    const int baseCol = n0 + wn * 32;
    #pragma unroll
    for (int mi = 0; mi < 4; ++mi)
        #pragma unroll
        for (int ni = 0; ni < 2; ++ni) {
            int col = baseCol + ni * 16 + lc;
            #pragma unroll
            for (int r = 0; r < 4; ++r) {
                int row = baseRow + mi * 16 + hi * 4 + r;
                float v = acc[mi][ni][r];
                if (MODE == 0)
                    v += bias[col] + b2f(resb[(size_t)row * N + col]);
                outb[(size_t)row * N + col] = f2b(v);
            }
        }
}

// ---------------------------------------------------------------------------
// Self-attention, swapped-QK^T layout. T14 async-STAGE (named pf regs) +
// T5 setprio around MFMA clusters.
__global__ __launch_bounds__(256) void attn_sa(const u16* __restrict__ qkv,
                                               const u16* __restrict__ vt,
                                               u16* __restrict__ out)
{
    __shared__ u16 Qs[64 * 80];
    __shared__ u16 Ks[64 * 80];
    __shared__ u16 Vs[80 * 64];
    __shared__ u16 Ps[4][16 * 64];

    const int lane = threadIdx.x & 63;
    const int wid  = threadIdx.x >> 6;
    const int hi   = lane >> 4;
    const int lc   = lane & 15;
    const int bid = blockIdx.x;
    const int qt = bid >> 6;
    const int bb = (bid >> 3) & 7;
    const int hh = bid & 7;
    const int tok0 = bb * 1024 + qt * 64;
    const char* qbase = (const char*)qkv;

    for (int c = wid; c < 10; c += 4) {       // stage Q [64][80] (gload_lds)
        int o = c * 1024 + lane * 16;
        int row = o / 160, col = o - row * 160;
        gload16(qbase + (size_t)(tok0 + row) * 3840 + hh * 160 + col, (char*)Qs + c * 1024);
    }

    // T14 prefetch setup: chunk c_i = wid + 4*i, i = 0..4.
    const char* gsrc0; const char* gsrc1; const char* gsrc2;
    const char* gsrc3; const char* gsrc4;
    char* ldst0; char* ldst1; char* ldst2; char* ldst3; char* ldst4;
    size_t tstep0, tstep1, tstep2, tstep3, tstep4;
    {
        const char* kbase = qbase + (size_t)(bb * 1024) * 3840 + 1280 + hh * 160;
        const char* vbase = (const char*)vt + (size_t)((bb * 8 + hh) * 80) * 2048;
#define SETUP_CH(I)                                                            \
        {                                                                      \
            int c = wid + 4 * I;                                               \
            if (c < 10) {                                                      \
                int o = c * 1024 + lane * 16;                                  \
                int row = o / 160, col = o - row * 160;                        \
                gsrc##I = kbase + (size_t)row * 3840 + col;                    \
                tstep##I = (size_t)64 * 3840;                                  \
                ldst##I = (char*)Ks + c * 1024 + lane * 16;                    \
            } else {                                                           \
                int c2 = c - 10;                                               \
                int o = c2 * 1024 + lane * 16;                                 \
                int row = o >> 7;                                              \
                int src = (o & 127) ^ ((row & 7) << 4);                        \
                gsrc##I = vbase + (size_t)row * 2048 + src;                    \
                tstep##I = 128;                                                \
                ldst##I = (char*)Vs + c2 * 1024 + lane * 16;                   \
            }                                                                  \
        }
        SETUP_CH(0) SETUP_CH(1) SETUP_CH(2) SETUP_CH(3) SETUP_CH(4)
#undef SETUP_CH
    }

    uint4 pf0, pf1, pf2, pf3, pf4;
#define LD_TILE(T)                                                             \
    pf0 = *(const uint4*)(gsrc0 + (size_t)(T) * tstep0);                       \
    pf1 = *(const uint4*)(gsrc1 + (size_t)(T) * tstep1);                       \
    pf2 = *(const uint4*)(gsrc2 + (size_t)(T) * tstep2);                       \
    pf3 = *(const uint4*)(gsrc3 + (size_t)(T) * tstep3);                       \
    pf4 = *(const uint4*)(gsrc4 + (size_t)(T) * tstep4);
#define ST_TILE()                                                              \
    *(uint4*)ldst0 = pf0; *(uint4*)ldst1 = pf1; *(uint4*)ldst2 = pf2;          \
    *(uint4*)ldst3 = pf3; *(uint4*)ldst4 = pf4;

    LD_TILE(0)
    ST_TILE()
    __syncthreads();

    const int qrow = wid * 16 + lc;
    bfrag qf0 = *(const bfrag*)((const char*)Qs + qrow * 160 + hi * 16);
    bfrag qf1 = *(const bfrag*)((const char*)Qs + qrow * 160 + 64 + hi * 16);
    bfrag qf2 = bzero();
    if (hi < 2) qf2 = *(const bfrag*)((const char*)Qs + qrow * 160 + 128 + hi * 16);

    float m = -3e30f, l = 0.f;
    f4 accO[5];
    #pragma unroll
    for (int no = 0; no < 5; ++no) accO[no] = (f4){0.f, 0.f, 0.f, 0.f};

    const float L2E = 1.4426950408889634f;

    for (int t = 0; t < 16; ++t) {
        if (t < 15) { LD_TILE(t + 1) }         // loads in flight under compute

        f4 sT[4];
        __builtin_amdgcn_s_setprio(1);
        #pragma unroll
        for (int nb = 0; nb < 4; ++nb) {
            const char* kb = (const char*)Ks + (nb * 16 + lc) * 160;
            bfrag k0 = *(const bfrag*)(kb + hi * 16);
            bfrag k1 = *(const bfrag*)(kb + 64 + hi * 16);
            bfrag k2 = bzero();
            if (hi < 2) k2 = *(const bfrag*)(kb + 128 + hi * 16);
            f4 a = {0.f, 0.f, 0.f, 0.f};
            a = MFMA(k0, qf0, a);
            a = MFMA(k1, qf1, a);
            a = MFMA(k2, qf2, a);
            sT[nb] = a;
        }
        __builtin_amdgcn_s_setprio(0);

        float pm = sT[0][0];
        #pragma unroll
        for (int nb = 0; nb < 4; ++nb)
            #pragma unroll
            for (int r = 0; r < 4; ++r) pm = fmaxf(pm, sT[nb][r]);
        pm = fmaxf(pm, __shfl_xor(pm, 16));
        pm = fmaxf(pm, __shfl_xor(pm, 32));

        if (__any(pm > m + 8.0f)) {
            float mn = fmaxf(m, pm);
            float al = exp2f((m - mn) * L2E);
            m = mn;
            l *= al;
            float af[4];
            #pragma unroll
            for (int r = 0; r < 4; ++r) af[r] = __shfl(al, hi * 4 + r);
            #pragma unroll
            for (int no = 0; no < 5; ++no)
                #pragma unroll
                for (int r = 0; r < 4; ++r) accO[no][r] *= af[r];
        }

        float sum = 0.f;
        #pragma unroll
        for (int nb = 0; nb < 4; ++nb)
            #pragma unroll
            for (int r = 0; r < 4; ++r) {
                float p = exp2f((sT[nb][r] - m) * L2E);
                sT[nb][r] = p;
                sum += p;
            }
        sum += __shfl_xor(sum, 16);
        sum += __shfl_xor(sum, 32);
        l += sum;

        char* Pw = (char*)&Ps[wid][0];
        #pragma unroll
        for (int nb = 0; nb < 4; ++nb) {
            us4 pk = { f2b(sT[nb][0]), f2b(sT[nb][1]), f2b(sT[nb][2]), f2b(sT[nb][3]) };
            int cb = (nb * 16 + hi * 4) * 2;
            *(us4*)(Pw + lc * 128 + (cb ^ ((lc & 7) << 4))) = pk;
        }

        bfrag pa0 = *(const bfrag*)(Pw + lc * 128 + ((hi * 16) ^ ((lc & 7) << 4)));
        bfrag pa1 = *(const bfrag*)(Pw + lc * 128 + ((64 + hi * 16) ^ ((lc & 7) << 4)));
        __builtin_amdgcn_s_setprio(1);
        #pragma unroll
        for (int no = 0; no < 5; ++no) {
            int vr = no * 16 + lc;
            const char* vb = (const char*)Vs + vr * 128;
            bfrag v0 = *(const bfrag*)(vb + ((hi * 16) ^ ((vr & 7) << 4)));
            bfrag v1 = *(const bfrag*)(vb + ((64 + hi * 16) ^ ((vr & 7) << 4)));
            accO[no] = MFMA(pa0, v0, accO[no]);
            accO[no] = MFMA(pa1, v1, accO[no]);
        }
        __builtin_amdgcn_s_setprio(0);

        __syncthreads();                       // all reads of tile t complete
        if (t < 15) {
            ST_TILE()                          // waits vmcnt on pf regs
            __syncthreads();                   // writes visible to all waves
        }
    }
#undef LD_TILE
#undef ST_TILE

    float rf[4];
    #pragma unroll
    for (int r = 0; r < 4; ++r) {
        float lf = __shfl(l, hi * 4 + r);
        rf[r] = __builtin_amdgcn_rcpf(lf);
    }
    #pragma unroll
    for (int no = 0; no < 5; ++no)
        #pragma unroll
        for (int r = 0; r < 4; ++r) {
            int row = tok0 + wid * 16 + hi * 4 + r;
            int col = hh * 80 + no * 16 + lc;
            out[(size_t)row * 640 + col] = f2b(accO[no][r] * rf[r]);
        }
}

// ---------------------------------------------------------------------------
// Cross-attention: single KV tile (77 keys padded to 80, masked).
__global__ __launch_bounds__(256) void attn_ca(const u16* __restrict__ qc,
                                               const u16* __restrict__ kc,
                                               const u16* __restrict__ vct,
                                               u16* __restrict__ out)
{
    __shared__ u16 Qs[64 * 80];
    __shared__ u16 Ks[84 * 80];
    __shared__ u16 Vs[84 * 80];
    __shared__ u16 Ps[4][16 * 80];

    const int lane = threadIdx.x & 63;
    const int wid  = threadIdx.x >> 6;
    const int q    = lane >> 4;
    const int lc   = lane & 15;
    const int bid = blockIdx.x;
    const int qt = bid & 15;
    const int hh = (bid >> 4) & 7;
    const int bb = bid >> 7;
    const int tok0 = bb * 1024 + qt * 64;

    for (int c = wid; c < 36; c += 4) {
        if (c < 10) {
            int o = c * 1024 + lane * 16;
            int row = o / 160, col = o - row * 160;
            gload16((const char*)qc + (size_t)(tok0 + row) * 1280 + hh * 160 + col,
                    (char*)Qs + c * 1024);
        } else if (c < 23) {
            int c2 = c - 10;
            int o = c2 * 1024 + lane * 16;
            int row = o / 160, col = o - row * 160;
            gload16((const char*)kc + (size_t)(bb * 80 + row) * 1280 + hh * 160 + col,
                    (char*)Ks + c2 * 1024);
        } else {
            int c2 = c - 23;
            int o = c2 * 1024 + lane * 16;
            int row = o / 160, col = o - row * 160;
            gload16((const char*)vct + (size_t)((bb * 8 + hh) * 80 + row) * 160 + col,
                    (char*)Vs + c2 * 1024);
        }
    }
    __syncthreads();

    const int qrow = wid * 16 + lc;
    bfrag qf0 = *(const bfrag*)((const char*)Qs + qrow * 160 + q * 16);
    bfrag qf1 = *(const bfrag*)((const char*)Qs + qrow * 160 + 64 + q * 16);
    bfrag qf2 = bzero();
    if (q < 2) qf2 = *(const bfrag*)((const char*)Qs + qrow * 160 + 128 + q * 16);

    const float SC = 0.11180339887498949f;
    const float L2E = 1.4426950408889634f;

    f4 s[5];
    __builtin_amdgcn_s_setprio(1);
    #pragma unroll
    for (int nb = 0; nb < 5; ++nb) {
        const char* kb = (const char*)Ks + (nb * 16 + lc) * 160;
        bfrag k0 = *(const bfrag*)(kb + q * 16);
        bfrag k1 = *(const bfrag*)(kb + 64 + q * 16);
        bfrag k2 = bzero();
        if (q < 2) k2 = *(const bfrag*)(kb + 128 + q * 16);
        f4 a = {0.f, 0.f, 0.f, 0.f};
        a = MFMA(qf0, k0, a);
        a = MFMA(qf1, k1, a);
        a = MFMA(qf2, k2, a);
        s[nb] = a;
    }
    __builtin_amdgcn_s_setprio(0);
    #pragma unroll
    for (int nb = 0; nb < 5; ++nb) {
        int key = nb * 16 + lc;
        #pragma unroll
        for (int r = 0; r < 4; ++r) {
            s[nb][r] *= SC;
            if (key >= 77) s[nb][r] = -1e30f;
        }
    }
    float mrow[4], lrow[4];
    #pragma unroll
    for (int r = 0; r < 4; ++r) {
        float v = fmaxf(fmaxf(fmaxf(s[0][r], s[1][r]), fmaxf(s[2][r], s[3][r])), s[4][r]);
        v = fmaxf(v, __shfl_xor(v, 1));
        v = fmaxf(v, __shfl_xor(v, 2));
        v = fmaxf(v, __shfl_xor(v, 4));
        v = fmaxf(v, __shfl_xor(v, 8));
        mrow[r] = v;
    }
    float rsum[4] = {0.f, 0.f, 0.f, 0.f};
    #pragma unroll
    for (int nb = 0; nb < 5; ++nb)
        #pragma unroll
        for (int r = 0; r < 4; ++r) {
            float p = exp2f((s[nb][r] - mrow[r]) * L2E);
            s[nb][r] = p;
            rsum[r] += p;
        }
    #pragma unroll
    for (int r = 0; r < 4; ++r) {
        float v = rsum[r];
        v += __shfl_xor(v, 1);
        v += __shfl_xor(v, 2);
        v += __shfl_xor(v, 4);
        v += __shfl_xor(v, 8);
        lrow[r] = v;
    }

    char* Pw = (char*)&Ps[wid][0];
    #pragma unroll
    for (int nb = 0; nb < 5; ++nb)
        #pragma unroll
        for (int r = 0; r < 4; ++r) {
            int prow = q * 4 + r;
            *(u16*)(Pw + prow * 160 + (nb * 16 + lc) * 2) = f2b(s[nb][r]);
        }
    bfrag pa0 = *(const bfrag*)(Pw + lc * 160 + q * 16);
    bfrag pa1 = *(const bfrag*)(Pw + lc * 160 + 64 + q * 16);
    bfrag pa2 = bzero();
    if (q < 2) pa2 = *(const bfrag*)(Pw + lc * 160 + 128 + q * 16);

    f4 accO[5];
    __builtin_amdgcn_s_setprio(1);
    #pragma unroll
    for (int no = 0; no < 5; ++no) {
        const char* vb = (const char*)Vs + (no * 16 + lc) * 160;
        bfrag v0 = *(const bfrag*)(vb + q * 16);
        bfrag v1 = *(const bfrag*)(vb + 64 + q * 16);
        bfrag v2 = bzero();
        if (q < 2) v2 = *(const bfrag*)(vb + 128 + q * 16);
        f4 a = {0.f, 0.f, 0.f, 0.f};
        a = MFMA(pa0, v0, a);
        a = MFMA(pa1, v1, a);
        a = MFMA(pa2, v2, a);
        accO[no] = a;
    }
    __builtin_amdgcn_s_setprio(0);
    #pragma unroll
    for (int no = 0; no < 5; ++no)
        #pragma unroll
        for (int r = 0; r < 4; ++r) {
            int row = tok0 + wid * 16 + q * 4 + r;
            int col = hh * 80 + no * 16 + lc;
            out[(size_t)row * 640 + col] = f2b(accO[no][r] / lrow[r]);
        }
}

// ---------------------------------------------------------------------------
// LayerNorm over 640 cols from bf16 psum; 1 wave per row, 4 rows per block.
__global__ __launch_bounds__(256) void ln_kb(const u16* __restrict__ pre,
                                             const float* __restrict__ g,
                                             const float* __restrict__ b,
                                             float* __restrict__ xo,
                                             u16* __restrict__ xb)
{
    const int lane = threadIdx.x & 63;
    const int wid  = threadIdx.x >> 6;
    const int row = blockIdx.x * 4 + wid;
    const u16* p = pre + (size_t)row * 640;
    float v[10];
    #pragma unroll
    for (int i = 0; i < 5; ++i) {
        unsigned d = *(const unsigned*)(p + i * 128 + lane * 2);
        v[2 * i]     = b2f((u16)(d & 0xffffu));
        v[2 * i + 1] = b2f((u16)(d >> 16));
    }
    float s = 0.f;
    #pragma unroll
    for (int i = 0; i < 10; ++i) s += v[i];
    #pragma unroll
    for (int m = 1; m < 64; m <<= 1) s += __shfl_xor(s, m);
    float mu = s * (1.0f / 640.0f);
    float d2 = 0.f;
    #pragma unroll
    for (int i = 0; i < 10; ++i) { float d = v[i] - mu; d2 += d * d; }
    #pragma unroll
    for (int m = 1; m < 64; m <<= 1) d2 += __shfl_xor(d2, m);
    float rs = rsqrtf(d2 * (1.0f / 640.0f) + 1e-5f);
    #pragma unroll
    for (int i = 0; i < 5; ++i) {
        int col = i * 128 + lane * 2;
        float y0 = (v[2 * i]     - mu) * rs * g[col]     + b[col];
        float y1 = (v[2 * i + 1] - mu) * rs * g[col + 1] + b[col + 1];
        if (xo) {
            *(float2*)&xo[(size_t)row * 640 + col] = make_float2(y0, y1);
        }
        if (xb) {
            *(unsigned*)&xb[(size_t)row * 640 + col] = pack2(y0, y1);
        }
    }
}

// ---------------------------------------------------------------------------
extern "C" void kernel_launch(void* const* d_in, const int* in_sizes, int n_in,
                              void* d_out, int out_size, void* d_ws, size_t ws_size,
                              hipStream_t stream)
{
    const float* x       = (const float*)d_in[0];
    const float* context = (const float*)d_in[1];
    const float* sa_wq = (const float*)d_in[2];
    const float* sa_wk = (const float*)d_in[3];
    const float* sa_wv = (const float*)d_in[4];
    const float* sa_wo = (const float*)d_in[5];
    const float* sa_bo = (const float*)d_in[6];
    const float* ca_wq = (const float*)d_in[7];
    const float* ca_wk = (const float*)d_in[8];
    const float* ca_wv = (const float*)d_in[9];
    const float* ca_wo = (const float*)d_in[10];
    const float* ca_bo = (const float*)d_in[11];
    const float* ff_w1 = (const float*)d_in[12];
    const float* ff_b1 = (const float*)d_in[13];
    const float* ff_w2 = (const float*)d_in[14];
    const float* ff_b2 = (const float*)d_in[15];
    const float* ln1_g = (const float*)d_in[16];
    const float* ln1_b = (const float*)d_in[17];
    const float* ln2_g = (const float*)d_in[18];
    const float* ln2_b = (const float*)d_in[19];
    const float* ln3_g = (const float*)d_in[20];
    const float* ln3_b = (const float*)d_in[21];

    char* ws = (char*)d_ws;
    const size_t OFF_XB     = 0;
    const size_t OFF_QKVB   = 10485760;
    const size_t OFF_VT     = 41943040;
    const size_t OFF_AB     = 52428800;
    const size_t OFF_ATTN   = 62914560;
    const size_t OFF_QC     = 73400320;
    const size_t OFF_KC     = 83886080;
    const size_t OFF_VCT    = 84705280;
    const size_t OFF_SAQKVT = 85524480;
    const size_t OFF_SAWOT  = 87982080;
    const size_t OFF_CAWQT  = 88801280;
    const size_t OFF_CAKVT  = 89620480;
    const size_t OFF_CAWOT  = 91586560;
    const size_t OFF_FFW1T  = 92405760;
    const size_t OFF_FFW2T  = 98959360;
    const size_t OFF_CTXB   = 102236160;
    const size_t OFF_PRE    = 103219200;    // bf16 psum

    u16* xb      = (u16*)(ws + OFF_XB);
    u16* qkvb    = (u16*)(ws + OFF_QKVB);
    u16* vt      = (u16*)(ws + OFF_VT);
    u16* ab      = (u16*)(ws + OFF_AB);
    u16* attnb   = (u16*)(ws + OFF_ATTN);
    u16* qc      = (u16*)(ws + OFF_QC);
    u16* kc      = (u16*)(ws + OFF_KC);
    u16* vct     = (u16*)(ws + OFF_VCT);
    u16* saqkvt  = (u16*)(ws + OFF_SAQKVT);
    u16* sawot   = (u16*)(ws + OFF_SAWOT);
    u16* cawqt   = (u16*)(ws + OFF_CAWQT);
    u16* cakvt   = (u16*)(ws + OFF_CAKVT);
    u16* cawot   = (u16*)(ws + OFF_CAWOT);
    u16* ffw1t   = (u16*)(ws + OFF_FFW1T);
    u16* ffw2t   = (u16*)(ws + OFF_FFW2T);
    u16* ctxb    = (u16*)(ws + OFF_CTXB);
    u16* psum    = (u16*)(ws + OFF_PRE);
    u16* ffh     = (u16*)(ws + OFF_XB);          // aliases xb+qkvb

    // --- prep: all transposes + conversions, one dispatch ---
    hipLaunchKernelGGL(prep_k, dim3(10960), dim3(256), 0, stream,
                       x, context, sa_wq, sa_wk, sa_wv, sa_wo, ca_wq, ca_wk,
                       ca_wv, ca_wo, ff_w1, ff_w2,
                       saqkvt, sawot, cawqt, cawot, cakvt, ffw1t, ffw2t, xb, ctxb);

    // --- self-attention (QKV fused with CA-KV) ---
    hipLaunchKernelGGL(gemm_qkv_cakv, dim3(1010), dim3(256), 0, stream,
                       xb, saqkvt, ctxb, cakvt, qkvb, vt, kc, vct);
    hipLaunchKernelGGL(attn_sa, dim3(1024), dim3(256), 0, stream, qkvb, vt, attnb);
    hipLaunchKernelGGL(gemm_n64<0>, dim3(10, 64), dim3(256), 0, stream,
                       attnb, sawot, 640, 640, sa_bo, xb, psum);
    hipLaunchKernelGGL(ln_kb, dim3(2048), dim3(256), 0, stream, psum, ln1_g, ln1_b,
                       (float*)nullptr, ab);

    // --- cross-attention ---
    hipLaunchKernelGGL(gemm_n64<1>, dim3(10, 64), dim3(256), 0, stream,
                       ab, cawqt, 640, 640, (const float*)nullptr, (const u16*)nullptr,
                       qc);
    hipLaunchKernelGGL(attn_ca, dim3(1024), dim3(256), 0, stream, qc, kc, vct, attnb);
    hipLaunchKernelGGL(gemm_n64<0>, dim3(10, 64), dim3(256), 0, stream,
                       attnb, cawot, 640, 640, ca_bo, ab, psum);
    hipLaunchKernelGGL(ln_kb, dim3(2048), dim3(256), 0, stream, psum, ln2_g, ln2_b,
                       (float*)nullptr, ab);

    // --- GEGLU FFN ---
    hipLaunchKernelGGL(gemm_bt<4>, dim3(40, 64), dim3(256), 0, stream,
                       ab, ffw1t, 5120, 640, ff_b1, (const u16*)nullptr,
                       (float*)nullptr, ffh, (u16*)nullptr);
    hipLaunchKernelGGL(gemm_n64<0>, dim3(10, 64), dim3(256), 0, stream,
                       ffh, ffw2t, 640, 2560, ff_b2, ab, psum);
    hipLaunchKernelGGL(ln_kb, dim3(2048), dim3(256), 0, stream, psum, ln3_g, ln3_b,
                       (float*)d_out, (u16*)nullptr);
}

// Round 14
// 332.380 us; speedup vs baseline: 1.2365x; 1.0080x over previous
//
#include <hip/hip_runtime.h>

// BasicTransformerBlock on gfx950, bf16 MFMA implementation.
// R14: (1) QKV V-tile coalescing: blocks bx>=10 (pure V) transpose acc through
//      32KB LDS (reused staging buffer) and store vt tok-major (256B runs)
//      instead of 8B scatters; (2) prep transp stores packed as us4 (4x wider).
//      Everything else identical to R13 (335.0us best).

using u16 = unsigned short;
typedef __attribute__((ext_vector_type(8))) short bfrag;   // 8 bf16 (4 VGPR)
typedef __attribute__((ext_vector_type(4))) float f4;
typedef __attribute__((ext_vector_type(4))) unsigned short us4;

#define MFMA(a, b, c) __builtin_amdgcn_mfma_f32_16x16x32_bf16((a), (b), (c), 0, 0, 0)

__device__ __forceinline__ void gload16(const void* g, void* l) {
    // async global->LDS, 16B per lane; LDS dest = uniform base + lane*16
    __builtin_amdgcn_global_load_lds(
        (const __attribute__((address_space(1))) void*)g,
        (__attribute__((address_space(3))) void*)l, 16, 0, 0);
}

__device__ __forceinline__ u16 f2b(float f) {   // f32 -> bf16 RNE
    unsigned u = __float_as_uint(f);
    unsigned r = u + 0x7FFFu + ((u >> 16) & 1u);
    return (u16)(r >> 16);
}
__device__ __forceinline__ float b2f(u16 u) {
    return __uint_as_float(((unsigned)u) << 16);
}
__device__ __forceinline__ unsigned pack2(float a, float b) {
    return (unsigned)f2b(a) | ((unsigned)f2b(b) << 16);
}
__device__ __forceinline__ bfrag bzero() {
    bfrag z = {0,0,0,0,0,0,0,0};
    return z;
}
// gelu: 0.5x(1+tanh(0.79788456(x+0.044715x^3))), tanh via e^{2y}
__device__ __forceinline__ float gelu_f(float x) {
    float y = 0.7978845608028654f * (x + 0.044715f * x * x * x);
    float e = exp2f(y * 2.8853900817779268f);          // e^{2y}
    float t = 1.0f - 2.0f * __builtin_amdgcn_rcpf(e + 1.0f);
    return 0.5f * x * (1.0f + t);
}

// ---------------------------------------------------------------------------
// prep mega-kernel: all weight transposes + input conversions in ONE dispatch.
// Store phase packs 4 k-values per thread (us4): kk = (tid&7)*4, nn = tid>>3.
__device__ __forceinline__ void transp_tile(const float* __restrict__ in,
                                            u16* __restrict__ out,
                                            int K, int N, int ldo,
                                            int tile, bool perm,
                                            float (*t)[33])
{
    int nw = N >> 5;
    int n0 = (tile % nw) * 32, k0 = (tile / nw) * 32;
    int tx = threadIdx.x & 31, ty = threadIdx.x >> 5;
    #pragma unroll
    for (int i = 0; i < 32; i += 8)
        t[ty + i][tx] = in[(size_t)(k0 + ty + i) * N + n0 + tx];
    __syncthreads();
    int kk = (threadIdx.x & 7) * 4;
    int nn = threadIdx.x >> 3;
    int n = n0 + nn;
    int dst;
    if (perm) {
        dst = (n < 2560) ? ((n >> 5) * 64 + (n & 31))
                         : (((n - 2560) >> 5) * 64 + 32 + ((n - 2560) & 31));
    } else {
        dst = n;
    }
    us4 w = { f2b(t[kk][nn]), f2b(t[kk + 1][nn]),
              f2b(t[kk + 2][nn]), f2b(t[kk + 3][nn]) };
    *(us4*)&out[(size_t)dst * ldo + k0 + kk] = w;
    __syncthreads();   // t reused by caller? (single tile per block; safe)
}

__global__ __launch_bounds__(256) void prep_k(
    const float* __restrict__ x, const float* __restrict__ ctx,
    const float* __restrict__ sa_wq, const float* __restrict__ sa_wk,
    const float* __restrict__ sa_wv, const float* __restrict__ sa_wo,
    const float* __restrict__ ca_wq, const float* __restrict__ ca_wk,
    const float* __restrict__ ca_wv, const float* __restrict__ ca_wo,
    const float* __restrict__ ff_w1, const float* __restrict__ ff_w2,
    u16* saqkvt, u16* sawot, u16* cawqt, u16* cawot, u16* cakvt,
    u16* ffw1t, u16* ffw2t, u16* xb, u16* ctxb)
{
    __shared__ float t[32][33];
    int b = blockIdx.x;
    if (b < 2400) {
        int task = b / 400, tile = b - task * 400;
        const float* src;
        u16* dst;
        if      (task == 0) { src = sa_wq; dst = saqkvt; }
        else if (task == 1) { src = sa_wk; dst = saqkvt + 409600; }
        else if (task == 2) { src = sa_wv; dst = saqkvt + 819200; }
        else if (task == 3) { src = sa_wo; dst = sawot; }
        else if (task == 4) { src = ca_wq; dst = cawqt; }
        else                { src = ca_wo; dst = cawot; }
        transp_tile(src, dst, 640, 640, 640, tile, false, t);
    } else if (b < 3360) {
        int tt = b - 2400;
        int task = tt / 480, tile = tt - task * 480;
        transp_tile(task ? ca_wv : ca_wk, cakvt + task * 491520, 768, 640, 768,
                    tile, false, t);
    } else if (b < 6560) {
        transp_tile(ff_w1, ffw1t, 640, 5120, 640, b - 3360, true, t);
    } else if (b < 8160) {
        transp_tile(ff_w2, ffw2t, 2560, 640, 2560, b - 6560, false, t);
    } else if (b < 10720) {
        int i = (b - 8160) * 256 + threadIdx.x;     // < 655360
        const float4* p = (const float4*)x + (size_t)i * 2;
        float4 a = p[0], bb = p[1];
        uint4 w = { pack2(a.x, a.y), pack2(a.z, a.w),
                    pack2(bb.x, bb.y), pack2(bb.z, bb.w) };
        ((uint4*)xb)[i] = w;
    } else {
        int i = (b - 10720) * 256 + threadIdx.x;    // < 61440
        int rowOut = i / 96, c8 = (i - rowOut * 96) * 8;
        int bb = rowOut / 80, r = rowOut - bb * 80;
        uint4 w = {0, 0, 0, 0};
        if (r < 77) {
            const float4* p = (const float4*)(ctx + ((size_t)(bb * 77 + r)) * 768 + c8);
            float4 a = p[0], b2 = p[1];
            w = (uint4){ pack2(a.x, a.y), pack2(a.z, a.w),
                         pack2(b2.x, b2.y), pack2(b2.z, b2.w) };
        }
        ((uint4*)ctxb)[i] = w;
    }
}

// ---------------------------------------------------------------------------
// GEMM core: C[M][N] = A[M][K](bf16) @ Bt[N][K](bf16)^T, 128x128 tile, BK=64.
// MODE 1: outb = acc (bf16)
// MODE 2: QKV. Blocks with n0<1280: Q/K -> qkvb (Q pre-scaled). Blocks with
//         n0>=1280 (pure V): acc -> 32KB LDS (As base; qkv kernel allocates
//         contiguous 128x128) -> coalesced tok-major store to out2=vt.
// MODE 3: CA KV; MODE 4: FF1+GEGLU
template<int MODE>
__device__ __forceinline__ void gemm_core(const u16* __restrict__ A,
                                          const u16* __restrict__ Bt,
                                          int N, int K, int ld,
                                          const float* __restrict__ bias,
                                          const u16* __restrict__ resb,
                                          float* __restrict__ outf,
                                          u16* __restrict__ outb,
                                          u16* __restrict__ out2,
                                          int bx, int by,
                                          u16* As, u16* Bs)
{
    const int lane = threadIdx.x & 63;
    const int wid  = threadIdx.x >> 6;
    const int q    = lane >> 4;
    const int lc   = lane & 15;
    const int wm = wid >> 1, wn = wid & 1;
    const int m0 = by * 128;
    const int n0 = bx * 128;
    const int ldb = ld * 2;               // bytes per row

    f4 acc[4][4];
    #pragma unroll
    for (int i = 0; i < 4; ++i)
        #pragma unroll
        for (int j = 0; j < 4; ++j) acc[i][j] = (f4){0.f, 0.f, 0.f, 0.f};

    const char* Abase = (const char*)A + (size_t)m0 * ldb;
    const char* Bbase = (const char*)Bt + (size_t)n0 * ldb;

    for (int kt = 0; kt < K; kt += 64) {
        #pragma unroll
        for (int c = 0; c < 4; ++c) {
            int cid = wid * 4 + c;
            int o = cid * 1024 + lane * 16;
            int row = o >> 7;
            int pc  = o & 127;
            int src = pc ^ ((row & 7) << 4);   // pre-swizzled source, linear dest
            gload16(Abase + (size_t)row * ldb + kt * 2 + src, (char*)As + cid * 1024);
            gload16(Bbase + (size_t)row * ldb + kt * 2 + src, (char*)Bs + cid * 1024);
        }
        __syncthreads();
        #pragma unroll
        for (int ks = 0; ks < 2; ++ks) {
            bfrag a[4], b[4];
            #pragma unroll
            for (int mi = 0; mi < 4; ++mi) {
                int row = wm * 64 + mi * 16 + lc;
                int off = row * 128 + ((ks * 64 + q * 16) ^ ((row & 7) << 4));
                a[mi] = *(const bfrag*)((const char*)As + off);
            }
            #pragma unroll
            for (int ni = 0; ni < 4; ++ni) {
                int row = wn * 64 + ni * 16 + lc;
                int off = row * 128 + ((ks * 64 + q * 16) ^ ((row & 7) << 4));
                b[ni] = *(const bfrag*)((const char*)Bs + off);
            }
            #pragma unroll
            for (int mi = 0; mi < 4; ++mi)
                #pragma unroll
                for (int ni = 0; ni < 4; ++ni)
                    acc[mi][ni] = MFMA(a[mi], b[ni], acc[mi][ni]);
        }
        __syncthreads();
    }

    const int baseRow = m0 + wm * 64;
    const int baseCol = n0 + wn * 64;

    if (MODE == 4) {
        const int blk = baseCol >> 6;
        #pragma unroll
        for (int mi = 0; mi < 4; ++mi)
            #pragma unroll
            for (int ni = 0; ni < 2; ++ni) {
                int j = blk * 32 + ni * 16 + lc;
                float ba = bias[j];
                float bg = bias[2560 + j];
                #pragma unroll
                for (int r = 0; r < 4; ++r) {
                    int row = baseRow + mi * 16 + q * 4 + r;
                    float aa = acc[mi][ni][r] + ba;
                    float gg = acc[mi][ni + 2][r] + bg;
                    outb[(size_t)row * 2560 + j] = f2b(aa * gelu_f(gg));
                }
            }
        return;
    }

    if (MODE == 2) {
        if (n0 >= 1280) {
            // Pure V tile: acc -> LDS [128 c][128 row] (XOR-swz, 32KB at As),
            // then tok-major coalesced store to vt (row bb*640+cd contiguous).
            char* VL = (char*)As;
            #pragma unroll
            for (int mi = 0; mi < 4; ++mi)
                #pragma unroll
                for (int ni = 0; ni < 4; ++ni) {
                    int c = wn * 64 + ni * 16 + lc;        // local col 0..127
                    int rb = wm * 64 + mi * 16 + q * 4;    // local row 0..124
                    us4 vv = { f2b(acc[mi][ni][0]), f2b(acc[mi][ni][1]),
                               f2b(acc[mi][ni][2]), f2b(acc[mi][ni][3]) };
                    *(us4*)(VL + c * 256 + ((rb * 2) ^ ((c & 7) << 4))) = vv;
                }
            __syncthreads();
            int bb = m0 >> 10, tokb = m0 & 1023;
            #pragma unroll
            for (int j = 0; j < 32; ++j) {
                int c = wid * 32 + j;
                unsigned d = *(const unsigned*)(VL + c * 256
                                                + ((lane * 4) ^ ((c & 7) << 4)));
                int cd = (bx - 10) * 128 + c;
                *(unsigned*)&out2[(size_t)(bb * 640 + cd) * 1024 + tokb + lane * 2] = d;
            }
            return;
        }
        // Q/K tile: scaled store to qkvb (cols all < 1280)
        #pragma unroll
        for (int mi = 0; mi < 4; ++mi)
            #pragma unroll
            for (int ni = 0; ni < 4; ++ni) {
                int col = baseCol + ni * 16 + lc;
                const float qs = (col < 640) ? 0.11180339887498949f : 1.0f;
                #pragma unroll
                for (int r = 0; r < 4; ++r) {
                    int row = baseRow + mi * 16 + q * 4 + r;
                    outb[(size_t)row * 1920 + col] = f2b(acc[mi][ni][r] * qs);
                }
            }
        return;
    }

    #pragma unroll
    for (int mi = 0; mi < 4; ++mi)
        #pragma unroll
        for (int ni = 0; ni < 4; ++ni) {
            int col = baseCol + ni * 16 + lc;
            #pragma unroll
            for (int r = 0; r < 4; ++r) {
                int row = baseRow + mi * 16 + q * 4 + r;
                float v = acc[mi][ni][r];
                if (MODE == 1) {
                    outb[(size_t)row * N + col] = f2b(v);
                } else if (MODE == 3) {
                    int bb = row / 80, rr = row - bb * 80;
                    if (rr < 77) {
                        u16 u = f2b(v);
                        if (col < 640) {
                            outb[(size_t)row * 640 + col] = u;
                        } else {
                            int cd = col - 640;
                            int hh = cd / 80, dd = cd - hh * 80;
                            out2[((bb * 8 + hh) * 80 + dd) * 80 + rr] = u;
                        }
                    }
                }
            }
        }
}

template<int MODE>
__global__ __launch_bounds__(256) void gemm_bt(const u16* __restrict__ A,
                                               const u16* __restrict__ Bt,
                                               int N, int K,
                                               const float* __restrict__ bias,
                                               const u16* __restrict__ resb,
                                               float* __restrict__ outf,
                                               u16* __restrict__ outb,
                                               u16* __restrict__ out2)
{
    __shared__ u16 As[128 * 64];
    __shared__ u16 Bs[128 * 64];
    gemm_core<MODE>(A, Bt, N, K, K, bias, resb, outf, outb, out2,
                    blockIdx.x, blockIdx.y, As, Bs);
}

// fused: blocks [0,960) = QKV GEMM (MODE 2), [960,1010) = CA-KV GEMM (MODE 3)
// Single 32KB LDS block: staging uses S[0..8191] + S[8192..16383]; MODE 2's
// V-transpose reuses the full 32KB (contiguity guaranteed by single array).
__global__ __launch_bounds__(256) void gemm_qkv_cakv(
    const u16* __restrict__ xb, const u16* __restrict__ saqkvt,
    const u16* __restrict__ ctxb, const u16* __restrict__ cakvt,
    u16* qkvb, u16* vt, u16* kc, u16* vct)
{
    __shared__ u16 S[128 * 128];
    u16* As = S;
    u16* Bs = S + 8192;
    int bid = blockIdx.x;
    if (bid < 960) {
        gemm_core<2>(xb, saqkvt, 1920, 640, 640, nullptr, nullptr, nullptr,
                     qkvb, vt, bid % 15, bid / 15, As, Bs);
    } else {
        int tt = bid - 960;
        gemm_core<3>(ctxb, cakvt, 1280, 768, 768, nullptr, nullptr, nullptr,
                     kc, vct, tt % 10, tt / 10, As, Bs);
    }
}

// ---------------------------------------------------------------------------
// 128x64-tile GEMM for N=640 occupancy-bound shapes (projections + FF2).
// MODE 0: outb = f2b(acc + bias[col] + b2f(resb[row*N+col]))  (bf16 psum)
// MODE 1: outb = f2b(acc)
template<int MODE>
__global__ __launch_bounds__(256) void gemm_n64(const u16* __restrict__ A,
                                                const u16* __restrict__ Bt,
                                                int N, int K,
                                                const float* __restrict__ bias,
                                                const u16* __restrict__ resb,
                                                u16* __restrict__ outb)
{
    __shared__ u16 As[128 * 64];
    __shared__ u16 Bs[64 * 64];
    const int lane = threadIdx.x & 63;
    const int wid  = threadIdx.x >> 6;
    const int hi   = lane >> 4;
    const int lc   = lane & 15;
    const int wm = wid >> 1, wn = wid & 1;
    const int m0 = blockIdx.y * 128;
    const int n0 = blockIdx.x * 64;
    const int ldb = K * 2;

    f4 acc[4][2];
    #pragma unroll
    for (int i = 0; i < 4; ++i)
        #pragma unroll
        for (int j = 0; j < 2; ++j) acc[i][j] = (f4){0.f, 0.f, 0.f, 0.f};

    const char* Abase = (const char*)A + (size_t)m0 * ldb;
    const char* Bbase = (const char*)Bt + (size_t)n0 * ldb;

    for (int kt = 0; kt < K; kt += 64) {
        #pragma unroll
        for (int c = 0; c < 6; ++c) {
            int cid = wid * 6 + c;              // 24 chunks: 16 A + 8 B
            if (cid < 16) {
                int o = cid * 1024 + lane * 16;
                int row = o >> 7;
                int src = (o & 127) ^ ((row & 7) << 4);
                gload16(Abase + (size_t)row * ldb + kt * 2 + src, (char*)As + cid * 1024);
            } else {
                int c2 = cid - 16;
                int o = c2 * 1024 + lane * 16;
                int row = o >> 7;
                int src = (o & 127) ^ ((row & 7) << 4);
                gload16(Bbase + (size_t)row * ldb + kt * 2 + src, (char*)Bs + c2 * 1024);
            }
        }
        __syncthreads();
        #pragma unroll
        for (int ks = 0; ks < 2; ++ks) {
            bfrag a[4], b[2];
            #pragma unroll
            for (int mi = 0; mi < 4; ++mi) {
                int row = wm * 64 + mi * 16 + lc;
                int off = row * 128 + ((ks * 64 + hi * 16) ^ ((row & 7) << 4));
                a[mi] = *(const bfrag*)((const char*)As + off);
            }
            #pragma unroll
            for (int ni = 0; ni < 2; ++ni) {
                int row = wn * 32 + ni * 16 + lc;
                int off = row * 128 + ((ks * 64 + hi * 16) ^ ((row & 7) << 4));
                b[ni] = *(const bfrag*)((const char*)Bs + off);
            }
            #pragma unroll
            for (int mi = 0; mi < 4; ++mi)
                #pragma unroll
                for (int ni = 0; ni < 2; ++ni)
                    acc[mi][ni] = MFMA(a[mi], b[ni], acc[mi][ni]);
        }
        __syncthreads();
    }

    const int baseRow = m0 + wm * 64;
    const int baseCol = n0 + wn * 32;
    #pragma unroll
    for (int mi = 0; mi < 4; ++mi)
        #pragma unroll
        for (int ni = 0; ni < 2; ++ni) {
            int col = baseCol + ni * 16 + lc;
            #pragma unroll
            for (int r = 0; r < 4; ++r) {
                int row = baseRow + mi * 16 + hi * 4 + r;
                float v = acc[mi][ni][r];
                if (MODE == 0)
                    v += bias[col] + b2f(resb[(size_t)row * N + col]);
                outb[(size_t)row * N + col] = f2b(v);
            }
        }
}

// ---------------------------------------------------------------------------
// Self-attention, swapped-QK^T layout. T14 async-STAGE (named pf regs) +
// T5 setprio around MFMA clusters.
__global__ __launch_bounds__(256) void attn_sa(const u16* __restrict__ qkv,
                                               const u16* __restrict__ vt,
                                               u16* __restrict__ out)
{
    __shared__ u16 Qs[64 * 80];
    __shared__ u16 Ks[64 * 80];
    __shared__ u16 Vs[80 * 64];
    __shared__ u16 Ps[4][16 * 64];

    const int lane = threadIdx.x & 63;
    const int wid  = threadIdx.x >> 6;
    const int hi   = lane >> 4;
    const int lc   = lane & 15;
    const int bid = blockIdx.x;
    const int qt = bid >> 6;
    const int bb = (bid >> 3) & 7;
    const int hh = bid & 7;
    const int tok0 = bb * 1024 + qt * 64;
    const char* qbase = (const char*)qkv;

    for (int c = wid; c < 10; c += 4) {       // stage Q [64][80] (gload_lds)
        int o = c * 1024 + lane * 16;
        int row = o / 160, col = o - row * 160;
        gload16(qbase + (size_t)(tok0 + row) * 3840 + hh * 160 + col, (char*)Qs + c * 1024);
    }

    // T14 prefetch setup: chunk c_i = wid + 4*i, i = 0..4.
    const char* gsrc0; const char* gsrc1; const char* gsrc2;
    const char* gsrc3; const char* gsrc4;
    char* ldst0; char* ldst1; char* ldst2; char* ldst3; char* ldst4;
    size_t tstep0, tstep1, tstep2, tstep3, tstep4;
    {
        const char* kbase = qbase + (size_t)(bb * 1024) * 3840 + 1280 + hh * 160;
        const char* vbase = (const char*)vt + (size_t)((bb * 8 + hh) * 80) * 2048;
#define SETUP_CH(I)                                                            \
        {                                                                      \
            int c = wid + 4 * I;                                               \
            if (c < 10) {                                                      \
                int o = c * 1024 + lane * 16;                                  \
                int row = o / 160, col = o - row * 160;                        \
                gsrc##I = kbase + (size_t)row * 3840 + col;                    \
                tstep##I = (size_t)64 * 3840;                                  \
                ldst##I = (char*)Ks + c * 1024 + lane * 16;                    \
            } else {                                                           \
                int c2 = c - 10;                                               \
                int o = c2 * 1024 + lane * 16;                                 \
                int row = o >> 7;                                              \
                int src = (o & 127) ^ ((row & 7) << 4);                        \
                gsrc##I = vbase + (size_t)row * 2048 + src;                    \
                tstep##I = 128;                                                \
                ldst##I = (char*)Vs + c2 * 1024 + lane * 16;                   \
            }                                                                  \
        }
        SETUP_CH(0) SETUP_CH(1) SETUP_CH(2) SETUP_CH(3) SETUP_CH(4)
#undef SETUP_CH
    }

    uint4 pf0, pf1, pf2, pf3, pf4;
#define LD_TILE(T)                                                             \
    pf0 = *(const uint4*)(gsrc0 + (size_t)(T) * tstep0);                       \
    pf1 = *(const uint4*)(gsrc1 + (size_t)(T) * tstep1);                       \
    pf2 = *(const uint4*)(gsrc2 + (size_t)(T) * tstep2);                       \
    pf3 = *(const uint4*)(gsrc3 + (size_t)(T) * tstep3);                       \
    pf4 = *(const uint4*)(gsrc4 + (size_t)(T) * tstep4);
#define ST_TILE()                                                              \
    *(uint4*)ldst0 = pf0; *(uint4*)ldst1 = pf1; *(uint4*)ldst2 = pf2;          \
    *(uint4*)ldst3 = pf3; *(uint4*)ldst4 = pf4;

    LD_TILE(0)
    ST_TILE()
    __syncthreads();

    const int qrow = wid * 16 + lc;
    bfrag qf0 = *(const bfrag*)((const char*)Qs + qrow * 160 + hi * 16);
    bfrag qf1 = *(const bfrag*)((const char*)Qs + qrow * 160 + 64 + hi * 16);
    bfrag qf2 = bzero();
    if (hi < 2) qf2 = *(const bfrag*)((const char*)Qs + qrow * 160 + 128 + hi * 16);

    float m = -3e30f, l = 0.f;
    f4 accO[5];
    #pragma unroll
    for (int no = 0; no < 5; ++no) accO[no] = (f4){0.f, 0.f, 0.f, 0.f};

    const float L2E = 1.4426950408889634f;

    for (int t = 0; t < 16; ++t) {
        if (t < 15) { LD_TILE(t + 1) }         // loads in flight under compute

        f4 sT[4];
        __builtin_amdgcn_s_setprio(1);
        #pragma unroll
        for (int nb = 0; nb < 4; ++nb) {
            const char* kb = (const char*)Ks + (nb * 16 + lc) * 160;
            bfrag k0 = *(const bfrag*)(kb + hi * 16);
            bfrag k1 = *(const bfrag*)(kb + 64 + hi * 16);
            bfrag k2 = bzero();
            if (hi < 2) k2 = *(const bfrag*)(kb + 128 + hi * 16);
            f4 a = {0.f, 0.f, 0.f, 0.f};
            a = MFMA(k0, qf0, a);
            a = MFMA(k1, qf1, a);
            a = MFMA(k2, qf2, a);
            sT[nb] = a;
        }
        __builtin_amdgcn_s_setprio(0);

        float pm = sT[0][0];
        #pragma unroll
        for (int nb = 0; nb < 4; ++nb)
            #pragma unroll
            for (int r = 0; r < 4; ++r) pm = fmaxf(pm, sT[nb][r]);
        pm = fmaxf(pm, __shfl_xor(pm, 16));
        pm = fmaxf(pm, __shfl_xor(pm, 32));

        if (__any(pm > m + 8.0f)) {
            float mn = fmaxf(m, pm);
            float al = exp2f((m - mn) * L2E);
            m = mn;
            l *= al;
            float af[4];
            #pragma unroll
            for (int r = 0; r < 4; ++r) af[r] = __shfl(al, hi * 4 + r);
            #pragma unroll
            for (int no = 0; no < 5; ++no)
                #pragma unroll
                for (int r = 0; r < 4; ++r) accO[no][r] *= af[r];
        }

        float sum = 0.f;
        #pragma unroll
        for (int nb = 0; nb < 4; ++nb)
            #pragma unroll
            for (int r = 0; r < 4; ++r) {
                float p = exp2f((sT[nb][r] - m) * L2E);
                sT[nb][r] = p;
                sum += p;
            }
        sum += __shfl_xor(sum, 16);
        sum += __shfl_xor(sum, 32);
        l += sum;

        char* Pw = (char*)&Ps[wid][0];
        #pragma unroll
        for (int nb = 0; nb < 4; ++nb) {
            us4 pk = { f2b(sT[nb][0]), f2b(sT[nb][1]), f2b(sT[nb][2]), f2b(sT[nb][3]) };
            int cb = (nb * 16 + hi * 4) * 2;
            *(us4*)(Pw + lc * 128 + (cb ^ ((lc & 7) << 4))) = pk;
        }

        bfrag pa0 = *(const bfrag*)(Pw + lc * 128 + ((hi * 16) ^ ((lc & 7) << 4)));
        bfrag pa1 = *(const bfrag*)(Pw + lc * 128 + ((64 + hi * 16) ^ ((lc & 7) << 4)));
        __builtin_amdgcn_s_setprio(1);
        #pragma unroll
        for (int no = 0; no < 5; ++no) {
            int vr = no * 16 + lc;
            const char* vb = (const char*)Vs + vr * 128;
            bfrag v0 = *(const bfrag*)(vb + ((hi * 16) ^ ((vr & 7) << 4)));
            bfrag v1 = *(const bfrag*)(vb + ((64 + hi * 16) ^ ((vr & 7) << 4)));
            accO[no] = MFMA(pa0, v0, accO[no]);
            accO[no] = MFMA(pa1, v1, accO[no]);
        }
        __builtin_amdgcn_s_setprio(0);

        __syncthreads();                       // all reads of tile t complete
        if (t < 15) {
            ST_TILE()                          // waits vmcnt on pf regs
            __syncthreads();                   // writes visible to all waves
        }
    }
#undef LD_TILE
#undef ST_TILE

    float rf[4];
    #pragma unroll
    for (int r = 0; r < 4; ++r) {
        float lf = __shfl(l, hi * 4 + r);
        rf[r] = __builtin_amdgcn_rcpf(lf);
    }
    #pragma unroll
    for (int no = 0; no < 5; ++no)
        #pragma unroll
        for (int r = 0; r < 4; ++r) {
            int row = tok0 + wid * 16 + hi * 4 + r;
            int col = hh * 80 + no * 16 + lc;
            out[(size_t)row * 640 + col] = f2b(accO[no][r] * rf[r]);
        }
}

// ---------------------------------------------------------------------------
// Cross-attention: single KV tile (77 keys padded to 80, masked).
__global__ __launch_bounds__(256) void attn_ca(const u16* __restrict__ qc,
                                               const u16* __restrict__ kc,
                                               const u16* __restrict__ vct,
                                               u16* __restrict__ out)
{
    __shared__ u16 Qs[64 * 80];
    __shared__ u16 Ks[84 * 80];
    __shared__ u16 Vs[84 * 80];
    __shared__ u16 Ps[4][16 * 80];

    const int lane = threadIdx.x & 63;
    const int wid  = threadIdx.x >> 6;
    const int q    = lane >> 4;
    const int lc   = lane & 15;
    const int bid = blockIdx.x;
    const int qt = bid & 15;
    const int hh = (bid >> 4) & 7;
    const int bb = bid >> 7;
    const int tok0 = bb * 1024 + qt * 64;

    for (int c = wid; c < 36; c += 4) {
        if (c < 10) {
            int o = c * 1024 + lane * 16;
            int row = o / 160, col = o - row * 160;
            gload16((const char*)qc + (size_t)(tok0 + row) * 1280 + hh * 160 + col,
                    (char*)Qs + c * 1024);
        } else if (c < 23) {
            int c2 = c - 10;
            int o = c2 * 1024 + lane * 16;
            int row = o / 160, col = o - row * 160;
            gload16((const char*)kc + (size_t)(bb * 80 + row) * 1280 + hh * 160 + col,
                    (char*)Ks + c2 * 1024);
        } else {
            int c2 = c - 23;
            int o = c2 * 1024 + lane * 16;
            int row = o / 160, col = o - row * 160;
            gload16((const char*)vct + (size_t)((bb * 8 + hh) * 80 + row) * 160 + col,
                    (char*)Vs + c2 * 1024);
        }
    }
    __syncthreads();

    const int qrow = wid * 16 + lc;
    bfrag qf0 = *(const bfrag*)((const char*)Qs + qrow * 160 + q * 16);
    bfrag qf1 = *(const bfrag*)((const char*)Qs + qrow * 160 + 64 + q * 16);
    bfrag qf2 = bzero();
    if (q < 2) qf2 = *(const bfrag*)((const char*)Qs + qrow * 160 + 128 + q * 16);

    const float SC = 0.11180339887498949f;
    const float L2E = 1.4426950408889634f;

    f4 s[5];
    __builtin_amdgcn_s_setprio(1);
    #pragma unroll
    for (int nb = 0; nb < 5; ++nb) {
        const char* kb = (const char*)Ks + (nb * 16 + lc) * 160;
        bfrag k0 = *(const bfrag*)(kb + q * 16);
        bfrag k1 = *(const bfrag*)(kb + 64 + q * 16);
        bfrag k2 = bzero();
        if (q < 2) k2 = *(const bfrag*)(kb + 128 + q * 16);
        f4 a = {0.f, 0.f, 0.f, 0.f};
        a = MFMA(qf0, k0, a);
        a = MFMA(qf1, k1, a);
        a = MFMA(qf2, k2, a);
        s[nb] = a;
    }
    __builtin_amdgcn_s_setprio(0);
    #pragma unroll
    for (int nb = 0; nb < 5; ++nb) {
        int key = nb * 16 + lc;
        #pragma unroll
        for (int r = 0; r < 4; ++r) {
            s[nb][r] *= SC;
            if (key >= 77) s[nb][r] = -1e30f;
        }
    }
    float mrow[4], lrow[4];
    #pragma unroll
    for (int r = 0; r < 4; ++r) {
        float v = fmaxf(fmaxf(fmaxf(s[0][r], s[1][r]), fmaxf(s[2][r], s[3][r])), s[4][r]);
        v = fmaxf(v, __shfl_xor(v, 1));
        v = fmaxf(v, __shfl_xor(v, 2));
        v = fmaxf(v, __shfl_xor(v, 4));
        v = fmaxf(v, __shfl_xor(v, 8));
        mrow[r] = v;
    }
    float rsum[4] = {0.f, 0.f, 0.f, 0.f};
    #pragma unroll
    for (int nb = 0; nb < 5; ++nb)
        #pragma unroll
        for (int r = 0; r < 4; ++r) {
            float p = exp2f((s[nb][r] - mrow[r]) * L2E);
            s[nb][r] = p;
            rsum[r] += p;
        }
    #pragma unroll
    for (int r = 0; r < 4; ++r) {
        float v = rsum[r];
        v += __shfl_xor(v, 1);
        v += __shfl_xor(v, 2);
        v += __shfl_xor(v, 4);
        v += __shfl_xor(v, 8);
        lrow[r] = v;
    }

    char* Pw = (char*)&Ps[wid][0];
    #pragma unroll
    for (int nb = 0; nb < 5; ++nb)
        #pragma unroll
        for (int r = 0; r < 4; ++r) {
            int prow = q * 4 + r;
            *(u16*)(Pw + prow * 160 + (nb * 16 + lc) * 2) = f2b(s[nb][r]);
        }
    bfrag pa0 = *(const bfrag*)(Pw + lc * 160 + q * 16);
    bfrag pa1 = *(const bfrag*)(Pw + lc * 160 + 64 + q * 16);
    bfrag pa2 = bzero();
    if (q < 2) pa2 = *(const bfrag*)(Pw + lc * 160 + 128 + q * 16);

    f4 accO[5];
    __builtin_amdgcn_s_setprio(1);
    #pragma unroll
    for (int no = 0; no < 5; ++no) {
        const char* vb = (const char*)Vs + (no * 16 + lc) * 160;
        bfrag v0 = *(const bfrag*)(vb + q * 16);
        bfrag v1 = *(const bfrag*)(vb + 64 + q * 16);
        bfrag v2 = bzero();
        if (q < 2) v2 = *(const bfrag*)(vb + 128 + q * 16);
        f4 a = {0.f, 0.f, 0.f, 0.f};
        a = MFMA(pa0, v0, a);
        a = MFMA(pa1, v1, a);
        a = MFMA(pa2, v2, a);
        accO[no] = a;
    }
    __builtin_amdgcn_s_setprio(0);
    #pragma unroll
    for (int no = 0; no < 5; ++no)
        #pragma unroll
        for (int r = 0; r < 4; ++r) {
            int row = tok0 + wid * 16 + q * 4 + r;
            int col = hh * 80 + no * 16 + lc;
            out[(size_t)row * 640 + col] = f2b(accO[no][r] / lrow[r]);
        }
}

// ---------------------------------------------------------------------------
// LayerNorm over 640 cols from bf16 psum; 1 wave per row, 4 rows per block.
__global__ __launch_bounds__(256) void ln_kb(const u16* __restrict__ pre,
                                             const float* __restrict__ g,
                                             const float* __restrict__ b,
                                             float* __restrict__ xo,
                                             u16* __restrict__ xb)
{
    const int lane = threadIdx.x & 63;
    const int wid  = threadIdx.x >> 6;
    const int row = blockIdx.x * 4 + wid;
    const u16* p = pre + (size_t)row * 640;
    float v[10];
    #pragma unroll
    for (int i = 0; i < 5; ++i) {
        unsigned d = *(const unsigned*)(p + i * 128 + lane * 2);
        v[2 * i]     = b2f((u16)(d & 0xffffu));
        v[2 * i + 1] = b2f((u16)(d >> 16));
    }
    float s = 0.f;
    #pragma unroll
    for (int i = 0; i < 10; ++i) s += v[i];
    #pragma unroll
    for (int m = 1; m < 64; m <<= 1) s += __shfl_xor(s, m);
    float mu = s * (1.0f / 640.0f);
    float d2 = 0.f;
    #pragma unroll
    for (int i = 0; i < 10; ++i) { float d = v[i] - mu; d2 += d * d; }
    #pragma unroll
    for (int m = 1; m < 64; m <<= 1) d2 += __shfl_xor(d2, m);
    float rs = rsqrtf(d2 * (1.0f / 640.0f) + 1e-5f);
    #pragma unroll
    for (int i = 0; i < 5; ++i) {
        int col = i * 128 + lane * 2;
        float y0 = (v[2 * i]     - mu) * rs * g[col]     + b[col];
        float y1 = (v[2 * i + 1] - mu) * rs * g[col + 1] + b[col + 1];
        if (xo) {
            *(float2*)&xo[(size_t)row * 640 + col] = make_float2(y0, y1);
        }
        if (xb) {
            *(unsigned*)&xb[(size_t)row * 640 + col] = pack2(y0, y1);
        }
    }
}

// ---------------------------------------------------------------------------
extern "C" void kernel_launch(void* const* d_in, const int* in_sizes, int n_in,
                              void* d_out, int out_size, void* d_ws, size_t ws_size,
                              hipStream_t stream)
{
    const float* x       = (const float*)d_in[0];
    const float* context = (const float*)d_in[1];
    const float* sa_wq = (const float*)d_in[2];
    const float* sa_wk = (const float*)d_in[3];
    const float* sa_wv = (const float*)d_in[4];
    const float* sa_wo = (const float*)d_in[5];
    const float* sa_bo = (const float*)d_in[6];
    const float* ca_wq = (const float*)d_in[7];
    const float* ca_wk = (const float*)d_in[8];
    const float* ca_wv = (const float*)d_in[9];
    const float* ca_wo = (const float*)d_in[10];
    const float* ca_bo = (const float*)d_in[11];
    const float* ff_w1 = (const float*)d_in[12];
    const float* ff_b1 = (const float*)d_in[13];
    const float* ff_w2 = (const float*)d_in[14];
    const float* ff_b2 = (const float*)d_in[15];
    const float* ln1_g = (const float*)d_in[16];
    const float* ln1_b = (const float*)d_in[17];
    const float* ln2_g = (const float*)d_in[18];
    const float* ln2_b = (const float*)d_in[19];
    const float* ln3_g = (const float*)d_in[20];
    const float* ln3_b = (const float*)d_in[21];

    char* ws = (char*)d_ws;
    const size_t OFF_XB     = 0;
    const size_t OFF_QKVB   = 10485760;
    const size_t OFF_VT     = 41943040;
    const size_t OFF_AB     = 52428800;
    const size_t OFF_ATTN   = 62914560;
    const size_t OFF_QC     = 73400320;
    const size_t OFF_KC     = 83886080;
    const size_t OFF_VCT    = 84705280;
    const size_t OFF_SAQKVT = 85524480;
    const size_t OFF_SAWOT  = 87982080;
    const size_t OFF_CAWQT  = 88801280;
    const size_t OFF_CAKVT  = 89620480;
    const size_t OFF_CAWOT  = 91586560;
    const size_t OFF_FFW1T  = 92405760;
    const size_t OFF_FFW2T  = 98959360;
    const size_t OFF_CTXB   = 102236160;
    const size_t OFF_PRE    = 103219200;    // bf16 psum

    u16* xb      = (u16*)(ws + OFF_XB);
    u16* qkvb    = (u16*)(ws + OFF_QKVB);
    u16* vt      = (u16*)(ws + OFF_VT);
    u16* ab      = (u16*)(ws + OFF_AB);
    u16* attnb   = (u16*)(ws + OFF_ATTN);
    u16* qc      = (u16*)(ws + OFF_QC);
    u16* kc      = (u16*)(ws + OFF_KC);
    u16* vct     = (u16*)(ws + OFF_VCT);
    u16* saqkvt  = (u16*)(ws + OFF_SAQKVT);
    u16* sawot   = (u16*)(ws + OFF_SAWOT);
    u16* cawqt   = (u16*)(ws + OFF_CAWQT);
    u16* cakvt   = (u16*)(ws + OFF_CAKVT);
    u16* cawot   = (u16*)(ws + OFF_CAWOT);
    u16* ffw1t   = (u16*)(ws + OFF_FFW1T);
    u16* ffw2t   = (u16*)(ws + OFF_FFW2T);
    u16* ctxb    = (u16*)(ws + OFF_CTXB);
    u16* psum    = (u16*)(ws + OFF_PRE);
    u16* ffh     = (u16*)(ws + OFF_XB);          // aliases xb+qkvb

    // --- prep: all transposes + conversions, one dispatch ---
    hipLaunchKernelGGL(prep_k, dim3(10960), dim3(256), 0, stream,
                       x, context, sa_wq, sa_wk, sa_wv, sa_wo, ca_wq, ca_wk,
                       ca_wv, ca_wo, ff_w1, ff_w2,
                       saqkvt, sawot, cawqt, cawot, cakvt, ffw1t, ffw2t, xb, ctxb);

    // --- self-attention (QKV fused with CA-KV) ---
    hipLaunchKernelGGL(gemm_qkv_cakv, dim3(1010), dim3(256), 0, stream,
                       xb, saqkvt, ctxb, cakvt, qkvb, vt, kc, vct);
    hipLaunchKernelGGL(attn_sa, dim3(1024), dim3(256), 0, stream, qkvb, vt, attnb);
    hipLaunchKernelGGL(gemm_n64<0>, dim3(10, 64), dim3(256), 0, stream,
                       attnb, sawot, 640, 640, sa_bo, xb, psum);
    hipLaunchKernelGGL(ln_kb, dim3(2048), dim3(256), 0, stream, psum, ln1_g, ln1_b,
                       (float*)nullptr, ab);

    // --- cross-attention ---
    hipLaunchKernelGGL(gemm_n64<1>, dim3(10, 64), dim3(256), 0, stream,
                       ab, cawqt, 640, 640, (const float*)nullptr, (const u16*)nullptr,
                       qc);
    hipLaunchKernelGGL(attn_ca, dim3(1024), dim3(256), 0, stream, qc, kc, vct, attnb);
    hipLaunchKernelGGL(gemm_n64<0>, dim3(10, 64), dim3(256), 0, stream,
                       attnb, cawot, 640, 640, ca_bo, ab, psum);
    hipLaunchKernelGGL(ln_kb, dim3(2048), dim3(256), 0, stream, psum, ln2_g, ln2_b,
                       (float*)nullptr, ab);

    // --- GEGLU FFN ---
    hipLaunchKernelGGL(gemm_bt<4>, dim3(40, 64), dim3(256), 0, stream,
                       ab, ffw1t, 5120, 640, ff_b1, (const u16*)nullptr,
                       (float*)nullptr, ffh, (u16*)nullptr);
    hipLaunchKernelGGL(gemm_n64<0>, dim3(10, 64), dim3(256), 0, stream,
                       ffh, ffw2t, 640, 2560, ff_b2, ab, psum);
    hipLaunchKernelGGL(ln_kb, dim3(2048), dim3(256), 0, stream, psum, ln3_g, ln3_b,
                       (float*)d_out, (u16*)nullptr);
}